// Round 3
// baseline (809.378 us; speedup 1.0000x reference)
//
#include <hip/hip_runtime.h>
#include <hip/hip_bf16.h>
#include <math.h>

// Problem constants
#define N_TOK 2048
#define H_DIM 4096
#define NH 32
#define NKV 8
#define HD 128
#define QKV_D 6144   // (NH + 2*NKV) * HD
#define NE 8
#define TOPK 2

// d_out layout (floats): permuted_output | topk_weights | topk_ids | reorder_ids
#define OUT_PERM 0
#define OUT_W    16777216   // 4096*4096
#define OUT_IDS  16781312
#define OUT_REO  16785408

typedef __bf16 bf16x8 __attribute__((ext_vector_type(8)));
typedef float f32x4 __attribute__((ext_vector_type(4)));

typedef __attribute__((address_space(3))) void lds_void;
typedef __attribute__((address_space(1))) const void gbl_void;

__device__ __forceinline__ void gld16(const void* g, void* l) {
    // async global->LDS, 16B per lane; LDS dest = wave-uniform base + lane*16
    __builtin_amdgcn_global_load_lds((gbl_void*)g, (lds_void*)l, 16, 0, 0);
}

__device__ __forceinline__ unsigned short f2bf(float f) {
    union { float f; unsigned u; } v; v.f = f;
    unsigned r = v.u + 0x7fff + ((v.u >> 16) & 1);
    return (unsigned short)(r >> 16);
}
__device__ __forceinline__ unsigned pack2bf(float a, float b) {
    return (unsigned)f2bf(a) | ((unsigned)f2bf(b) << 16);
}
__device__ __forceinline__ float bf2f(unsigned short u) {
    union { unsigned u; float f; } v; v.u = ((unsigned)u) << 16;
    return v.f;
}

// ---------------- RMSNorm (fp32 in; fp32 or bf16 out) ----------------
__global__ __launch_bounds__(256) void rmsnorm_k(const float* __restrict__ x,
                                                 const float* __restrict__ w,
                                                 float* __restrict__ yf,
                                                 unsigned short* __restrict__ yb) {
    int row = blockIdx.x;
    int tid = threadIdx.x;
    const float4* x4 = (const float4*)(x + (size_t)row * H_DIM);
    const float4* w4 = (const float4*)w;
    float4 v[4];
    float ss = 0.f;
#pragma unroll
    for (int k = 0; k < 4; ++k) {
        v[k] = x4[tid + k * 256];
        ss += v[k].x * v[k].x + v[k].y * v[k].y + v[k].z * v[k].z + v[k].w * v[k].w;
    }
#pragma unroll
    for (int off = 32; off; off >>= 1) ss += __shfl_xor(ss, off);
    __shared__ float sacc[4];
    if ((tid & 63) == 0) sacc[tid >> 6] = ss;
    __syncthreads();
    float tot = sacc[0] + sacc[1] + sacc[2] + sacc[3];
    float sc = rsqrtf(tot * (1.0f / H_DIM) + 1e-6f);
#pragma unroll
    for (int k = 0; k < 4; ++k) {
        float4 ww = w4[tid + k * 256];
        float4 o;
        o.x = v[k].x * sc * ww.x;
        o.y = v[k].y * sc * ww.y;
        o.z = v[k].z * sc * ww.z;
        o.w = v[k].w * sc * ww.w;
        if (yf) {
            *(float4*)(yf + (size_t)row * H_DIM + (tid + k * 256) * 4) = o;
        } else {
            uint2 p;
            p.x = pack2bf(o.x, o.y);
            p.y = pack2bf(o.z, o.w);
            *(uint2*)(yb + (size_t)row * H_DIM + (tid + k * 256) * 4) = p;
        }
    }
}

// ---------------- transpose + fp32->bf16 weight conversion ----------------
// src[R][C] fp32 -> dst[C][R] bf16 (64x64 tiles)
__global__ __launch_bounds__(256) void convT_k(const float* __restrict__ src,
                                               unsigned short* __restrict__ dst,
                                               int R, int C) {
    __shared__ float t[64][68];
    int r0 = blockIdx.y * 64, c0 = blockIdx.x * 64;
    int tid = threadIdx.x;
    int lr = tid >> 4, lc = tid & 15;
#pragma unroll
    for (int it = 0; it < 4; ++it) {
        int r = lr + it * 16;
        float4 v = *(const float4*)(src + (size_t)(r0 + r) * C + c0 + lc * 4);
        *(float4*)&t[r][lc * 4] = v;
    }
    __syncthreads();
#pragma unroll
    for (int it = 0; it < 4; ++it) {
        int cc = lr + it * 16;
        uint2 o;
        o.x = pack2bf(t[lc * 4 + 0][cc], t[lc * 4 + 1][cc]);
        o.y = pack2bf(t[lc * 4 + 2][cc], t[lc * 4 + 3][cc]);
        *(uint2*)(dst + (size_t)(c0 + cc) * R + r0 + lc * 4) = o;
    }
}

// ---------------- bf16 MFMA GEMM: C[M x Nc] = A[M x 4096] @ Bt[Nc x 4096]^T ----
// 128x128 tile, BK=64, 4 waves each 64x64, 16x16x32 MFMA.
// T3 2-phase pipeline: double-buffered LDS, next-tile global_load_lds issued
// BEFORE compute, single __syncthreads (implicit vmcnt drain) per K-step.
// T1 bijective XCD swizzle (nwg % 8 == 0 for both call sites).
// LDS linear for global_load_lds; XOR swizzle on pre-swizzled GLOBAL source,
// mirrored on the ds_read side (rule #21).
// Output: bf16 (Cb) or fp32 + residual (C).
__global__ __launch_bounds__(256) void gemm_k(const __hip_bfloat16* __restrict__ A,
                                              const __hip_bfloat16* __restrict__ Bt,
                                              float* __restrict__ C,
                                              unsigned short* __restrict__ Cb,
                                              const float* __restrict__ residual,
                                              int Ncols) {
    __shared__ __align__(16) __hip_bfloat16 As[2][128 * 64];  // 2 x 16 KB
    __shared__ __align__(16) __hip_bfloat16 Bs[2][128 * 64];  // 2 x 16 KB
    const int K = H_DIM;
    int tid = threadIdx.x, w = tid >> 6, lane = tid & 63;
    int quad = lane >> 4, l15 = lane & 15;

    // XCD-aware bijective block swizzle: each XCD gets a contiguous chunk of
    // linear block ids -> contiguous n-panels stay in one XCD's L2.
    int gx = gridDim.x;
    int nwg = gx * gridDim.y;
    int v = blockIdx.y * gx + blockIdx.x;           // hw dispatch order (xcd ~ v%8)
    int lin = (v & 7) * (nwg >> 3) + (v >> 3);
    int m0 = (lin % gx) * 128, n0 = (lin / gx) * 128;
    int wm = (w & 1) * 64, wn = (w >> 1) * 64;

    // staging: 16 chunks of 8 rows (1024B) each for A and B; wave w owns chunks 4w..4w+3
    int rowInChunk = lane >> 3;   // 0..7
    int uIdx = lane & 7;          // 16B unit within 128B row
    const char* Ag[4]; const char* Bg[4];
    int chOff[4];
#pragma unroll
    for (int c = 0; c < 4; ++c) {
        int ch = w * 4 + c;
        int r = ch * 8 + rowInChunk;
        int gu = uIdx ^ (r & 7);   // pre-swizzled global source unit
        Ag[c] = (const char*)(A + (size_t)(m0 + r) * K) + gu * 16;
        Bg[c] = (const char*)(Bt + (size_t)(n0 + r) * K) + gu * 16;
        chOff[c] = ch * 1024;
    }

    f32x4 acc[4][4];
#pragma unroll
    for (int i = 0; i < 4; ++i)
#pragma unroll
        for (int j = 0; j < 4; ++j) acc[i][j] = (f32x4){0.f, 0.f, 0.f, 0.f};

    const int nsteps = K / 64;

    // prologue: stage step 0 into buf 0; barrier drains vmcnt for all waves
#pragma unroll
    for (int c = 0; c < 4; ++c) gld16(Ag[c], (char*)&As[0][0] + chOff[c]);
#pragma unroll
    for (int c = 0; c < 4; ++c) gld16(Bg[c], (char*)&Bs[0][0] + chOff[c]);
    __syncthreads();

    for (int t = 0; t < nsteps; ++t) {
        int cur = t & 1;
        if (t + 1 < nsteps) {   // issue next K-tile loads (hidden under compute)
            size_t kb = (size_t)(t + 1) * 128;   // bytes along K
            char* dA = (char*)&As[cur ^ 1][0];
            char* dB = (char*)&Bs[cur ^ 1][0];
#pragma unroll
            for (int c = 0; c < 4; ++c) gld16(Ag[c] + kb, dA + chOff[c]);
#pragma unroll
            for (int c = 0; c < 4; ++c) gld16(Bg[c] + kb, dB + chOff[c]);
        }
        const char* sA = (const char*)&As[cur][0];
        const char* sB = (const char*)&Bs[cur][0];
#pragma unroll
        for (int kk = 0; kk < 2; ++kk) {
            bf16x8 af[4], bfr[4];
#pragma unroll
            for (int mt = 0; mt < 4; ++mt) {
                int m = wm + mt * 16 + l15;
                af[mt] = *(const bf16x8*)(sA + m * 128 + (((kk * 4 + quad) ^ (m & 7)) * 16));
            }
#pragma unroll
            for (int nt = 0; nt < 4; ++nt) {
                int n = wn + nt * 16 + l15;
                bfr[nt] = *(const bf16x8*)(sB + n * 128 + (((kk * 4 + quad) ^ (n & 7)) * 16));
            }
#pragma unroll
            for (int mt = 0; mt < 4; ++mt)
#pragma unroll
                for (int nt = 0; nt < 4; ++nt)
                    acc[mt][nt] = __builtin_amdgcn_mfma_f32_16x16x32_bf16(af[mt], bfr[nt], acc[mt][nt], 0, 0, 0);
        }
        // single barrier per step: implicit vmcnt(0)+lgkmcnt(0) drain covers
        // next-tile loads (issued ~32 MFMAs ago) and this step's ds_reads
        __syncthreads();
    }
    // epilogue: C/D layout col=lane&15, row=quad*4+reg
#pragma unroll
    for (int mt = 0; mt < 4; ++mt)
#pragma unroll
        for (int nt = 0; nt < 4; ++nt)
#pragma unroll
            for (int r = 0; r < 4; ++r) {
                int row = m0 + wm + mt * 16 + quad * 4 + r;
                int col = n0 + wn + nt * 16 + l15;
                size_t off = (size_t)row * Ncols + col;
                float vv = acc[mt][nt][r];
                if (Cb) {
                    Cb[off] = f2bf(vv);
                } else {
                    if (residual) vv += residual[off];
                    C[off] = vv;
                }
            }
}

// ---------------- prep: RoPE + pack Qc (scaled bf16) and Kc (bf16, per-head rows) ----
// reads bf16 qkv
__global__ __launch_bounds__(256) void prep_k(const unsigned short* __restrict__ qkvb,
                                              const int* __restrict__ pos,
                                              unsigned short* __restrict__ Qc,
                                              unsigned short* __restrict__ Kc) {
    int row = blockIdx.x, tid = threadIdx.x;
    float fpos = (float)pos[row];
    const float scale = 0.08838834764831845f;  // 1/sqrt(128)
    const float lg = 0.20762050593045f;        // log2(10000)/64
#pragma unroll
    for (int it = 0; it < 8; ++it) {
        int pi = tid + it * 256;        // 0..2047 : q pairs
        int head = pi >> 6, t = pi & 63;
        float inv = exp2f(-(float)t * lg);
        float ang = fpos * inv;
        float s = __sinf(ang), c = __cosf(ang);
        const unsigned short* bp = qkvb + (size_t)row * QKV_D + head * HD + t;
        float x1 = bf2f(bp[0]), x2 = bf2f(bp[64]);
        unsigned short* qb = Qc + (size_t)row * H_DIM + head * HD + t;
        qb[0]  = f2bf((x1 * c - x2 * s) * scale);
        qb[64] = f2bf((x2 * c + x1 * s) * scale);
    }
#pragma unroll
    for (int it = 0; it < 2; ++it) {
        int pi = tid + it * 256;        // 0..511 : k pairs
        int kvh = pi >> 6, t = pi & 63;
        float inv = exp2f(-(float)t * lg);
        float ang = fpos * inv;
        float s = __sinf(ang), c = __cosf(ang);
        const unsigned short* bp = qkvb + (size_t)row * QKV_D + H_DIM + kvh * HD + t;
        float x1 = bf2f(bp[0]), x2 = bf2f(bp[64]);
        unsigned short* kb = Kc + ((size_t)kvh * N_TOK + row) * HD + t;
        kb[0]  = f2bf(x1 * c - x2 * s);
        kb[64] = f2bf(x2 * c + x1 * s);
    }
}

// ---------------- V transpose: bf16 qkv V section -> Vt[kvh][d][key] ----------------
__global__ __launch_bounds__(256) void vt_k(const unsigned short* __restrict__ qkvb,
                                            unsigned short* __restrict__ Vt) {
    __shared__ unsigned short ts[64][136];
    int j0 = blockIdx.x * 64, kvh = blockIdx.y, tid = threadIdx.x;
#pragma unroll
    for (int it = 0; it < 4; ++it) {
        int idx = tid + it * 256;   // 16B slots of 64x128 ushort tile
        int r = idx >> 4, c8 = idx & 15;
        *(uint4*)&ts[r][c8 * 8] =
            *(const uint4*)(qkvb + (size_t)(j0 + r) * QKV_D + (NH + NKV) * HD + kvh * HD + c8 * 8);
    }
    __syncthreads();
    int d = tid >> 1, half = tid & 1;
    unsigned short* dst = Vt + ((size_t)kvh * HD + d) * N_TOK + j0 + half * 32;
#pragma unroll
    for (int g = 0; g < 4; ++g) {
        int kb = half * 32 + g * 8;
        uint4 o;
        o.x = (unsigned)ts[kb + 0][d] | ((unsigned)ts[kb + 1][d] << 16);
        o.y = (unsigned)ts[kb + 2][d] | ((unsigned)ts[kb + 3][d] << 16);
        o.z = (unsigned)ts[kb + 4][d] | ((unsigned)ts[kb + 5][d] << 16);
        o.w = (unsigned)ts[kb + 6][d] | ((unsigned)ts[kb + 7][d] << 16);
        *(uint4*)(dst + g * 8) = o;
    }
}

// ---------------- bf16 MFMA flash attention ----------------
// block = 512 threads / 8 waves: 64 q-rows x 2 heads (same kv-head group).
// Wave w: head = base + (w&1), q-rows i0 + (w>>1)*16.
// K/V double-buffered in LDS, T3 2-phase pipeline: issue next-tile
// global_load_lds BEFORE compute, single __syncthreads (with its implicit
// vmcnt drain) per 32-key step.
__global__ __launch_bounds__(512) void attn_k(const __hip_bfloat16* __restrict__ Qc,
                                              const __hip_bfloat16* __restrict__ Kc,
                                              const __hip_bfloat16* __restrict__ Vt,
                                              unsigned short* __restrict__ ao) {
    __shared__ __align__(16) __hip_bfloat16 Ks[2][32 * 128];   // [key][d], swizzled 16B units, 8KB/buf
    __shared__ __align__(16) __hip_bfloat16 Vs[2][128 * 32];   // [d][key], swizzled 16B units, 8KB/buf
    __shared__ __align__(16) unsigned short Pw[8][16 * 40];    // per-wave P, row stride 80B

    int tid = threadIdx.x, w = tid >> 6, lane = tid & 63;
    int quad = lane >> 4, l15 = lane & 15;
    int pr = blockIdx.y;                 // 0..15: (kvh, head-pair)
    int kvh = pr >> 1;
    int h = kvh * 4 + (pr & 1) * 2 + (w & 1);
    int qt = gridDim.x - 1 - blockIdx.x; // heavy tiles first
    int i0 = qt * 64;
    int i0q = i0 + (w >> 1) * 16;
    int q = i0q + l15;

    bf16x8 qf[4];
    const __hip_bfloat16* qrow = Qc + (size_t)q * H_DIM + h * HD;
#pragma unroll
    for (int kf = 0; kf < 4; ++kf)
        qf[kf] = *(const bf16x8*)(qrow + kf * 32 + quad * 8);

    const char* KcH = (const char*)(Kc + (size_t)kvh * N_TOK * HD);
    const char* VtH = (const char*)(Vt + (size_t)kvh * HD * N_TOK);

    // staging: wave w stages K chunk w (keys 4w..4w+3) and V chunk w (d 16w..16w+15)
    int kKey = w * 4 + (lane >> 4);                 // key row within 32-key tile
    int kPart = (lane & 15) ^ (kKey & 15);          // pre-swizzled global 16B unit
    int vD = w * 16 + (lane >> 2);                  // d row
    int vP = (lane & 3) ^ (vD & 3);
    char* Kl[2] = { (char*)&Ks[0][0] + w * 1024, (char*)&Ks[1][0] + w * 1024 };
    char* Vl[2] = { (char*)&Vs[0][0] + w * 1024, (char*)&Vs[1][0] + w * 1024 };

    float mstat = -INFINITY, lstat = 0.f;
    f32x4 o[8];
#pragma unroll
    for (int nt = 0; nt < 8; ++nt) o[nt] = (f32x4){0.f, 0.f, 0.f, 0.f};

    int nsteps = (i0 + 64) >> 5;

    // prologue: stage step 0 into buf 0; __syncthreads drains vmcnt(0) for all waves
    gld16(KcH + (size_t)kKey * 256 + kPart * 16, Kl[0]);
    gld16(VtH + (size_t)vD * (N_TOK * 2) + vP * 16, Vl[0]);
    __syncthreads();

    for (int t = 0; t < nsteps; ++t) {
        int j0 = t << 5;
        int cur = t & 1;
        if (t + 1 < nsteps) {   // issue next tile's loads (hidden under compute)
            int jn = j0 + 32;
            gld16(KcH + (size_t)(jn + kKey) * 256 + kPart * 16, Kl[cur ^ 1]);
            gld16(VtH + (size_t)vD * (N_TOK * 2) + (size_t)jn * 2 + vP * 16, Vl[cur ^ 1]);
        }
        if (j0 <= i0q + 15) {
            const char* Kb = (const char*)&Ks[cur][0];
            const char* Vb = (const char*)&Vs[cur][0];

            // S^T = K (32keys x 128d) * Q^T : D row=key(quad*4+reg), col=q(lane&15)
            f32x4 s[2];
            s[0] = (f32x4){0.f, 0.f, 0.f, 0.f};
            s[1] = (f32x4){0.f, 0.f, 0.f, 0.f};
#pragma unroll
            for (int mt = 0; mt < 2; ++mt) {
                int key = mt * 16 + l15;
#pragma unroll
                for (int kf = 0; kf < 4; ++kf) {
                    bf16x8 kfr = *(const bf16x8*)(Kb + key * 256 + (((kf * 4 + quad) ^ (key & 15)) * 16));
                    s[mt] = __builtin_amdgcn_mfma_f32_16x16x32_bf16(kfr, qf[kf], s[mt], 0, 0, 0);
                }
            }
            if (j0 + 31 > i0q) {
#pragma unroll
                for (int mt = 0; mt < 2; ++mt) {
                    int keyb = j0 + mt * 16 + quad * 4;
#pragma unroll
                    for (int r = 0; r < 4; ++r)
                        if (keyb + r > q) s[mt][r] = -INFINITY;
                }
            }
            float mx = fmaxf(fmaxf(fmaxf(s[0][0], s[0][1]), fmaxf(s[0][2], s[0][3])),
                             fmaxf(fmaxf(s[1][0], s[1][1]), fmaxf(s[1][2], s[1][3])));
            mx = fmaxf(mx, __shfl_xor(mx, 16));
            mx = fmaxf(mx, __shfl_xor(mx, 32));
            float newm = fmaxf(mstat, mx);
            float alpha = __expf(mstat - newm);
            float p[8];
#pragma unroll
            for (int mt = 0; mt < 2; ++mt)
#pragma unroll
                for (int r = 0; r < 4; ++r) p[mt * 4 + r] = __expf(s[mt][r] - newm);
            float ps = p[0] + p[1] + p[2] + p[3] + p[4] + p[5] + p[6] + p[7];
            ps += __shfl_xor(ps, 16);
            ps += __shfl_xor(ps, 32);
            lstat = lstat * alpha + ps;
            mstat = newm;

            unsigned* pwb = (unsigned*)(&Pw[w][0]);
            int eo = l15 * 20 + quad * 2;   // u32 units
            pwb[eo]     = pack2bf(p[0], p[1]);
            pwb[eo + 1] = pack2bf(p[2], p[3]);
            pwb[eo + 8] = pack2bf(p[4], p[5]);
            pwb[eo + 9] = pack2bf(p[6], p[7]);
            bf16x8 pf = *(const bf16x8*)(&Pw[w][l15 * 40 + quad * 8]);

            float alq[4];
#pragma unroll
            for (int r = 0; r < 4; ++r) alq[r] = __shfl(alpha, quad * 4 + r);
#pragma unroll
            for (int nt = 0; nt < 8; ++nt)
#pragma unroll
                for (int r = 0; r < 4; ++r) o[nt][r] *= alq[r];

#pragma unroll
            for (int nt = 0; nt < 8; ++nt) {
                int d = nt * 16 + l15;
                bf16x8 vf = *(const bf16x8*)(Vb + d * 64 + ((quad ^ (d & 3)) * 16));
                o[nt] = __builtin_amdgcn_mfma_f32_16x16x32_bf16(pf, vf, o[nt], 0, 0, 0);
            }
        }
        // single barrier per step: implicit vmcnt(0) drain covers next-tile loads
        __syncthreads();
    }

    float linv[4];
#pragma unroll
    for (int r = 0; r < 4; ++r) linv[r] = 1.f / __shfl(lstat, quad * 4 + r);
#pragma unroll
    for (int nt = 0; nt < 8; ++nt)
#pragma unroll
        for (int r = 0; r < 4; ++r) {
            int row = i0q + quad * 4 + r;
            int col = h * HD + nt * 16 + l15;
            ao[(size_t)row * H_DIM + col] = f2bf(o[nt][r] * linv[r]);
        }
}

// ---------------- top-2 routing ----------------
__global__ __launch_bounds__(256) void topk_k(const float* __restrict__ elog,
                                              float* __restrict__ w_out,
                                              float* __restrict__ id_out,
                                              int* __restrict__ ids_int) {
    int row = blockIdx.x * 256 + threadIdx.x;
    if (row >= N_TOK) return;
    const float4* e4 = (const float4*)(elog + (size_t)row * NE);
    float4 a = e4[0], b = e4[1];
    float e[8] = {a.x, a.y, a.z, a.w, b.x, b.y, b.z, b.w};
    int id0 = 0;
    float b0 = e[0];
#pragma unroll
    for (int t = 1; t < 8; ++t)
        if (e[t] > b0) { b0 = e[t]; id0 = t; }
    int id1 = -1;
    float b1 = -INFINITY;
#pragma unroll
    for (int t = 0; t < 8; ++t)
        if (t != id0 && e[t] > b1) { b1 = e[t]; id1 = t; }
    float s = b0 + b1;
    w_out[row * 2 + 0] = b0 / s;
    w_out[row * 2 + 1] = b1 / s;
    id_out[row * 2 + 0] = (float)id0;
    id_out[row * 2 + 1] = (float)id1;
    ids_int[row * 2 + 0] = id0;
    ids_int[row * 2 + 1] = id1;
}

// ---------------- stable argsort of 4096 expert ids (counting rank) ----------------
__global__ __launch_bounds__(256) void sort_k(const int* __restrict__ ids,
                                              float* __restrict__ reorder_out,
                                              int* __restrict__ perm) {
    __shared__ int sh[N_TOK * TOPK];
    int tid = threadIdx.x;
    for (int r = tid; r < N_TOK * TOPK; r += 256) sh[r] = ids[r];
    __syncthreads();
    int i = blockIdx.x * 256 + tid;
    int e = sh[i];
    int rank = 0;
    for (int j = 0; j < N_TOK * TOPK; ++j) {
        int ej = sh[j];
        rank += (ej < e) ? 1 : ((ej == e && j < i) ? 1 : 0);
    }
    reorder_out[rank] = (float)i;
    perm[rank] = i;
}

// ---------------- permuted row gather ----------------
__global__ __launch_bounds__(256) void gather_k(const float* __restrict__ src,
                                                const int* __restrict__ perm,
                                                float* __restrict__ dst) {
    int r = blockIdx.x;
    int srow = perm[r] >> 1;  // // TOPK
    const float4* s4 = (const float4*)(src + (size_t)srow * H_DIM);
    float4* d4 = (float4*)(dst + (size_t)r * H_DIM);
    int tid = threadIdx.x;
#pragma unroll
    for (int k = 0; k < 4; ++k) d4[tid + k * 256] = s4[tid + k * 256];
}

extern "C" void kernel_launch(void* const* d_in, const int* in_sizes, int n_in,
                              void* d_out, int out_size, void* d_ws, size_t ws_size,
                              hipStream_t stream) {
    const int*   positions = (const int*)d_in[0];
    const float* hidden    = (const float*)d_in[1];
    const float* w_qkv     = (const float*)d_in[2];
    const float* w_o       = (const float*)d_in[3];
    // d_in[4] = w_gate: dead code in reference
    const float* rms_pre   = (const float*)d_in[5];
    const float* rms_post  = (const float*)d_in[6];
    const float* elog      = (const float*)d_in[7];
    float* out = (float*)d_out;

    char* ws = (char*)d_ws;
    unsigned short* wqkvT = (unsigned short*)(ws);                 // [0, 50.3M) until qkv-gemm
    unsigned short* woT   = (unsigned short*)(ws);                 // [0, 33.5M) conv2..o-gemm
    float*          post  = (float*)(ws + 33554432ULL);            // [33.5M, 67.1M) rms2..gather
    unsigned short* xn    = (unsigned short*)(ws + 50331648ULL);   // [50.3M, 67.1M) rms1..qkv-gemm
    unsigned short* aout  = (unsigned short*)(ws + 50331648ULL);   // [50.3M, 67.1M) attn..o-gemm
    unsigned short* qkvb  = (unsigned short*)(ws + 67108864ULL);   // [67.1M, 92.3M) bf16 qkv
    float*          sbuf  = (float*)(ws + 67108864ULL);            // [67.1M, 100.7M) o-gemm..rms2
    unsigned short* Qc    = (unsigned short*)(ws + 117440512ULL);  // 16 MB
    unsigned short* Kc    = (unsigned short*)(ws + 134217728ULL);  // 4 MB
    unsigned short* Vt    = (unsigned short*)(ws + 138412032ULL);  // 4 MB
    int* ids_int  = (int*)(ws + 142606336ULL);
    int* perm_int = (int*)(ws + 142622720ULL);

    // 1. w_qkv -> bf16 transposed [6144][4096]
    convT_k<<<dim3(QKV_D / 64, H_DIM / 64), 256, 0, stream>>>(w_qkv, wqkvT, H_DIM, QKV_D);
    // 2. pre-attention RMSNorm -> bf16
    rmsnorm_k<<<N_TOK, 256, 0, stream>>>(hidden, rms_pre, nullptr, xn);
    // 3. QKV projection (bf16 MFMA) -> bf16 qkv
    gemm_k<<<dim3(N_TOK / 128, QKV_D / 128), 256, 0, stream>>>(
        (const __hip_bfloat16*)xn, (const __hip_bfloat16*)wqkvT, nullptr, qkvb, nullptr, QKV_D);
    // 4. w_o -> bf16 transposed [4096][4096]  (reuses wqkvT region)
    convT_k<<<dim3(H_DIM / 64, H_DIM / 64), 256, 0, stream>>>(w_o, woT, H_DIM, H_DIM);
    // 5. RoPE + pack Qc/Kc bf16
    prep_k<<<N_TOK, 256, 0, stream>>>(qkvb, positions, Qc, Kc);
    // 6. V transpose -> Vt bf16
    vt_k<<<dim3(N_TOK / 64, NKV), 256, 0, stream>>>(qkvb, Vt);
    // 7. causal GQA flash attention (bf16 MFMA) -> bf16 attn_out
    //    512 threads: 64 q-rows x 2 heads per block, double-buffered K/V
    attn_k<<<dim3(N_TOK / 64, 16), 512, 0, stream>>>(
        (const __hip_bfloat16*)Qc, (const __hip_bfloat16*)Kc, (const __hip_bfloat16*)Vt, aout);
    // 8. output projection + residual (bf16 MFMA) -> fp32 s
    gemm_k<<<dim3(N_TOK / 128, H_DIM / 128), 256, 0, stream>>>(
        (const __hip_bfloat16*)aout, (const __hip_bfloat16*)woT, sbuf, nullptr, hidden, H_DIM);
    // 9. post-attention RMSNorm -> fp32
    rmsnorm_k<<<N_TOK, 256, 0, stream>>>(sbuf, rms_post, post, nullptr);
    // 10. top-2 experts
    topk_k<<<N_TOK / 256, 256, 0, stream>>>(elog, out + OUT_W, out + OUT_IDS, ids_int);
    // 11. stable argsort of expert ids
    sort_k<<<(N_TOK * TOPK) / 256, 256, 0, stream>>>(ids_int, out + OUT_REO, perm_int);
    // 12. permuted gather
    gather_k<<<N_TOK * TOPK, 256, 0, stream>>>(post, perm_int, out + OUT_PERM);
}

// Round 4
// 735.255 us; speedup vs baseline: 1.1008x; 1.1008x over previous
//
#include <hip/hip_runtime.h>
#include <hip/hip_bf16.h>
#include <math.h>

// Problem constants
#define N_TOK 2048
#define H_DIM 4096
#define NH 32
#define NKV 8
#define HD 128
#define QKV_D 6144   // (NH + 2*NKV) * HD
#define NE 8
#define TOPK 2

// d_out layout (floats): permuted_output | topk_weights | topk_ids | reorder_ids
#define OUT_PERM 0
#define OUT_W    16777216   // 4096*4096
#define OUT_IDS  16781312
#define OUT_REO  16785408

typedef __bf16 bf16x8 __attribute__((ext_vector_type(8)));
typedef float f32x4 __attribute__((ext_vector_type(4)));

typedef __attribute__((address_space(3))) void lds_void;
typedef __attribute__((address_space(1))) const void gbl_void;

__device__ __forceinline__ void gld16(const void* g, void* l) {
    // async global->LDS, 16B per lane; LDS dest = wave-uniform base + lane*16
    __builtin_amdgcn_global_load_lds((gbl_void*)g, (lds_void*)l, 16, 0, 0);
}

__device__ __forceinline__ unsigned short f2bf(float f) {
    union { float f; unsigned u; } v; v.f = f;
    unsigned r = v.u + 0x7fff + ((v.u >> 16) & 1);
    return (unsigned short)(r >> 16);
}
__device__ __forceinline__ unsigned pack2bf(float a, float b) {
    return (unsigned)f2bf(a) | ((unsigned)f2bf(b) << 16);
}
__device__ __forceinline__ float bf2f(unsigned short u) {
    union { unsigned u; float f; } v; v.u = ((unsigned)u) << 16;
    return v.f;
}

// ---------------- RMSNorm (fp32 in; fp32 or bf16 out) ----------------
__global__ __launch_bounds__(256) void rmsnorm_k(const float* __restrict__ x,
                                                 const float* __restrict__ w,
                                                 float* __restrict__ yf,
                                                 unsigned short* __restrict__ yb) {
    int row = blockIdx.x;
    int tid = threadIdx.x;
    const float4* x4 = (const float4*)(x + (size_t)row * H_DIM);
    const float4* w4 = (const float4*)w;
    float4 v[4];
    float ss = 0.f;
#pragma unroll
    for (int k = 0; k < 4; ++k) {
        v[k] = x4[tid + k * 256];
        ss += v[k].x * v[k].x + v[k].y * v[k].y + v[k].z * v[k].z + v[k].w * v[k].w;
    }
#pragma unroll
    for (int off = 32; off; off >>= 1) ss += __shfl_xor(ss, off);
    __shared__ float sacc[4];
    if ((tid & 63) == 0) sacc[tid >> 6] = ss;
    __syncthreads();
    float tot = sacc[0] + sacc[1] + sacc[2] + sacc[3];
    float sc = rsqrtf(tot * (1.0f / H_DIM) + 1e-6f);
#pragma unroll
    for (int k = 0; k < 4; ++k) {
        float4 ww = w4[tid + k * 256];
        float4 o;
        o.x = v[k].x * sc * ww.x;
        o.y = v[k].y * sc * ww.y;
        o.z = v[k].z * sc * ww.z;
        o.w = v[k].w * sc * ww.w;
        if (yf) {
            *(float4*)(yf + (size_t)row * H_DIM + (tid + k * 256) * 4) = o;
        } else {
            uint2 p;
            p.x = pack2bf(o.x, o.y);
            p.y = pack2bf(o.z, o.w);
            *(uint2*)(yb + (size_t)row * H_DIM + (tid + k * 256) * 4) = p;
        }
    }
}

// ---------------- transpose + fp32->bf16 weight conversion ----------------
// src[R][C] fp32 -> dst[C][R] bf16 (64x64 tiles)
__global__ __launch_bounds__(256) void convT_k(const float* __restrict__ src,
                                               unsigned short* __restrict__ dst,
                                               int R, int C) {
    __shared__ float t[64][68];
    int r0 = blockIdx.y * 64, c0 = blockIdx.x * 64;
    int tid = threadIdx.x;
    int lr = tid >> 4, lc = tid & 15;
#pragma unroll
    for (int it = 0; it < 4; ++it) {
        int r = lr + it * 16;
        float4 v = *(const float4*)(src + (size_t)(r0 + r) * C + c0 + lc * 4);
        *(float4*)&t[r][lc * 4] = v;
    }
    __syncthreads();
#pragma unroll
    for (int it = 0; it < 4; ++it) {
        int cc = lr + it * 16;
        uint2 o;
        o.x = pack2bf(t[lc * 4 + 0][cc], t[lc * 4 + 1][cc]);
        o.y = pack2bf(t[lc * 4 + 2][cc], t[lc * 4 + 3][cc]);
        *(uint2*)(dst + (size_t)(c0 + cc) * R + r0 + lc * 4) = o;
    }
}

// ---------------- bf16 MFMA GEMM: C[M x Nc] = A[M x 4096] @ Bt[Nc x 4096]^T ----
// 128x128 tile, BK=64, 4 waves each 64x64, 16x16x32 MFMA.
// T3+T4: double-buffered LDS, next-tile global_load_lds issued before compute,
// COUNTED s_waitcnt vmcnt(8) + raw s_barrier (no vmcnt(0) drain at barriers —
// the 8 just-issued loads stay in flight across the barrier).
// T1 bijective XCD swizzle (nwg % 8 == 0 for both call sites).
// LDS linear for global_load_lds; XOR swizzle on pre-swizzled GLOBAL source,
// mirrored on the ds_read side (rule #21).
// Output: bf16 (Cb) or fp32 + residual (C).
__global__ __launch_bounds__(256) void gemm_k(const __hip_bfloat16* __restrict__ A,
                                              const __hip_bfloat16* __restrict__ Bt,
                                              float* __restrict__ C,
                                              unsigned short* __restrict__ Cb,
                                              const float* __restrict__ residual,
                                              int Ncols) {
    __shared__ __align__(16) __hip_bfloat16 As[2][128 * 64];  // 2 x 16 KB
    __shared__ __align__(16) __hip_bfloat16 Bs[2][128 * 64];  // 2 x 16 KB
    const int K = H_DIM;
    int tid = threadIdx.x, w = tid >> 6, lane = tid & 63;
    int quad = lane >> 4, l15 = lane & 15;

    // XCD-aware bijective block swizzle: each XCD gets a contiguous chunk of
    // linear block ids -> contiguous n-panels stay in one XCD's L2.
    int gx = gridDim.x;
    int nwg = gx * gridDim.y;
    int v = blockIdx.y * gx + blockIdx.x;           // hw dispatch order (xcd ~ v%8)
    int lin = (v & 7) * (nwg >> 3) + (v >> 3);
    int m0 = (lin % gx) * 128, n0 = (lin / gx) * 128;
    int wm = (w & 1) * 64, wn = (w >> 1) * 64;

    // staging: 16 chunks of 8 rows (1024B) each for A and B; wave w owns chunks 4w..4w+3
    int rowInChunk = lane >> 3;   // 0..7
    int uIdx = lane & 7;          // 16B unit within 128B row
    const char* Ag[4]; const char* Bg[4];
    int chOff[4];
#pragma unroll
    for (int c = 0; c < 4; ++c) {
        int ch = w * 4 + c;
        int r = ch * 8 + rowInChunk;
        int gu = uIdx ^ (r & 7);   // pre-swizzled global source unit
        Ag[c] = (const char*)(A + (size_t)(m0 + r) * K) + gu * 16;
        Bg[c] = (const char*)(Bt + (size_t)(n0 + r) * K) + gu * 16;
        chOff[c] = ch * 1024;
    }

    f32x4 acc[4][4];
#pragma unroll
    for (int i = 0; i < 4; ++i)
#pragma unroll
        for (int j = 0; j < 4; ++j) acc[i][j] = (f32x4){0.f, 0.f, 0.f, 0.f};

    const int nsteps = K / 64;

    // prologue: stage step 0 into buf 0 (8 loads in flight)
#pragma unroll
    for (int c = 0; c < 4; ++c) gld16(Ag[c], (char*)&As[0][0] + chOff[c]);
#pragma unroll
    for (int c = 0; c < 4; ++c) gld16(Bg[c], (char*)&Bs[0][0] + chOff[c]);

    for (int t = 0; t < nsteps; ++t) {
        int cur = t & 1;
        if (t + 1 < nsteps) {   // issue next K-tile loads (stay in flight across barrier)
            size_t kb = (size_t)(t + 1) * 128;   // bytes along K
            char* dA = (char*)&As[cur ^ 1][0];
            char* dB = (char*)&Bs[cur ^ 1][0];
#pragma unroll
            for (int c = 0; c < 4; ++c) gld16(Ag[c] + kb, dA + chOff[c]);
#pragma unroll
            for (int c = 0; c < 4; ++c) gld16(Bg[c] + kb, dB + chOff[c]);
            // wait only for step t's 8 loads (leave the 8 new ones in flight)
            asm volatile("s_waitcnt vmcnt(8)" ::: "memory");
        } else {
            asm volatile("s_waitcnt vmcnt(0)" ::: "memory");
        }
        __builtin_amdgcn_sched_barrier(0);
        __builtin_amdgcn_s_barrier();          // A: all waves' step-t data in LDS
        __builtin_amdgcn_sched_barrier(0);

        const char* sA = (const char*)&As[cur][0];
        const char* sB = (const char*)&Bs[cur][0];
#pragma unroll
        for (int kk = 0; kk < 2; ++kk) {
            bf16x8 af[4], bfr[4];
#pragma unroll
            for (int mt = 0; mt < 4; ++mt) {
                int m = wm + mt * 16 + l15;
                af[mt] = *(const bf16x8*)(sA + m * 128 + (((kk * 4 + quad) ^ (m & 7)) * 16));
            }
#pragma unroll
            for (int nt = 0; nt < 4; ++nt) {
                int n = wn + nt * 16 + l15;
                bfr[nt] = *(const bf16x8*)(sB + n * 128 + (((kk * 4 + quad) ^ (n & 7)) * 16));
            }
#pragma unroll
            for (int mt = 0; mt < 4; ++mt)
#pragma unroll
                for (int nt = 0; nt < 4; ++nt)
                    acc[mt][nt] = __builtin_amdgcn_mfma_f32_16x16x32_bf16(af[mt], bfr[nt], acc[mt][nt], 0, 0, 0);
        }
        __builtin_amdgcn_sched_barrier(0);
        __builtin_amdgcn_s_barrier();          // B: buf[cur] free for reuse at t+2
        __builtin_amdgcn_sched_barrier(0);
    }
    // epilogue: C/D layout col=lane&15, row=quad*4+reg
#pragma unroll
    for (int mt = 0; mt < 4; ++mt)
#pragma unroll
        for (int nt = 0; nt < 4; ++nt)
#pragma unroll
            for (int r = 0; r < 4; ++r) {
                int row = m0 + wm + mt * 16 + quad * 4 + r;
                int col = n0 + wn + nt * 16 + l15;
                size_t off = (size_t)row * Ncols + col;
                float vv = acc[mt][nt][r];
                if (Cb) {
                    Cb[off] = f2bf(vv);
                } else {
                    if (residual) vv += residual[off];
                    C[off] = vv;
                }
            }
}

// ---------------- prep: RoPE + pack Qc (scaled bf16) and Kc (bf16, per-head rows) ----
// reads bf16 qkv
__global__ __launch_bounds__(256) void prep_k(const unsigned short* __restrict__ qkvb,
                                              const int* __restrict__ pos,
                                              unsigned short* __restrict__ Qc,
                                              unsigned short* __restrict__ Kc) {
    int row = blockIdx.x, tid = threadIdx.x;
    float fpos = (float)pos[row];
    const float scale = 0.08838834764831845f;  // 1/sqrt(128)
    const float lg = 0.20762050593045f;        // log2(10000)/64
#pragma unroll
    for (int it = 0; it < 8; ++it) {
        int pi = tid + it * 256;        // 0..2047 : q pairs
        int head = pi >> 6, t = pi & 63;
        float inv = exp2f(-(float)t * lg);
        float ang = fpos * inv;
        float s = __sinf(ang), c = __cosf(ang);
        const unsigned short* bp = qkvb + (size_t)row * QKV_D + head * HD + t;
        float x1 = bf2f(bp[0]), x2 = bf2f(bp[64]);
        unsigned short* qb = Qc + (size_t)row * H_DIM + head * HD + t;
        qb[0]  = f2bf((x1 * c - x2 * s) * scale);
        qb[64] = f2bf((x2 * c + x1 * s) * scale);
    }
#pragma unroll
    for (int it = 0; it < 2; ++it) {
        int pi = tid + it * 256;        // 0..511 : k pairs
        int kvh = pi >> 6, t = pi & 63;
        float inv = exp2f(-(float)t * lg);
        float ang = fpos * inv;
        float s = __sinf(ang), c = __cosf(ang);
        const unsigned short* bp = qkvb + (size_t)row * QKV_D + H_DIM + kvh * HD + t;
        float x1 = bf2f(bp[0]), x2 = bf2f(bp[64]);
        unsigned short* kb = Kc + ((size_t)kvh * N_TOK + row) * HD + t;
        kb[0]  = f2bf(x1 * c - x2 * s);
        kb[64] = f2bf(x2 * c + x1 * s);
    }
}

// ---------------- V transpose: bf16 qkv V section -> Vt[kvh][d][key] ----------------
__global__ __launch_bounds__(256) void vt_k(const unsigned short* __restrict__ qkvb,
                                            unsigned short* __restrict__ Vt) {
    __shared__ unsigned short ts[64][136];
    int j0 = blockIdx.x * 64, kvh = blockIdx.y, tid = threadIdx.x;
#pragma unroll
    for (int it = 0; it < 4; ++it) {
        int idx = tid + it * 256;   // 16B slots of 64x128 ushort tile
        int r = idx >> 4, c8 = idx & 15;
        *(uint4*)&ts[r][c8 * 8] =
            *(const uint4*)(qkvb + (size_t)(j0 + r) * QKV_D + (NH + NKV) * HD + kvh * HD + c8 * 8);
    }
    __syncthreads();
    int d = tid >> 1, half = tid & 1;
    unsigned short* dst = Vt + ((size_t)kvh * HD + d) * N_TOK + j0 + half * 32;
#pragma unroll
    for (int g = 0; g < 4; ++g) {
        int kb = half * 32 + g * 8;
        uint4 o;
        o.x = (unsigned)ts[kb + 0][d] | ((unsigned)ts[kb + 1][d] << 16);
        o.y = (unsigned)ts[kb + 2][d] | ((unsigned)ts[kb + 3][d] << 16);
        o.z = (unsigned)ts[kb + 4][d] | ((unsigned)ts[kb + 5][d] << 16);
        o.w = (unsigned)ts[kb + 6][d] | ((unsigned)ts[kb + 7][d] << 16);
        *(uint4*)(dst + g * 8) = o;
    }
}

// ---------------- bf16 MFMA flash attention ----------------
// block = 512 threads / 8 waves: 64 q-rows x 2 heads (same kv-head group).
// Wave w: head = base + (w&1), q-rows i0 + (w>>1)*16.
// K/V double-buffered in LDS, T3 2-phase pipeline: issue next-tile
// global_load_lds BEFORE compute, single __syncthreads (with its implicit
// vmcnt drain) per 32-key step.
__global__ __launch_bounds__(512) void attn_k(const __hip_bfloat16* __restrict__ Qc,
                                              const __hip_bfloat16* __restrict__ Kc,
                                              const __hip_bfloat16* __restrict__ Vt,
                                              unsigned short* __restrict__ ao) {
    __shared__ __align__(16) __hip_bfloat16 Ks[2][32 * 128];   // [key][d], swizzled 16B units, 8KB/buf
    __shared__ __align__(16) __hip_bfloat16 Vs[2][128 * 32];   // [d][key], swizzled 16B units, 8KB/buf
    __shared__ __align__(16) unsigned short Pw[8][16 * 40];    // per-wave P, row stride 80B

    int tid = threadIdx.x, w = tid >> 6, lane = tid & 63;
    int quad = lane >> 4, l15 = lane & 15;
    int pr = blockIdx.y;                 // 0..15: (kvh, head-pair)
    int kvh = pr >> 1;
    int h = kvh * 4 + (pr & 1) * 2 + (w & 1);
    int qt = gridDim.x - 1 - blockIdx.x; // heavy tiles first
    int i0 = qt * 64;
    int i0q = i0 + (w >> 1) * 16;
    int q = i0q + l15;

    bf16x8 qf[4];
    const __hip_bfloat16* qrow = Qc + (size_t)q * H_DIM + h * HD;
#pragma unroll
    for (int kf = 0; kf < 4; ++kf)
        qf[kf] = *(const bf16x8*)(qrow + kf * 32 + quad * 8);

    const char* KcH = (const char*)(Kc + (size_t)kvh * N_TOK * HD);
    const char* VtH = (const char*)(Vt + (size_t)kvh * HD * N_TOK);

    // staging: wave w stages K chunk w (keys 4w..4w+3) and V chunk w (d 16w..16w+15)
    int kKey = w * 4 + (lane >> 4);                 // key row within 32-key tile
    int kPart = (lane & 15) ^ (kKey & 15);          // pre-swizzled global 16B unit
    int vD = w * 16 + (lane >> 2);                  // d row
    int vP = (lane & 3) ^ (vD & 3);
    char* Kl[2] = { (char*)&Ks[0][0] + w * 1024, (char*)&Ks[1][0] + w * 1024 };
    char* Vl[2] = { (char*)&Vs[0][0] + w * 1024, (char*)&Vs[1][0] + w * 1024 };

    float mstat = -INFINITY, lstat = 0.f;
    f32x4 o[8];
#pragma unroll
    for (int nt = 0; nt < 8; ++nt) o[nt] = (f32x4){0.f, 0.f, 0.f, 0.f};

    int nsteps = (i0 + 64) >> 5;

    // prologue: stage step 0 into buf 0; __syncthreads drains vmcnt(0) for all waves
    gld16(KcH + (size_t)kKey * 256 + kPart * 16, Kl[0]);
    gld16(VtH + (size_t)vD * (N_TOK * 2) + vP * 16, Vl[0]);
    __syncthreads();

    for (int t = 0; t < nsteps; ++t) {
        int j0 = t << 5;
        int cur = t & 1;
        if (t + 1 < nsteps) {   // issue next tile's loads (hidden under compute)
            int jn = j0 + 32;
            gld16(KcH + (size_t)(jn + kKey) * 256 + kPart * 16, Kl[cur ^ 1]);
            gld16(VtH + (size_t)vD * (N_TOK * 2) + (size_t)jn * 2 + vP * 16, Vl[cur ^ 1]);
        }
        if (j0 <= i0q + 15) {
            const char* Kb = (const char*)&Ks[cur][0];
            const char* Vb = (const char*)&Vs[cur][0];

            // S^T = K (32keys x 128d) * Q^T : D row=key(quad*4+reg), col=q(lane&15)
            f32x4 s[2];
            s[0] = (f32x4){0.f, 0.f, 0.f, 0.f};
            s[1] = (f32x4){0.f, 0.f, 0.f, 0.f};
#pragma unroll
            for (int mt = 0; mt < 2; ++mt) {
                int key = mt * 16 + l15;
#pragma unroll
                for (int kf = 0; kf < 4; ++kf) {
                    bf16x8 kfr = *(const bf16x8*)(Kb + key * 256 + (((kf * 4 + quad) ^ (key & 15)) * 16));
                    s[mt] = __builtin_amdgcn_mfma_f32_16x16x32_bf16(kfr, qf[kf], s[mt], 0, 0, 0);
                }
            }
            if (j0 + 31 > i0q) {
#pragma unroll
                for (int mt = 0; mt < 2; ++mt) {
                    int keyb = j0 + mt * 16 + quad * 4;
#pragma unroll
                    for (int r = 0; r < 4; ++r)
                        if (keyb + r > q) s[mt][r] = -INFINITY;
                }
            }
            float mx = fmaxf(fmaxf(fmaxf(s[0][0], s[0][1]), fmaxf(s[0][2], s[0][3])),
                             fmaxf(fmaxf(s[1][0], s[1][1]), fmaxf(s[1][2], s[1][3])));
            mx = fmaxf(mx, __shfl_xor(mx, 16));
            mx = fmaxf(mx, __shfl_xor(mx, 32));
            float newm = fmaxf(mstat, mx);
            float alpha = __expf(mstat - newm);
            float p[8];
#pragma unroll
            for (int mt = 0; mt < 2; ++mt)
#pragma unroll
                for (int r = 0; r < 4; ++r) p[mt * 4 + r] = __expf(s[mt][r] - newm);
            float ps = p[0] + p[1] + p[2] + p[3] + p[4] + p[5] + p[6] + p[7];
            ps += __shfl_xor(ps, 16);
            ps += __shfl_xor(ps, 32);
            lstat = lstat * alpha + ps;
            mstat = newm;

            unsigned* pwb = (unsigned*)(&Pw[w][0]);
            int eo = l15 * 20 + quad * 2;   // u32 units
            pwb[eo]     = pack2bf(p[0], p[1]);
            pwb[eo + 1] = pack2bf(p[2], p[3]);
            pwb[eo + 8] = pack2bf(p[4], p[5]);
            pwb[eo + 9] = pack2bf(p[6], p[7]);
            bf16x8 pf = *(const bf16x8*)(&Pw[w][l15 * 40 + quad * 8]);

            float alq[4];
#pragma unroll
            for (int r = 0; r < 4; ++r) alq[r] = __shfl(alpha, quad * 4 + r);
#pragma unroll
            for (int nt = 0; nt < 8; ++nt)
#pragma unroll
                for (int r = 0; r < 4; ++r) o[nt][r] *= alq[r];

#pragma unroll
            for (int nt = 0; nt < 8; ++nt) {
                int d = nt * 16 + l15;
                bf16x8 vf = *(const bf16x8*)(Vb + d * 64 + ((quad ^ (d & 3)) * 16));
                o[nt] = __builtin_amdgcn_mfma_f32_16x16x32_bf16(pf, vf, o[nt], 0, 0, 0);
            }
        }
        // single barrier per step: implicit vmcnt(0) drain covers next-tile loads
        __syncthreads();
    }

    float linv[4];
#pragma unroll
    for (int r = 0; r < 4; ++r) linv[r] = 1.f / __shfl(lstat, quad * 4 + r);
#pragma unroll
    for (int nt = 0; nt < 8; ++nt)
#pragma unroll
        for (int r = 0; r < 4; ++r) {
            int row = i0q + quad * 4 + r;
            int col = h * HD + nt * 16 + l15;
            ao[(size_t)row * H_DIM + col] = f2bf(o[nt][r] * linv[r]);
        }
}

// ---------------- top-2 routing ----------------
__global__ __launch_bounds__(256) void topk_k(const float* __restrict__ elog,
                                              float* __restrict__ w_out,
                                              float* __restrict__ id_out,
                                              int* __restrict__ ids_int) {
    int row = blockIdx.x * 256 + threadIdx.x;
    if (row >= N_TOK) return;
    const float4* e4 = (const float4*)(elog + (size_t)row * NE);
    float4 a = e4[0], b = e4[1];
    float e[8] = {a.x, a.y, a.z, a.w, b.x, b.y, b.z, b.w};
    int id0 = 0;
    float b0 = e[0];
#pragma unroll
    for (int t = 1; t < 8; ++t)
        if (e[t] > b0) { b0 = e[t]; id0 = t; }
    int id1 = -1;
    float b1 = -INFINITY;
#pragma unroll
    for (int t = 0; t < 8; ++t)
        if (t != id0 && e[t] > b1) { b1 = e[t]; id1 = t; }
    float s = b0 + b1;
    w_out[row * 2 + 0] = b0 / s;
    w_out[row * 2 + 1] = b1 / s;
    id_out[row * 2 + 0] = (float)id0;
    id_out[row * 2 + 1] = (float)id1;
    ids_int[row * 2 + 0] = id0;
    ids_int[row * 2 + 1] = id1;
}

// ---------------- stable argsort of 4096 expert ids (counting rank) ----------------
__global__ __launch_bounds__(256) void sort_k(const int* __restrict__ ids,
                                              float* __restrict__ reorder_out,
                                              int* __restrict__ perm) {
    __shared__ int sh[N_TOK * TOPK];
    int tid = threadIdx.x;
    for (int r = tid; r < N_TOK * TOPK; r += 256) sh[r] = ids[r];
    __syncthreads();
    int i = blockIdx.x * 256 + tid;
    int e = sh[i];
    int rank = 0;
    for (int j = 0; j < N_TOK * TOPK; ++j) {
        int ej = sh[j];
        rank += (ej < e) ? 1 : ((ej == e && j < i) ? 1 : 0);
    }
    reorder_out[rank] = (float)i;
    perm[rank] = i;
}

// ---------------- permuted row gather ----------------
__global__ __launch_bounds__(256) void gather_k(const float* __restrict__ src,
                                                const int* __restrict__ perm,
                                                float* __restrict__ dst) {
    int r = blockIdx.x;
    int srow = perm[r] >> 1;  // // TOPK
    const float4* s4 = (const float4*)(src + (size_t)srow * H_DIM);
    float4* d4 = (float4*)(dst + (size_t)r * H_DIM);
    int tid = threadIdx.x;
#pragma unroll
    for (int k = 0; k < 4; ++k) d4[tid + k * 256] = s4[tid + k * 256];
}

extern "C" void kernel_launch(void* const* d_in, const int* in_sizes, int n_in,
                              void* d_out, int out_size, void* d_ws, size_t ws_size,
                              hipStream_t stream) {
    const int*   positions = (const int*)d_in[0];
    const float* hidden    = (const float*)d_in[1];
    const float* w_qkv     = (const float*)d_in[2];
    const float* w_o       = (const float*)d_in[3];
    // d_in[4] = w_gate: dead code in reference
    const float* rms_pre   = (const float*)d_in[5];
    const float* rms_post  = (const float*)d_in[6];
    const float* elog      = (const float*)d_in[7];
    float* out = (float*)d_out;

    char* ws = (char*)d_ws;
    unsigned short* wqkvT = (unsigned short*)(ws);                 // [0, 50.3M) until qkv-gemm
    unsigned short* woT   = (unsigned short*)(ws);                 // [0, 33.5M) conv2..o-gemm
    float*          post  = (float*)(ws + 33554432ULL);            // [33.5M, 67.1M) rms2..gather
    unsigned short* xn    = (unsigned short*)(ws + 50331648ULL);   // [50.3M, 67.1M) rms1..qkv-gemm
    unsigned short* aout  = (unsigned short*)(ws + 50331648ULL);   // [50.3M, 67.1M) attn..o-gemm
    unsigned short* qkvb  = (unsigned short*)(ws + 67108864ULL);   // [67.1M, 92.3M) bf16 qkv
    float*          sbuf  = (float*)(ws + 67108864ULL);            // [67.1M, 100.7M) o-gemm..rms2
    unsigned short* Qc    = (unsigned short*)(ws + 117440512ULL);  // 16 MB
    unsigned short* Kc    = (unsigned short*)(ws + 134217728ULL);  // 4 MB
    unsigned short* Vt    = (unsigned short*)(ws + 138412032ULL);  // 4 MB
    int* ids_int  = (int*)(ws + 142606336ULL);
    int* perm_int = (int*)(ws + 142622720ULL);

    // 1. w_qkv -> bf16 transposed [6144][4096]
    convT_k<<<dim3(QKV_D / 64, H_DIM / 64), 256, 0, stream>>>(w_qkv, wqkvT, H_DIM, QKV_D);
    // 2. pre-attention RMSNorm -> bf16
    rmsnorm_k<<<N_TOK, 256, 0, stream>>>(hidden, rms_pre, nullptr, xn);
    // 3. QKV projection (bf16 MFMA) -> bf16 qkv
    gemm_k<<<dim3(N_TOK / 128, QKV_D / 128), 256, 0, stream>>>(
        (const __hip_bfloat16*)xn, (const __hip_bfloat16*)wqkvT, nullptr, qkvb, nullptr, QKV_D);
    // 4. w_o -> bf16 transposed [4096][4096]  (reuses wqkvT region)
    convT_k<<<dim3(H_DIM / 64, H_DIM / 64), 256, 0, stream>>>(w_o, woT, H_DIM, H_DIM);
    // 5. RoPE + pack Qc/Kc bf16
    prep_k<<<N_TOK, 256, 0, stream>>>(qkvb, positions, Qc, Kc);
    // 6. V transpose -> Vt bf16
    vt_k<<<dim3(N_TOK / 64, NKV), 256, 0, stream>>>(qkvb, Vt);
    // 7. causal GQA flash attention (bf16 MFMA) -> bf16 attn_out
    //    512 threads: 64 q-rows x 2 heads per block, double-buffered K/V
    attn_k<<<dim3(N_TOK / 64, 16), 512, 0, stream>>>(
        (const __hip_bfloat16*)Qc, (const __hip_bfloat16*)Kc, (const __hip_bfloat16*)Vt, aout);
    // 8. output projection + residual (bf16 MFMA) -> fp32 s
    gemm_k<<<dim3(N_TOK / 128, H_DIM / 128), 256, 0, stream>>>(
        (const __hip_bfloat16*)aout, (const __hip_bfloat16*)woT, sbuf, nullptr, hidden, H_DIM);
    // 9. post-attention RMSNorm -> fp32
    rmsnorm_k<<<N_TOK, 256, 0, stream>>>(sbuf, rms_post, post, nullptr);
    // 10. top-2 experts
    topk_k<<<N_TOK / 256, 256, 0, stream>>>(elog, out + OUT_W, out + OUT_IDS, ids_int);
    // 11. stable argsort of expert ids
    sort_k<<<(N_TOK * TOPK) / 256, 256, 0, stream>>>(ids_int, out + OUT_REO, perm_int);
    // 12. permuted gather
    gather_k<<<N_TOK * TOPK, 256, 0, stream>>>(post, perm_int, out + OUT_PERM);
}

// Round 5
// 717.306 us; speedup vs baseline: 1.1284x; 1.0250x over previous
//
#include <hip/hip_runtime.h>
#include <hip/hip_bf16.h>
#include <math.h>

// Problem constants
#define N_TOK 2048
#define H_DIM 4096
#define NH 32
#define NKV 8
#define HD 128
#define QKV_D 6144   // (NH + 2*NKV) * HD
#define NE 8
#define TOPK 2

// d_out layout (floats): permuted_output | topk_weights | topk_ids | reorder_ids
#define OUT_PERM 0
#define OUT_W    16777216   // 4096*4096
#define OUT_IDS  16781312
#define OUT_REO  16785408

typedef __bf16 bf16x8 __attribute__((ext_vector_type(8)));
typedef float f32x4 __attribute__((ext_vector_type(4)));

typedef __attribute__((address_space(3))) void lds_void;
typedef __attribute__((address_space(1))) const void gbl_void;

__device__ __forceinline__ void gld16(const void* g, void* l) {
    // async global->LDS, 16B per lane; LDS dest = wave-uniform base + lane*16
    __builtin_amdgcn_global_load_lds((gbl_void*)g, (lds_void*)l, 16, 0, 0);
}

__device__ __forceinline__ unsigned short f2bf(float f) {
    union { float f; unsigned u; } v; v.f = f;
    unsigned r = v.u + 0x7fff + ((v.u >> 16) & 1);
    return (unsigned short)(r >> 16);
}
__device__ __forceinline__ unsigned pack2bf(float a, float b) {
    return (unsigned)f2bf(a) | ((unsigned)f2bf(b) << 16);
}
__device__ __forceinline__ float bf2f(unsigned short u) {
    union { unsigned u; float f; } v; v.u = ((unsigned)u) << 16;
    return v.f;
}

// ---------------- RMSNorm (fp32 in; fp32 or bf16 out) ----------------
__global__ __launch_bounds__(256) void rmsnorm_k(const float* __restrict__ x,
                                                 const float* __restrict__ w,
                                                 float* __restrict__ yf,
                                                 unsigned short* __restrict__ yb) {
    int row = blockIdx.x;
    int tid = threadIdx.x;
    const float4* x4 = (const float4*)(x + (size_t)row * H_DIM);
    const float4* w4 = (const float4*)w;
    float4 v[4];
    float ss = 0.f;
#pragma unroll
    for (int k = 0; k < 4; ++k) {
        v[k] = x4[tid + k * 256];
        ss += v[k].x * v[k].x + v[k].y * v[k].y + v[k].z * v[k].z + v[k].w * v[k].w;
    }
#pragma unroll
    for (int off = 32; off; off >>= 1) ss += __shfl_xor(ss, off);
    __shared__ float sacc[4];
    if ((tid & 63) == 0) sacc[tid >> 6] = ss;
    __syncthreads();
    float tot = sacc[0] + sacc[1] + sacc[2] + sacc[3];
    float sc = rsqrtf(tot * (1.0f / H_DIM) + 1e-6f);
#pragma unroll
    for (int k = 0; k < 4; ++k) {
        float4 ww = w4[tid + k * 256];
        float4 o;
        o.x = v[k].x * sc * ww.x;
        o.y = v[k].y * sc * ww.y;
        o.z = v[k].z * sc * ww.z;
        o.w = v[k].w * sc * ww.w;
        if (yf) {
            *(float4*)(yf + (size_t)row * H_DIM + (tid + k * 256) * 4) = o;
        } else {
            uint2 p;
            p.x = pack2bf(o.x, o.y);
            p.y = pack2bf(o.z, o.w);
            *(uint2*)(yb + (size_t)row * H_DIM + (tid + k * 256) * 4) = p;
        }
    }
}

// ---------------- transpose + fp32->bf16 weight conversion ----------------
// src[R][C] fp32 -> dst[C][R] bf16 (64x64 tiles)
__global__ __launch_bounds__(256) void convT_k(const float* __restrict__ src,
                                               unsigned short* __restrict__ dst,
                                               int R, int C) {
    __shared__ float t[64][68];
    int r0 = blockIdx.y * 64, c0 = blockIdx.x * 64;
    int tid = threadIdx.x;
    int lr = tid >> 4, lc = tid & 15;
#pragma unroll
    for (int it = 0; it < 4; ++it) {
        int r = lr + it * 16;
        float4 v = *(const float4*)(src + (size_t)(r0 + r) * C + c0 + lc * 4);
        *(float4*)&t[r][lc * 4] = v;
    }
    __syncthreads();
#pragma unroll
    for (int it = 0; it < 4; ++it) {
        int cc = lr + it * 16;
        uint2 o;
        o.x = pack2bf(t[lc * 4 + 0][cc], t[lc * 4 + 1][cc]);
        o.y = pack2bf(t[lc * 4 + 2][cc], t[lc * 4 + 3][cc]);
        *(uint2*)(dst + (size_t)(c0 + cc) * R + r0 + lc * 4) = o;
    }
}

// ---------------- 2-phase bf16 MFMA GEMM (kept for O-projection) ----------------
// 128x128 tile, BK=64, 4 waves each 64x64, counted vmcnt(8) + raw s_barrier.
__global__ __launch_bounds__(256) void gemm_k(const __hip_bfloat16* __restrict__ A,
                                              const __hip_bfloat16* __restrict__ Bt,
                                              float* __restrict__ C,
                                              unsigned short* __restrict__ Cb,
                                              const float* __restrict__ residual,
                                              int Ncols) {
    __shared__ __align__(16) __hip_bfloat16 As[2][128 * 64];  // 2 x 16 KB
    __shared__ __align__(16) __hip_bfloat16 Bs[2][128 * 64];  // 2 x 16 KB
    const int K = H_DIM;
    int tid = threadIdx.x, w = tid >> 6, lane = tid & 63;
    int quad = lane >> 4, l15 = lane & 15;

    int gx = gridDim.x;
    int nwg = gx * gridDim.y;
    int v = blockIdx.y * gx + blockIdx.x;           // hw dispatch order (xcd ~ v%8)
    int lin = (v & 7) * (nwg >> 3) + (v >> 3);
    int m0 = (lin % gx) * 128, n0 = (lin / gx) * 128;
    int wm = (w & 1) * 64, wn = (w >> 1) * 64;

    int rowInChunk = lane >> 3;   // 0..7
    int uIdx = lane & 7;          // 16B unit within 128B row
    const char* Ag[4]; const char* Bg[4];
    int chOff[4];
#pragma unroll
    for (int c = 0; c < 4; ++c) {
        int ch = w * 4 + c;
        int r = ch * 8 + rowInChunk;
        int gu = uIdx ^ (r & 7);   // pre-swizzled global source unit
        Ag[c] = (const char*)(A + (size_t)(m0 + r) * K) + gu * 16;
        Bg[c] = (const char*)(Bt + (size_t)(n0 + r) * K) + gu * 16;
        chOff[c] = ch * 1024;
    }

    f32x4 acc[4][4];
#pragma unroll
    for (int i = 0; i < 4; ++i)
#pragma unroll
        for (int j = 0; j < 4; ++j) acc[i][j] = (f32x4){0.f, 0.f, 0.f, 0.f};

    const int nsteps = K / 64;

#pragma unroll
    for (int c = 0; c < 4; ++c) gld16(Ag[c], (char*)&As[0][0] + chOff[c]);
#pragma unroll
    for (int c = 0; c < 4; ++c) gld16(Bg[c], (char*)&Bs[0][0] + chOff[c]);

    for (int t = 0; t < nsteps; ++t) {
        int cur = t & 1;
        if (t + 1 < nsteps) {
            size_t kb = (size_t)(t + 1) * 128;
            char* dA = (char*)&As[cur ^ 1][0];
            char* dB = (char*)&Bs[cur ^ 1][0];
#pragma unroll
            for (int c = 0; c < 4; ++c) gld16(Ag[c] + kb, dA + chOff[c]);
#pragma unroll
            for (int c = 0; c < 4; ++c) gld16(Bg[c] + kb, dB + chOff[c]);
            asm volatile("s_waitcnt vmcnt(8)" ::: "memory");
        } else {
            asm volatile("s_waitcnt vmcnt(0)" ::: "memory");
        }
        __builtin_amdgcn_sched_barrier(0);
        __builtin_amdgcn_s_barrier();
        __builtin_amdgcn_sched_barrier(0);

        const char* sA = (const char*)&As[cur][0];
        const char* sB = (const char*)&Bs[cur][0];
#pragma unroll
        for (int kk = 0; kk < 2; ++kk) {
            bf16x8 af[4], bfr[4];
#pragma unroll
            for (int mt = 0; mt < 4; ++mt) {
                int m = wm + mt * 16 + l15;
                af[mt] = *(const bf16x8*)(sA + m * 128 + (((kk * 4 + quad) ^ (m & 7)) * 16));
            }
#pragma unroll
            for (int nt = 0; nt < 4; ++nt) {
                int n = wn + nt * 16 + l15;
                bfr[nt] = *(const bf16x8*)(sB + n * 128 + (((kk * 4 + quad) ^ (n & 7)) * 16));
            }
#pragma unroll
            for (int mt = 0; mt < 4; ++mt)
#pragma unroll
                for (int nt = 0; nt < 4; ++nt)
                    acc[mt][nt] = __builtin_amdgcn_mfma_f32_16x16x32_bf16(af[mt], bfr[nt], acc[mt][nt], 0, 0, 0);
        }
        __builtin_amdgcn_sched_barrier(0);
        __builtin_amdgcn_s_barrier();
        __builtin_amdgcn_sched_barrier(0);
    }
#pragma unroll
    for (int mt = 0; mt < 4; ++mt)
#pragma unroll
        for (int nt = 0; nt < 4; ++nt)
#pragma unroll
            for (int r = 0; r < 4; ++r) {
                int row = m0 + wm + mt * 16 + quad * 4 + r;
                int col = n0 + wn + nt * 16 + l15;
                size_t off = (size_t)row * Ncols + col;
                float vv = acc[mt][nt][r];
                if (Cb) {
                    Cb[off] = f2bf(vv);
                } else {
                    if (residual) vv += residual[off];
                    C[off] = vv;
                }
            }
}

// ---------------- 8-phase 256x256 bf16 MFMA GEMM (QKV projection) ----------------
// m201-style template: BM=BN=256, BK=64, 8 waves (2M x 4N), per-wave 128x64 out.
// LDS 128 KB: A[2][256][64], B[2][256][64] double-buffered per K-tile parity.
// Per K-tile: 4 phases, each {ds_read subtile; stage 1 half-tile prefetch;
// barrier; lgkmcnt(0); setprio(1); 16 MFMA; setprio(0); barrier}.
// Prefetch targets only dead regions: tile j+1 A-halves in ph1/ph2 (other buf,
// fully read during tile j-1), tile j+2 B-halves in ph3/ph4 (this buf, B dead
// after ph2). Counted vmcnt(4) once per tile at ph4 (2 half-tiles in flight).
__global__ __launch_bounds__(512) void gemm8_k(const __hip_bfloat16* __restrict__ A,
                                               const __hip_bfloat16* __restrict__ Bt,
                                               unsigned short* __restrict__ Cb,
                                               int Ncols) {
    __shared__ __align__(16) __hip_bfloat16 As[2][256 * 64];  // 2 x 32 KB
    __shared__ __align__(16) __hip_bfloat16 Bs[2][256 * 64];  // 2 x 32 KB
    const int K = H_DIM;
    int tid = threadIdx.x, w = tid >> 6, lane = tid & 63;
    int quad = lane >> 4, l15 = lane & 15;
    int wr = w >> 2, wc = w & 3;       // wave grid 2M x 4N

    // XCD-aware bijective block swizzle (nwg % 8 == 0)
    int gx = gridDim.x;
    int nwg = gx * gridDim.y;
    int v = blockIdx.y * gx + blockIdx.x;
    int lin = (v & 7) * (nwg >> 3) + (v >> 3);
    int m0 = (lin % gx) * 256, n0 = (lin / gx) * 256;

    const char* Abase = (const char*)A + (size_t)m0 * (K * 2);
    const char* Bbase = (const char*)Bt + (size_t)n0 * (K * 2);
    int srow = w * 8 + (lane >> 3);    // 0..63 stage row group

    // stage one half-tile (128 rows x 128 B): 2 gld16 per thread, linear LDS,
    // XOR swizzle applied on the global source unit (rule #21)
    auto stage = [&](const char* gbase, int rowoff, char* lbase, size_t kbyte) {
#pragma unroll
        for (int l = 0; l < 2; ++l) {
            int r = l * 64 + srow;                  // 0..127 within half
            int gu = (lane & 7) ^ (r & 7);
            gld16(gbase + (size_t)(rowoff + r) * (K * 2) + kbyte + gu * 16,
                  lbase + (l * 64 + w * 8) * 128);
        }
    };

    f32x4 acc[8][4];
#pragma unroll
    for (int i = 0; i < 8; ++i)
#pragma unroll
        for (int j = 0; j < 4; ++j) acc[i][j] = (f32x4){0.f, 0.f, 0.f, 0.f};

    const int ntiles = K / 64;   // 64

    // prologue: tile0 {A0,A1,B0,B1} + tile1 {B0,B1}; wait tile0 (leave 4 in flight)
    stage(Abase, 0,   (char*)&As[0][0],         0);
    stage(Abase, 128, (char*)&As[0][0] + 16384, 0);
    stage(Bbase, 0,   (char*)&Bs[0][0],         0);
    stage(Bbase, 128, (char*)&Bs[0][0] + 16384, 0);
    stage(Bbase, 0,   (char*)&Bs[1][0],         128);
    stage(Bbase, 128, (char*)&Bs[1][0] + 16384, 128);
    asm volatile("s_waitcnt vmcnt(4)" ::: "memory");
    __builtin_amdgcn_sched_barrier(0);
    __builtin_amdgcn_s_barrier();
    __builtin_amdgcn_sched_barrier(0);

    for (int j = 0; j < ntiles; ++j) {
        int d = j & 1;
        const char* sA = (const char*)&As[d][0];
        const char* sB = (const char*)&Bs[d][0];
        char* nA = (char*)&As[d ^ 1][0];     // tile j+1 A buffer
        char* pB = (char*)&Bs[d][0];         // tile j+2 B buffer (same parity)
        size_t kb1 = (size_t)(j + 1) * 128, kb2 = (size_t)(j + 2) * 128;
        bf16x8 aR[4][2], bR[4][2];

        // ---------- phase 1: read A[mt0-3] + B[nt0-1]; stage t(j+1) A0 ----------
#pragma unroll
        for (int mt = 0; mt < 4; ++mt)
#pragma unroll
            for (int kk = 0; kk < 2; ++kk) {
                int m = wr * 128 + mt * 16 + l15;
                aR[mt][kk] = *(const bf16x8*)(sA + m * 128 + (((kk * 4 + quad) ^ (m & 7)) * 16));
            }
#pragma unroll
        for (int nt = 0; nt < 2; ++nt)
#pragma unroll
            for (int kk = 0; kk < 2; ++kk) {
                int n = wc * 64 + nt * 16 + l15;
                bR[nt][kk] = *(const bf16x8*)(sB + n * 128 + (((kk * 4 + quad) ^ (n & 7)) * 16));
            }
        if (j + 1 < ntiles) stage(Abase, 0, nA, kb1);
        __builtin_amdgcn_sched_barrier(0);
        __builtin_amdgcn_s_barrier();
        asm volatile("s_waitcnt lgkmcnt(0)" ::: "memory");
        __builtin_amdgcn_sched_barrier(0);
        __builtin_amdgcn_s_setprio(1);
#pragma unroll
        for (int mt = 0; mt < 4; ++mt)
#pragma unroll
            for (int nt = 0; nt < 2; ++nt)
#pragma unroll
                for (int kk = 0; kk < 2; ++kk)
                    acc[mt][nt] = __builtin_amdgcn_mfma_f32_16x16x32_bf16(aR[mt][kk], bR[nt][kk], acc[mt][nt], 0, 0, 0);
        __builtin_amdgcn_s_setprio(0);
        __builtin_amdgcn_sched_barrier(0);
        __builtin_amdgcn_s_barrier();
        __builtin_amdgcn_sched_barrier(0);

        // ---------- phase 2: read B[nt2-3]; stage t(j+1) A1 ----------
#pragma unroll
        for (int nt = 2; nt < 4; ++nt)
#pragma unroll
            for (int kk = 0; kk < 2; ++kk) {
                int n = wc * 64 + nt * 16 + l15;
                bR[nt][kk] = *(const bf16x8*)(sB + n * 128 + (((kk * 4 + quad) ^ (n & 7)) * 16));
            }
        if (j + 1 < ntiles) stage(Abase, 128, nA + 16384, kb1);
        __builtin_amdgcn_sched_barrier(0);
        __builtin_amdgcn_s_barrier();
        asm volatile("s_waitcnt lgkmcnt(0)" ::: "memory");
        __builtin_amdgcn_sched_barrier(0);
        __builtin_amdgcn_s_setprio(1);
#pragma unroll
        for (int mt = 0; mt < 4; ++mt)
#pragma unroll
            for (int nt = 2; nt < 4; ++nt)
#pragma unroll
                for (int kk = 0; kk < 2; ++kk)
                    acc[mt][nt] = __builtin_amdgcn_mfma_f32_16x16x32_bf16(aR[mt][kk], bR[nt][kk], acc[mt][nt], 0, 0, 0);
        __builtin_amdgcn_s_setprio(0);
        __builtin_amdgcn_sched_barrier(0);
        __builtin_amdgcn_s_barrier();
        __builtin_amdgcn_sched_barrier(0);

        // ---------- phase 3: read A[mt4-7] (reuse slots); stage t(j+2) B0 ----------
#pragma unroll
        for (int mt = 0; mt < 4; ++mt)
#pragma unroll
            for (int kk = 0; kk < 2; ++kk) {
                int m = wr * 128 + (mt + 4) * 16 + l15;
                aR[mt][kk] = *(const bf16x8*)(sA + m * 128 + (((kk * 4 + quad) ^ (m & 7)) * 16));
            }
        if (j + 2 < ntiles) stage(Bbase, 0, pB, kb2);
        __builtin_amdgcn_sched_barrier(0);
        __builtin_amdgcn_s_barrier();
        asm volatile("s_waitcnt lgkmcnt(0)" ::: "memory");
        __builtin_amdgcn_sched_barrier(0);
        __builtin_amdgcn_s_setprio(1);
#pragma unroll
        for (int mt = 0; mt < 4; ++mt)
#pragma unroll
            for (int nt = 0; nt < 2; ++nt)
#pragma unroll
                for (int kk = 0; kk < 2; ++kk)
                    acc[mt + 4][nt] = __builtin_amdgcn_mfma_f32_16x16x32_bf16(aR[mt][kk], bR[nt][kk], acc[mt + 4][nt], 0, 0, 0);
        __builtin_amdgcn_s_setprio(0);
        __builtin_amdgcn_sched_barrier(0);
        __builtin_amdgcn_s_barrier();
        __builtin_amdgcn_sched_barrier(0);

        // ---------- phase 4: stage t(j+2) B1; counted vmcnt; MFMA mt4-7 x nt2-3 ----------
        if (j + 2 < ntiles) {
            stage(Bbase, 128, pB + 16384, kb2);
            asm volatile("s_waitcnt vmcnt(4)" ::: "memory");   // t(j+1) fully resident
        } else {
            asm volatile("s_waitcnt vmcnt(0)" ::: "memory");
        }
        __builtin_amdgcn_sched_barrier(0);
        __builtin_amdgcn_s_barrier();
        __builtin_amdgcn_sched_barrier(0);
        __builtin_amdgcn_s_setprio(1);
#pragma unroll
        for (int mt = 0; mt < 4; ++mt)
#pragma unroll
            for (int nt = 2; nt < 4; ++nt)
#pragma unroll
                for (int kk = 0; kk < 2; ++kk)
                    acc[mt + 4][nt] = __builtin_amdgcn_mfma_f32_16x16x32_bf16(aR[mt][kk], bR[nt][kk], acc[mt + 4][nt], 0, 0, 0);
        __builtin_amdgcn_s_setprio(0);
        __builtin_amdgcn_sched_barrier(0);
        __builtin_amdgcn_s_barrier();
        __builtin_amdgcn_sched_barrier(0);
    }

    // epilogue: C/D layout col=lane&15, row=quad*4+reg
#pragma unroll
    for (int mt = 0; mt < 8; ++mt)
#pragma unroll
        for (int nt = 0; nt < 4; ++nt)
#pragma unroll
            for (int r = 0; r < 4; ++r) {
                int row = m0 + wr * 128 + mt * 16 + quad * 4 + r;
                int col = n0 + wc * 64 + nt * 16 + l15;
                Cb[(size_t)row * Ncols + col] = f2bf(acc[mt][nt][r]);
            }
}

// ---------------- prep: RoPE + pack Qc (scaled bf16) and Kc (bf16, per-head rows) ----
__global__ __launch_bounds__(256) void prep_k(const unsigned short* __restrict__ qkvb,
                                              const int* __restrict__ pos,
                                              unsigned short* __restrict__ Qc,
                                              unsigned short* __restrict__ Kc) {
    int row = blockIdx.x, tid = threadIdx.x;
    float fpos = (float)pos[row];
    const float scale = 0.08838834764831845f;  // 1/sqrt(128)
    const float lg = 0.20762050593045f;        // log2(10000)/64
#pragma unroll
    for (int it = 0; it < 8; ++it) {
        int pi = tid + it * 256;        // 0..2047 : q pairs
        int head = pi >> 6, t = pi & 63;
        float inv = exp2f(-(float)t * lg);
        float ang = fpos * inv;
        float s = __sinf(ang), c = __cosf(ang);
        const unsigned short* bp = qkvb + (size_t)row * QKV_D + head * HD + t;
        float x1 = bf2f(bp[0]), x2 = bf2f(bp[64]);
        unsigned short* qb = Qc + (size_t)row * H_DIM + head * HD + t;
        qb[0]  = f2bf((x1 * c - x2 * s) * scale);
        qb[64] = f2bf((x2 * c + x1 * s) * scale);
    }
#pragma unroll
    for (int it = 0; it < 2; ++it) {
        int pi = tid + it * 256;        // 0..511 : k pairs
        int kvh = pi >> 6, t = pi & 63;
        float inv = exp2f(-(float)t * lg);
        float ang = fpos * inv;
        float s = __sinf(ang), c = __cosf(ang);
        const unsigned short* bp = qkvb + (size_t)row * QKV_D + H_DIM + kvh * HD + t;
        float x1 = bf2f(bp[0]), x2 = bf2f(bp[64]);
        unsigned short* kb = Kc + ((size_t)kvh * N_TOK + row) * HD + t;
        kb[0]  = f2bf(x1 * c - x2 * s);
        kb[64] = f2bf(x2 * c + x1 * s);
    }
}

// ---------------- V transpose: bf16 qkv V section -> Vt[kvh][d][key] ----------------
__global__ __launch_bounds__(256) void vt_k(const unsigned short* __restrict__ qkvb,
                                            unsigned short* __restrict__ Vt) {
    __shared__ unsigned short ts[64][136];
    int j0 = blockIdx.x * 64, kvh = blockIdx.y, tid = threadIdx.x;
#pragma unroll
    for (int it = 0; it < 4; ++it) {
        int idx = tid + it * 256;   // 16B slots of 64x128 ushort tile
        int r = idx >> 4, c8 = idx & 15;
        *(uint4*)&ts[r][c8 * 8] =
            *(const uint4*)(qkvb + (size_t)(j0 + r) * QKV_D + (NH + NKV) * HD + kvh * HD + c8 * 8);
    }
    __syncthreads();
    int d = tid >> 1, half = tid & 1;
    unsigned short* dst = Vt + ((size_t)kvh * HD + d) * N_TOK + j0 + half * 32;
#pragma unroll
    for (int g = 0; g < 4; ++g) {
        int kb = half * 32 + g * 8;
        uint4 o;
        o.x = (unsigned)ts[kb + 0][d] | ((unsigned)ts[kb + 1][d] << 16);
        o.y = (unsigned)ts[kb + 2][d] | ((unsigned)ts[kb + 3][d] << 16);
        o.z = (unsigned)ts[kb + 4][d] | ((unsigned)ts[kb + 5][d] << 16);
        o.w = (unsigned)ts[kb + 6][d] | ((unsigned)ts[kb + 7][d] << 16);
        *(uint4*)(dst + g * 8) = o;
    }
}

// ---------------- bf16 MFMA flash attention ----------------
// block = 512 threads / 8 waves: 64 q-rows x 2 heads (same kv-head group).
__global__ __launch_bounds__(512) void attn_k(const __hip_bfloat16* __restrict__ Qc,
                                              const __hip_bfloat16* __restrict__ Kc,
                                              const __hip_bfloat16* __restrict__ Vt,
                                              unsigned short* __restrict__ ao) {
    __shared__ __align__(16) __hip_bfloat16 Ks[2][32 * 128];   // [key][d], swizzled 16B units, 8KB/buf
    __shared__ __align__(16) __hip_bfloat16 Vs[2][128 * 32];   // [d][key], swizzled 16B units, 8KB/buf
    __shared__ __align__(16) unsigned short Pw[8][16 * 40];    // per-wave P, row stride 80B

    int tid = threadIdx.x, w = tid >> 6, lane = tid & 63;
    int quad = lane >> 4, l15 = lane & 15;
    int pr = blockIdx.y;                 // 0..15: (kvh, head-pair)
    int kvh = pr >> 1;
    int h = kvh * 4 + (pr & 1) * 2 + (w & 1);
    int qt = gridDim.x - 1 - blockIdx.x; // heavy tiles first
    int i0 = qt * 64;
    int i0q = i0 + (w >> 1) * 16;
    int q = i0q + l15;

    bf16x8 qf[4];
    const __hip_bfloat16* qrow = Qc + (size_t)q * H_DIM + h * HD;
#pragma unroll
    for (int kf = 0; kf < 4; ++kf)
        qf[kf] = *(const bf16x8*)(qrow + kf * 32 + quad * 8);

    const char* KcH = (const char*)(Kc + (size_t)kvh * N_TOK * HD);
    const char* VtH = (const char*)(Vt + (size_t)kvh * HD * N_TOK);

    int kKey = w * 4 + (lane >> 4);
    int kPart = (lane & 15) ^ (kKey & 15);
    int vD = w * 16 + (lane >> 2);
    int vP = (lane & 3) ^ (vD & 3);
    char* Kl[2] = { (char*)&Ks[0][0] + w * 1024, (char*)&Ks[1][0] + w * 1024 };
    char* Vl[2] = { (char*)&Vs[0][0] + w * 1024, (char*)&Vs[1][0] + w * 1024 };

    float mstat = -INFINITY, lstat = 0.f;
    f32x4 o[8];
#pragma unroll
    for (int nt = 0; nt < 8; ++nt) o[nt] = (f32x4){0.f, 0.f, 0.f, 0.f};

    int nsteps = (i0 + 64) >> 5;

    gld16(KcH + (size_t)kKey * 256 + kPart * 16, Kl[0]);
    gld16(VtH + (size_t)vD * (N_TOK * 2) + vP * 16, Vl[0]);
    __syncthreads();

    for (int t = 0; t < nsteps; ++t) {
        int j0 = t << 5;
        int cur = t & 1;
        if (t + 1 < nsteps) {
            int jn = j0 + 32;
            gld16(KcH + (size_t)(jn + kKey) * 256 + kPart * 16, Kl[cur ^ 1]);
            gld16(VtH + (size_t)vD * (N_TOK * 2) + (size_t)jn * 2 + vP * 16, Vl[cur ^ 1]);
        }
        if (j0 <= i0q + 15) {
            const char* Kb = (const char*)&Ks[cur][0];
            const char* Vb = (const char*)&Vs[cur][0];

            f32x4 s[2];
            s[0] = (f32x4){0.f, 0.f, 0.f, 0.f};
            s[1] = (f32x4){0.f, 0.f, 0.f, 0.f};
#pragma unroll
            for (int mt = 0; mt < 2; ++mt) {
                int key = mt * 16 + l15;
#pragma unroll
                for (int kf = 0; kf < 4; ++kf) {
                    bf16x8 kfr = *(const bf16x8*)(Kb + key * 256 + (((kf * 4 + quad) ^ (key & 15)) * 16));
                    s[mt] = __builtin_amdgcn_mfma_f32_16x16x32_bf16(kfr, qf[kf], s[mt], 0, 0, 0);
                }
            }
            if (j0 + 31 > i0q) {
#pragma unroll
                for (int mt = 0; mt < 2; ++mt) {
                    int keyb = j0 + mt * 16 + quad * 4;
#pragma unroll
                    for (int r = 0; r < 4; ++r)
                        if (keyb + r > q) s[mt][r] = -INFINITY;
                }
            }
            float mx = fmaxf(fmaxf(fmaxf(s[0][0], s[0][1]), fmaxf(s[0][2], s[0][3])),
                             fmaxf(fmaxf(s[1][0], s[1][1]), fmaxf(s[1][2], s[1][3])));
            mx = fmaxf(mx, __shfl_xor(mx, 16));
            mx = fmaxf(mx, __shfl_xor(mx, 32));
            float newm = fmaxf(mstat, mx);
            float alpha = __expf(mstat - newm);
            float p[8];
#pragma unroll
            for (int mt = 0; mt < 2; ++mt)
#pragma unroll
                for (int r = 0; r < 4; ++r) p[mt * 4 + r] = __expf(s[mt][r] - newm);
            float ps = p[0] + p[1] + p[2] + p[3] + p[4] + p[5] + p[6] + p[7];
            ps += __shfl_xor(ps, 16);
            ps += __shfl_xor(ps, 32);
            lstat = lstat * alpha + ps;
            mstat = newm;

            unsigned* pwb = (unsigned*)(&Pw[w][0]);
            int eo = l15 * 20 + quad * 2;
            pwb[eo]     = pack2bf(p[0], p[1]);
            pwb[eo + 1] = pack2bf(p[2], p[3]);
            pwb[eo + 8] = pack2bf(p[4], p[5]);
            pwb[eo + 9] = pack2bf(p[6], p[7]);
            bf16x8 pf = *(const bf16x8*)(&Pw[w][l15 * 40 + quad * 8]);

            float alq[4];
#pragma unroll
            for (int r = 0; r < 4; ++r) alq[r] = __shfl(alpha, quad * 4 + r);
#pragma unroll
            for (int nt = 0; nt < 8; ++nt)
#pragma unroll
                for (int r = 0; r < 4; ++r) o[nt][r] *= alq[r];

#pragma unroll
            for (int nt = 0; nt < 8; ++nt) {
                int d = nt * 16 + l15;
                bf16x8 vf = *(const bf16x8*)(Vb + d * 64 + ((quad ^ (d & 3)) * 16));
                o[nt] = __builtin_amdgcn_mfma_f32_16x16x32_bf16(pf, vf, o[nt], 0, 0, 0);
            }
        }
        __syncthreads();
    }

    float linv[4];
#pragma unroll
    for (int r = 0; r < 4; ++r) linv[r] = 1.f / __shfl(lstat, quad * 4 + r);
#pragma unroll
    for (int nt = 0; nt < 8; ++nt)
#pragma unroll
        for (int r = 0; r < 4; ++r) {
            int row = i0q + quad * 4 + r;
            int col = h * HD + nt * 16 + l15;
            ao[(size_t)row * H_DIM + col] = f2bf(o[nt][r] * linv[r]);
        }
}

// ---------------- top-2 routing ----------------
__global__ __launch_bounds__(256) void topk_k(const float* __restrict__ elog,
                                              float* __restrict__ w_out,
                                              float* __restrict__ id_out,
                                              int* __restrict__ ids_int) {
    int row = blockIdx.x * 256 + threadIdx.x;
    if (row >= N_TOK) return;
    const float4* e4 = (const float4*)(elog + (size_t)row * NE);
    float4 a = e4[0], b = e4[1];
    float e[8] = {a.x, a.y, a.z, a.w, b.x, b.y, b.z, b.w};
    int id0 = 0;
    float b0 = e[0];
#pragma unroll
    for (int t = 1; t < 8; ++t)
        if (e[t] > b0) { b0 = e[t]; id0 = t; }
    int id1 = -1;
    float b1 = -INFINITY;
#pragma unroll
    for (int t = 0; t < 8; ++t)
        if (t != id0 && e[t] > b1) { b1 = e[t]; id1 = t; }
    float s = b0 + b1;
    w_out[row * 2 + 0] = b0 / s;
    w_out[row * 2 + 1] = b1 / s;
    id_out[row * 2 + 0] = (float)id0;
    id_out[row * 2 + 1] = (float)id1;
    ids_int[row * 2 + 0] = id0;
    ids_int[row * 2 + 1] = id1;
}

// ---------------- stable argsort of 4096 expert ids (counting rank) ----------------
__global__ __launch_bounds__(256) void sort_k(const int* __restrict__ ids,
                                              float* __restrict__ reorder_out,
                                              int* __restrict__ perm) {
    __shared__ int sh[N_TOK * TOPK];
    int tid = threadIdx.x;
    for (int r = tid; r < N_TOK * TOPK; r += 256) sh[r] = ids[r];
    __syncthreads();
    int i = blockIdx.x * 256 + tid;
    int e = sh[i];
    int rank = 0;
    for (int j = 0; j < N_TOK * TOPK; ++j) {
        int ej = sh[j];
        rank += (ej < e) ? 1 : ((ej == e && j < i) ? 1 : 0);
    }
    reorder_out[rank] = (float)i;
    perm[rank] = i;
}

// ---------------- permuted row gather ----------------
__global__ __launch_bounds__(256) void gather_k(const float* __restrict__ src,
                                                const int* __restrict__ perm,
                                                float* __restrict__ dst) {
    int r = blockIdx.x;
    int srow = perm[r] >> 1;  // // TOPK
    const float4* s4 = (const float4*)(src + (size_t)srow * H_DIM);
    float4* d4 = (float4*)(dst + (size_t)r * H_DIM);
    int tid = threadIdx.x;
#pragma unroll
    for (int k = 0; k < 4; ++k) d4[tid + k * 256] = s4[tid + k * 256];
}

extern "C" void kernel_launch(void* const* d_in, const int* in_sizes, int n_in,
                              void* d_out, int out_size, void* d_ws, size_t ws_size,
                              hipStream_t stream) {
    const int*   positions = (const int*)d_in[0];
    const float* hidden    = (const float*)d_in[1];
    const float* w_qkv     = (const float*)d_in[2];
    const float* w_o       = (const float*)d_in[3];
    // d_in[4] = w_gate: dead code in reference
    const float* rms_pre   = (const float*)d_in[5];
    const float* rms_post  = (const float*)d_in[6];
    const float* elog      = (const float*)d_in[7];
    float* out = (float*)d_out;

    char* ws = (char*)d_ws;
    unsigned short* wqkvT = (unsigned short*)(ws);                 // [0, 50.3M) until qkv-gemm
    unsigned short* woT   = (unsigned short*)(ws);                 // [0, 33.5M) conv2..o-gemm
    float*          post  = (float*)(ws + 33554432ULL);            // [33.5M, 67.1M) rms2..gather
    unsigned short* xn    = (unsigned short*)(ws + 50331648ULL);   // [50.3M, 67.1M) rms1..qkv-gemm
    unsigned short* aout  = (unsigned short*)(ws + 50331648ULL);   // [50.3M, 67.1M) attn..o-gemm
    unsigned short* qkvb  = (unsigned short*)(ws + 67108864ULL);   // [67.1M, 92.3M) bf16 qkv
    float*          sbuf  = (float*)(ws + 67108864ULL);            // [67.1M, 100.7M) o-gemm..rms2
    unsigned short* Qc    = (unsigned short*)(ws + 117440512ULL);  // 16 MB
    unsigned short* Kc    = (unsigned short*)(ws + 134217728ULL);  // 4 MB
    unsigned short* Vt    = (unsigned short*)(ws + 138412032ULL);  // 4 MB
    int* ids_int  = (int*)(ws + 142606336ULL);
    int* perm_int = (int*)(ws + 142622720ULL);

    // 1. w_qkv -> bf16 transposed [6144][4096]
    convT_k<<<dim3(QKV_D / 64, H_DIM / 64), 256, 0, stream>>>(w_qkv, wqkvT, H_DIM, QKV_D);
    // 2. pre-attention RMSNorm -> bf16
    rmsnorm_k<<<N_TOK, 256, 0, stream>>>(hidden, rms_pre, nullptr, xn);
    // 3. QKV projection: 8-phase 256^2 MFMA GEMM -> bf16 qkv
    gemm8_k<<<dim3(N_TOK / 256, QKV_D / 256), 512, 0, stream>>>(
        (const __hip_bfloat16*)xn, (const __hip_bfloat16*)wqkvT, qkvb, QKV_D);
    // 4. w_o -> bf16 transposed [4096][4096]  (reuses wqkvT region)
    convT_k<<<dim3(H_DIM / 64, H_DIM / 64), 256, 0, stream>>>(w_o, woT, H_DIM, H_DIM);
    // 5. RoPE + pack Qc/Kc bf16
    prep_k<<<N_TOK, 256, 0, stream>>>(qkvb, positions, Qc, Kc);
    // 6. V transpose -> Vt bf16
    vt_k<<<dim3(N_TOK / 64, NKV), 256, 0, stream>>>(qkvb, Vt);
    // 7. causal GQA flash attention (bf16 MFMA) -> bf16 attn_out
    attn_k<<<dim3(N_TOK / 64, 16), 512, 0, stream>>>(
        (const __hip_bfloat16*)Qc, (const __hip_bfloat16*)Kc, (const __hip_bfloat16*)Vt, aout);
    // 8. output projection + residual (2-phase bf16 MFMA) -> fp32 s
    gemm_k<<<dim3(N_TOK / 128, H_DIM / 128), 256, 0, stream>>>(
        (const __hip_bfloat16*)aout, (const __hip_bfloat16*)woT, sbuf, nullptr, hidden, H_DIM);
    // 9. post-attention RMSNorm -> fp32
    rmsnorm_k<<<N_TOK, 256, 0, stream>>>(sbuf, rms_post, post, nullptr);
    // 10. top-2 experts
    topk_k<<<N_TOK / 256, 256, 0, stream>>>(elog, out + OUT_W, out + OUT_IDS, ids_int);
    // 11. stable argsort of expert ids
    sort_k<<<(N_TOK * TOPK) / 256, 256, 0, stream>>>(ids_int, out + OUT_REO, perm_int);
    // 12. permuted gather
    gather_k<<<N_TOK * TOPK, 256, 0, stream>>>(post, perm_int, out + OUT_PERM);
}

// Round 6
// 714.492 us; speedup vs baseline: 1.1328x; 1.0039x over previous
//
#include <hip/hip_runtime.h>
#include <hip/hip_bf16.h>
#include <math.h>

// Problem constants
#define N_TOK 2048
#define H_DIM 4096
#define NH 32
#define NKV 8
#define HD 128
#define QKV_D 6144   // (NH + 2*NKV) * HD
#define NE 8
#define TOPK 2

// d_out layout (floats): permuted_output | topk_weights | topk_ids | reorder_ids
#define OUT_PERM 0
#define OUT_W    16777216   // 4096*4096
#define OUT_IDS  16781312
#define OUT_REO  16785408

typedef __bf16 bf16x8 __attribute__((ext_vector_type(8)));
typedef float f32x4 __attribute__((ext_vector_type(4)));

typedef __attribute__((address_space(3))) void lds_void;
typedef __attribute__((address_space(1))) const void gbl_void;

__device__ __forceinline__ void gld16(const void* g, void* l) {
    // async global->LDS, 16B per lane; LDS dest = wave-uniform base + lane*16
    __builtin_amdgcn_global_load_lds((gbl_void*)g, (lds_void*)l, 16, 0, 0);
}

__device__ __forceinline__ unsigned short f2bf(float f) {
    union { float f; unsigned u; } v; v.f = f;
    unsigned r = v.u + 0x7fff + ((v.u >> 16) & 1);
    return (unsigned short)(r >> 16);
}
__device__ __forceinline__ unsigned pack2bf(float a, float b) {
    return (unsigned)f2bf(a) | ((unsigned)f2bf(b) << 16);
}
__device__ __forceinline__ float bf2f(unsigned short u) {
    union { unsigned u; float f; } v; v.u = ((unsigned)u) << 16;
    return v.f;
}

// ---------------- RMSNorm (fp32 in; fp32 or bf16 out) ----------------
__global__ __launch_bounds__(256) void rmsnorm_k(const float* __restrict__ x,
                                                 const float* __restrict__ w,
                                                 float* __restrict__ yf,
                                                 unsigned short* __restrict__ yb) {
    int row = blockIdx.x;
    int tid = threadIdx.x;
    const float4* x4 = (const float4*)(x + (size_t)row * H_DIM);
    const float4* w4 = (const float4*)w;
    float4 v[4];
    float ss = 0.f;
#pragma unroll
    for (int k = 0; k < 4; ++k) {
        v[k] = x4[tid + k * 256];
        ss += v[k].x * v[k].x + v[k].y * v[k].y + v[k].z * v[k].z + v[k].w * v[k].w;
    }
#pragma unroll
    for (int off = 32; off; off >>= 1) ss += __shfl_xor(ss, off);
    __shared__ float sacc[4];
    if ((tid & 63) == 0) sacc[tid >> 6] = ss;
    __syncthreads();
    float tot = sacc[0] + sacc[1] + sacc[2] + sacc[3];
    float sc = rsqrtf(tot * (1.0f / H_DIM) + 1e-6f);
#pragma unroll
    for (int k = 0; k < 4; ++k) {
        float4 ww = w4[tid + k * 256];
        float4 o;
        o.x = v[k].x * sc * ww.x;
        o.y = v[k].y * sc * ww.y;
        o.z = v[k].z * sc * ww.z;
        o.w = v[k].w * sc * ww.w;
        if (yf) {
            *(float4*)(yf + (size_t)row * H_DIM + (tid + k * 256) * 4) = o;
        } else {
            uint2 p;
            p.x = pack2bf(o.x, o.y);
            p.y = pack2bf(o.z, o.w);
            *(uint2*)(yb + (size_t)row * H_DIM + (tid + k * 256) * 4) = p;
        }
    }
}

// ---------------- transpose + fp32->bf16 weight conversion ----------------
// src[R][C] fp32 -> dst[C][R] bf16 (64x64 tiles)
__global__ __launch_bounds__(256) void convT_k(const float* __restrict__ src,
                                               unsigned short* __restrict__ dst,
                                               int R, int C) {
    __shared__ float t[64][68];
    int r0 = blockIdx.y * 64, c0 = blockIdx.x * 64;
    int tid = threadIdx.x;
    int lr = tid >> 4, lc = tid & 15;
#pragma unroll
    for (int it = 0; it < 4; ++it) {
        int r = lr + it * 16;
        float4 v = *(const float4*)(src + (size_t)(r0 + r) * C + c0 + lc * 4);
        *(float4*)&t[r][lc * 4] = v;
    }
    __syncthreads();
#pragma unroll
    for (int it = 0; it < 4; ++it) {
        int cc = lr + it * 16;
        uint2 o;
        o.x = pack2bf(t[lc * 4 + 0][cc], t[lc * 4 + 1][cc]);
        o.y = pack2bf(t[lc * 4 + 2][cc], t[lc * 4 + 3][cc]);
        *(uint2*)(dst + (size_t)(c0 + cc) * R + r0 + lc * 4) = o;
    }
}

// ---------------- 2-phase bf16 MFMA GEMM (kept for O-projection) ----------------
// 128x128 tile, BK=64, 4 waves each 64x64, counted vmcnt(8) + raw s_barrier.
__global__ __launch_bounds__(256) void gemm_k(const __hip_bfloat16* __restrict__ A,
                                              const __hip_bfloat16* __restrict__ Bt,
                                              float* __restrict__ C,
                                              unsigned short* __restrict__ Cb,
                                              const float* __restrict__ residual,
                                              int Ncols) {
    __shared__ __align__(16) __hip_bfloat16 As[2][128 * 64];  // 2 x 16 KB
    __shared__ __align__(16) __hip_bfloat16 Bs[2][128 * 64];  // 2 x 16 KB
    const int K = H_DIM;
    int tid = threadIdx.x, w = tid >> 6, lane = tid & 63;
    int quad = lane >> 4, l15 = lane & 15;

    int gx = gridDim.x;
    int nwg = gx * gridDim.y;
    int v = blockIdx.y * gx + blockIdx.x;           // hw dispatch order (xcd ~ v%8)
    int lin = (v & 7) * (nwg >> 3) + (v >> 3);
    int m0 = (lin % gx) * 128, n0 = (lin / gx) * 128;
    int wm = (w & 1) * 64, wn = (w >> 1) * 64;

    int rowInChunk = lane >> 3;   // 0..7
    int uIdx = lane & 7;          // 16B unit within 128B row
    const char* Ag[4]; const char* Bg[4];
    int chOff[4];
#pragma unroll
    for (int c = 0; c < 4; ++c) {
        int ch = w * 4 + c;
        int r = ch * 8 + rowInChunk;
        int gu = uIdx ^ (r & 7);   // pre-swizzled global source unit
        Ag[c] = (const char*)(A + (size_t)(m0 + r) * K) + gu * 16;
        Bg[c] = (const char*)(Bt + (size_t)(n0 + r) * K) + gu * 16;
        chOff[c] = ch * 1024;
    }

    f32x4 acc[4][4];
#pragma unroll
    for (int i = 0; i < 4; ++i)
#pragma unroll
        for (int j = 0; j < 4; ++j) acc[i][j] = (f32x4){0.f, 0.f, 0.f, 0.f};

    const int nsteps = K / 64;

#pragma unroll
    for (int c = 0; c < 4; ++c) gld16(Ag[c], (char*)&As[0][0] + chOff[c]);
#pragma unroll
    for (int c = 0; c < 4; ++c) gld16(Bg[c], (char*)&Bs[0][0] + chOff[c]);

    for (int t = 0; t < nsteps; ++t) {
        int cur = t & 1;
        if (t + 1 < nsteps) {
            size_t kb = (size_t)(t + 1) * 128;
            char* dA = (char*)&As[cur ^ 1][0];
            char* dB = (char*)&Bs[cur ^ 1][0];
#pragma unroll
            for (int c = 0; c < 4; ++c) gld16(Ag[c] + kb, dA + chOff[c]);
#pragma unroll
            for (int c = 0; c < 4; ++c) gld16(Bg[c] + kb, dB + chOff[c]);
            asm volatile("s_waitcnt vmcnt(8)" ::: "memory");
        } else {
            asm volatile("s_waitcnt vmcnt(0)" ::: "memory");
        }
        __builtin_amdgcn_sched_barrier(0);
        __builtin_amdgcn_s_barrier();
        __builtin_amdgcn_sched_barrier(0);

        const char* sA = (const char*)&As[cur][0];
        const char* sB = (const char*)&Bs[cur][0];
#pragma unroll
        for (int kk = 0; kk < 2; ++kk) {
            bf16x8 af[4], bfr[4];
#pragma unroll
            for (int mt = 0; mt < 4; ++mt) {
                int m = wm + mt * 16 + l15;
                af[mt] = *(const bf16x8*)(sA + m * 128 + (((kk * 4 + quad) ^ (m & 7)) * 16));
            }
#pragma unroll
            for (int nt = 0; nt < 4; ++nt) {
                int n = wn + nt * 16 + l15;
                bfr[nt] = *(const bf16x8*)(sB + n * 128 + (((kk * 4 + quad) ^ (n & 7)) * 16));
            }
#pragma unroll
            for (int mt = 0; mt < 4; ++mt)
#pragma unroll
                for (int nt = 0; nt < 4; ++nt)
                    acc[mt][nt] = __builtin_amdgcn_mfma_f32_16x16x32_bf16(af[mt], bfr[nt], acc[mt][nt], 0, 0, 0);
        }
        __builtin_amdgcn_sched_barrier(0);
        __builtin_amdgcn_s_barrier();
        __builtin_amdgcn_sched_barrier(0);
    }
#pragma unroll
    for (int mt = 0; mt < 4; ++mt)
#pragma unroll
        for (int nt = 0; nt < 4; ++nt)
#pragma unroll
            for (int r = 0; r < 4; ++r) {
                int row = m0 + wm + mt * 16 + quad * 4 + r;
                int col = n0 + wn + nt * 16 + l15;
                size_t off = (size_t)row * Ncols + col;
                float vv = acc[mt][nt][r];
                if (Cb) {
                    Cb[off] = f2bf(vv);
                } else {
                    if (residual) vv += residual[off];
                    C[off] = vv;
                }
            }
}

// ---------------- 8-phase-derived 256x256 bf16 MFMA GEMM (QKV projection) ----------------
// BM=BN=256, BK=64, 8 waves (2M x 4N), per-wave 128x64 out, 128 KB LDS dbuf.
// TWO barriers per K-tile (minimal sync, derived from buffer lifetimes):
//   region1: read A0-3 + all B; stage A(j+1); 32 MFMA        | mid barrier
//   region2: read A4-7; stage B(j+2); 32 MFMA; vmcnt(4)      | end barrier
// vmcnt ledger: end-of-tile vmcnt(4) leaves exactly B(j+2)'s 4 loads in flight
// -> A(j+1) and B(j+1) proven resident for tile j+1's reads. Tails vmcnt(0).
// Mid barrier: all waves' B-reads of tile j complete (MFMA consumed them;
// sched_barrier pins) -> safe to overwrite Bs[d] with B(j+2) in region2.
// End barrier: tile j-1's A-readers done -> safe to stage A into As[d^1] next.
__global__ __launch_bounds__(512) void gemm8_k(const __hip_bfloat16* __restrict__ A,
                                               const __hip_bfloat16* __restrict__ Bt,
                                               unsigned short* __restrict__ Cb,
                                               int Ncols) {
    __shared__ __align__(16) __hip_bfloat16 As[2][256 * 64];  // 2 x 32 KB
    __shared__ __align__(16) __hip_bfloat16 Bs[2][256 * 64];  // 2 x 32 KB
    const int K = H_DIM;
    int tid = threadIdx.x, w = tid >> 6, lane = tid & 63;
    int quad = lane >> 4, l15 = lane & 15;
    int wr = w >> 2, wc = w & 3;       // wave grid 2M x 4N

    // XCD-aware bijective block swizzle (nwg % 8 == 0)
    int gx = gridDim.x;
    int nwg = gx * gridDim.y;
    int v = blockIdx.y * gx + blockIdx.x;
    int lin = (v & 7) * (nwg >> 3) + (v >> 3);
    int m0 = (lin % gx) * 256, n0 = (lin / gx) * 256;

    const char* Abase = (const char*)A + (size_t)m0 * (K * 2);
    const char* Bbase = (const char*)Bt + (size_t)n0 * (K * 2);
    int srow = w * 8 + (lane >> 3);    // 0..63 stage row group

    // stage one half-tile (128 rows x 128 B): 2 gld16 per thread, linear LDS,
    // XOR swizzle applied on the global source unit (rule #21)
    auto stage = [&](const char* gbase, int rowoff, char* lbase, size_t kbyte) {
#pragma unroll
        for (int l = 0; l < 2; ++l) {
            int r = l * 64 + srow;                  // 0..127 within half
            int gu = (lane & 7) ^ (r & 7);
            gld16(gbase + (size_t)(rowoff + r) * (K * 2) + kbyte + gu * 16,
                  lbase + (l * 64 + w * 8) * 128);
        }
    };

    f32x4 acc[8][4];
#pragma unroll
    for (int i = 0; i < 8; ++i)
#pragma unroll
        for (int j = 0; j < 4; ++j) acc[i][j] = (f32x4){0.f, 0.f, 0.f, 0.f};

    const int ntiles = K / 64;   // 64

    // prologue: tile0 {A0,A1,B0,B1} + tile1 {B0,B1}; wait tile0 (leave 4 in flight)
    stage(Abase, 0,   (char*)&As[0][0],         0);
    stage(Abase, 128, (char*)&As[0][0] + 16384, 0);
    stage(Bbase, 0,   (char*)&Bs[0][0],         0);
    stage(Bbase, 128, (char*)&Bs[0][0] + 16384, 0);
    stage(Bbase, 0,   (char*)&Bs[1][0],         128);
    stage(Bbase, 128, (char*)&Bs[1][0] + 16384, 128);
    asm volatile("s_waitcnt vmcnt(4)" ::: "memory");
    __builtin_amdgcn_sched_barrier(0);
    __builtin_amdgcn_s_barrier();
    __builtin_amdgcn_sched_barrier(0);

    for (int j = 0; j < ntiles; ++j) {
        int d = j & 1;
        const char* sA = (const char*)&As[d][0];
        const char* sB = (const char*)&Bs[d][0];
        char* nA = (char*)&As[d ^ 1][0];     // tile j+1 A buffer
        char* pB = (char*)&Bs[d][0];         // tile j+2 B buffer (same parity)
        size_t kb1 = (size_t)(j + 1) * 128, kb2 = (size_t)(j + 2) * 128;
        bf16x8 aR[4][2], bR[4][2];

        // ========== region 1: A[mt0-3] + B[nt0-3] reads; stage A(j+1); 32 MFMA ==========
#pragma unroll
        for (int mt = 0; mt < 4; ++mt)
#pragma unroll
            for (int kk = 0; kk < 2; ++kk) {
                int m = wr * 128 + mt * 16 + l15;
                aR[mt][kk] = *(const bf16x8*)(sA + m * 128 + (((kk * 4 + quad) ^ (m & 7)) * 16));
            }
#pragma unroll
        for (int nt = 0; nt < 4; ++nt)
#pragma unroll
            for (int kk = 0; kk < 2; ++kk) {
                int n = wc * 64 + nt * 16 + l15;
                bR[nt][kk] = *(const bf16x8*)(sB + n * 128 + (((kk * 4 + quad) ^ (n & 7)) * 16));
            }
        if (j + 1 < ntiles) {
            stage(Abase, 0,   nA,         kb1);
            stage(Abase, 128, nA + 16384, kb1);
        }
        __builtin_amdgcn_s_setprio(1);
#pragma unroll
        for (int mt = 0; mt < 4; ++mt)
#pragma unroll
            for (int nt = 0; nt < 4; ++nt)
#pragma unroll
                for (int kk = 0; kk < 2; ++kk)
                    acc[mt][nt] = __builtin_amdgcn_mfma_f32_16x16x32_bf16(aR[mt][kk], bR[nt][kk], acc[mt][nt], 0, 0, 0);
        __builtin_amdgcn_s_setprio(0);
        __builtin_amdgcn_sched_barrier(0);
        __builtin_amdgcn_s_barrier();      // mid: all waves' B-reads of tile j done
        __builtin_amdgcn_sched_barrier(0);

        // ========== region 2: A[mt4-7] reads; stage B(j+2); 32 MFMA; counted vmcnt ==========
#pragma unroll
        for (int mt = 0; mt < 4; ++mt)
#pragma unroll
            for (int kk = 0; kk < 2; ++kk) {
                int m = wr * 128 + (mt + 4) * 16 + l15;
                aR[mt][kk] = *(const bf16x8*)(sA + m * 128 + (((kk * 4 + quad) ^ (m & 7)) * 16));
            }
        if (j + 2 < ntiles) {
            stage(Bbase, 0,   pB,         kb2);
            stage(Bbase, 128, pB + 16384, kb2);
        }
        __builtin_amdgcn_s_setprio(1);
#pragma unroll
        for (int mt = 0; mt < 4; ++mt)
#pragma unroll
            for (int nt = 0; nt < 4; ++nt)
#pragma unroll
                for (int kk = 0; kk < 2; ++kk)
                    acc[mt + 4][nt] = __builtin_amdgcn_mfma_f32_16x16x32_bf16(aR[mt][kk], bR[nt][kk], acc[mt + 4][nt], 0, 0, 0);
        __builtin_amdgcn_s_setprio(0);
        if (j + 2 < ntiles) {
            asm volatile("s_waitcnt vmcnt(4)" ::: "memory");   // leaves B(j+2) in flight
        } else {
            asm volatile("s_waitcnt vmcnt(0)" ::: "memory");   // tail: drain
        }
        __builtin_amdgcn_sched_barrier(0);
        __builtin_amdgcn_s_barrier();      // end: tile j+1 resident; A-readers done
        __builtin_amdgcn_sched_barrier(0);
    }

    // epilogue: C/D layout col=lane&15, row=quad*4+reg
#pragma unroll
    for (int mt = 0; mt < 8; ++mt)
#pragma unroll
        for (int nt = 0; nt < 4; ++nt)
#pragma unroll
            for (int r = 0; r < 4; ++r) {
                int row = m0 + wr * 128 + mt * 16 + quad * 4 + r;
                int col = n0 + wc * 64 + nt * 16 + l15;
                Cb[(size_t)row * Ncols + col] = f2bf(acc[mt][nt][r]);
            }
}

// ---------------- prep: RoPE + pack Qc (scaled bf16) and Kc (bf16, per-head rows) ----
__global__ __launch_bounds__(256) void prep_k(const unsigned short* __restrict__ qkvb,
                                              const int* __restrict__ pos,
                                              unsigned short* __restrict__ Qc,
                                              unsigned short* __restrict__ Kc) {
    int row = blockIdx.x, tid = threadIdx.x;
    float fpos = (float)pos[row];
    const float scale = 0.08838834764831845f;  // 1/sqrt(128)
    const float lg = 0.20762050593045f;        // log2(10000)/64
#pragma unroll
    for (int it = 0; it < 8; ++it) {
        int pi = tid + it * 256;        // 0..2047 : q pairs
        int head = pi >> 6, t = pi & 63;
        float inv = exp2f(-(float)t * lg);
        float ang = fpos * inv;
        float s = __sinf(ang), c = __cosf(ang);
        const unsigned short* bp = qkvb + (size_t)row * QKV_D + head * HD + t;
        float x1 = bf2f(bp[0]), x2 = bf2f(bp[64]);
        unsigned short* qb = Qc + (size_t)row * H_DIM + head * HD + t;
        qb[0]  = f2bf((x1 * c - x2 * s) * scale);
        qb[64] = f2bf((x2 * c + x1 * s) * scale);
    }
#pragma unroll
    for (int it = 0; it < 2; ++it) {
        int pi = tid + it * 256;        // 0..511 : k pairs
        int kvh = pi >> 6, t = pi & 63;
        float inv = exp2f(-(float)t * lg);
        float ang = fpos * inv;
        float s = __sinf(ang), c = __cosf(ang);
        const unsigned short* bp = qkvb + (size_t)row * QKV_D + H_DIM + kvh * HD + t;
        float x1 = bf2f(bp[0]), x2 = bf2f(bp[64]);
        unsigned short* kb = Kc + ((size_t)kvh * N_TOK + row) * HD + t;
        kb[0]  = f2bf(x1 * c - x2 * s);
        kb[64] = f2bf(x2 * c + x1 * s);
    }
}

// ---------------- V transpose: bf16 qkv V section -> Vt[kvh][d][key] ----------------
__global__ __launch_bounds__(256) void vt_k(const unsigned short* __restrict__ qkvb,
                                            unsigned short* __restrict__ Vt) {
    __shared__ unsigned short ts[64][136];
    int j0 = blockIdx.x * 64, kvh = blockIdx.y, tid = threadIdx.x;
#pragma unroll
    for (int it = 0; it < 4; ++it) {
        int idx = tid + it * 256;   // 16B slots of 64x128 ushort tile
        int r = idx >> 4, c8 = idx & 15;
        *(uint4*)&ts[r][c8 * 8] =
            *(const uint4*)(qkvb + (size_t)(j0 + r) * QKV_D + (NH + NKV) * HD + kvh * HD + c8 * 8);
    }
    __syncthreads();
    int d = tid >> 1, half = tid & 1;
    unsigned short* dst = Vt + ((size_t)kvh * HD + d) * N_TOK + j0 + half * 32;
#pragma unroll
    for (int g = 0; g < 4; ++g) {
        int kb = half * 32 + g * 8;
        uint4 o;
        o.x = (unsigned)ts[kb + 0][d] | ((unsigned)ts[kb + 1][d] << 16);
        o.y = (unsigned)ts[kb + 2][d] | ((unsigned)ts[kb + 3][d] << 16);
        o.z = (unsigned)ts[kb + 4][d] | ((unsigned)ts[kb + 5][d] << 16);
        o.w = (unsigned)ts[kb + 6][d] | ((unsigned)ts[kb + 7][d] << 16);
        *(uint4*)(dst + g * 8) = o;
    }
}

// ---------------- bf16 MFMA flash attention ----------------
// block = 512 threads / 8 waves: 64 q-rows x 2 heads (same kv-head group).
__global__ __launch_bounds__(512) void attn_k(const __hip_bfloat16* __restrict__ Qc,
                                              const __hip_bfloat16* __restrict__ Kc,
                                              const __hip_bfloat16* __restrict__ Vt,
                                              unsigned short* __restrict__ ao) {
    __shared__ __align__(16) __hip_bfloat16 Ks[2][32 * 128];   // [key][d], swizzled 16B units, 8KB/buf
    __shared__ __align__(16) __hip_bfloat16 Vs[2][128 * 32];   // [d][key], swizzled 16B units, 8KB/buf
    __shared__ __align__(16) unsigned short Pw[8][16 * 40];    // per-wave P, row stride 80B

    int tid = threadIdx.x, w = tid >> 6, lane = tid & 63;
    int quad = lane >> 4, l15 = lane & 15;
    int pr = blockIdx.y;                 // 0..15: (kvh, head-pair)
    int kvh = pr >> 1;
    int h = kvh * 4 + (pr & 1) * 2 + (w & 1);
    int qt = gridDim.x - 1 - blockIdx.x; // heavy tiles first
    int i0 = qt * 64;
    int i0q = i0 + (w >> 1) * 16;
    int q = i0q + l15;

    bf16x8 qf[4];
    const __hip_bfloat16* qrow = Qc + (size_t)q * H_DIM + h * HD;
#pragma unroll
    for (int kf = 0; kf < 4; ++kf)
        qf[kf] = *(const bf16x8*)(qrow + kf * 32 + quad * 8);

    const char* KcH = (const char*)(Kc + (size_t)kvh * N_TOK * HD);
    const char* VtH = (const char*)(Vt + (size_t)kvh * HD * N_TOK);

    int kKey = w * 4 + (lane >> 4);
    int kPart = (lane & 15) ^ (kKey & 15);
    int vD = w * 16 + (lane >> 2);
    int vP = (lane & 3) ^ (vD & 3);
    char* Kl[2] = { (char*)&Ks[0][0] + w * 1024, (char*)&Ks[1][0] + w * 1024 };
    char* Vl[2] = { (char*)&Vs[0][0] + w * 1024, (char*)&Vs[1][0] + w * 1024 };

    float mstat = -INFINITY, lstat = 0.f;
    f32x4 o[8];
#pragma unroll
    for (int nt = 0; nt < 8; ++nt) o[nt] = (f32x4){0.f, 0.f, 0.f, 0.f};

    int nsteps = (i0 + 64) >> 5;

    gld16(KcH + (size_t)kKey * 256 + kPart * 16, Kl[0]);
    gld16(VtH + (size_t)vD * (N_TOK * 2) + vP * 16, Vl[0]);
    __syncthreads();

    for (int t = 0; t < nsteps; ++t) {
        int j0 = t << 5;
        int cur = t & 1;
        if (t + 1 < nsteps) {
            int jn = j0 + 32;
            gld16(KcH + (size_t)(jn + kKey) * 256 + kPart * 16, Kl[cur ^ 1]);
            gld16(VtH + (size_t)vD * (N_TOK * 2) + (size_t)jn * 2 + vP * 16, Vl[cur ^ 1]);
        }
        if (j0 <= i0q + 15) {
            const char* Kb = (const char*)&Ks[cur][0];
            const char* Vb = (const char*)&Vs[cur][0];

            f32x4 s[2];
            s[0] = (f32x4){0.f, 0.f, 0.f, 0.f};
            s[1] = (f32x4){0.f, 0.f, 0.f, 0.f};
#pragma unroll
            for (int mt = 0; mt < 2; ++mt) {
                int key = mt * 16 + l15;
#pragma unroll
                for (int kf = 0; kf < 4; ++kf) {
                    bf16x8 kfr = *(const bf16x8*)(Kb + key * 256 + (((kf * 4 + quad) ^ (key & 15)) * 16));
                    s[mt] = __builtin_amdgcn_mfma_f32_16x16x32_bf16(kfr, qf[kf], s[mt], 0, 0, 0);
                }
            }
            if (j0 + 31 > i0q) {
#pragma unroll
                for (int mt = 0; mt < 2; ++mt) {
                    int keyb = j0 + mt * 16 + quad * 4;
#pragma unroll
                    for (int r = 0; r < 4; ++r)
                        if (keyb + r > q) s[mt][r] = -INFINITY;
                }
            }
            float mx = fmaxf(fmaxf(fmaxf(s[0][0], s[0][1]), fmaxf(s[0][2], s[0][3])),
                             fmaxf(fmaxf(s[1][0], s[1][1]), fmaxf(s[1][2], s[1][3])));
            mx = fmaxf(mx, __shfl_xor(mx, 16));
            mx = fmaxf(mx, __shfl_xor(mx, 32));
            float newm = fmaxf(mstat, mx);
            float alpha = __expf(mstat - newm);
            float p[8];
#pragma unroll
            for (int mt = 0; mt < 2; ++mt)
#pragma unroll
                for (int r = 0; r < 4; ++r) p[mt * 4 + r] = __expf(s[mt][r] - newm);
            float ps = p[0] + p[1] + p[2] + p[3] + p[4] + p[5] + p[6] + p[7];
            ps += __shfl_xor(ps, 16);
            ps += __shfl_xor(ps, 32);
            lstat = lstat * alpha + ps;
            mstat = newm;

            unsigned* pwb = (unsigned*)(&Pw[w][0]);
            int eo = l15 * 20 + quad * 2;
            pwb[eo]     = pack2bf(p[0], p[1]);
            pwb[eo + 1] = pack2bf(p[2], p[3]);
            pwb[eo + 8] = pack2bf(p[4], p[5]);
            pwb[eo + 9] = pack2bf(p[6], p[7]);
            bf16x8 pf = *(const bf16x8*)(&Pw[w][l15 * 40 + quad * 8]);

            float alq[4];
#pragma unroll
            for (int r = 0; r < 4; ++r) alq[r] = __shfl(alpha, quad * 4 + r);
#pragma unroll
            for (int nt = 0; nt < 8; ++nt)
#pragma unroll
                for (int r = 0; r < 4; ++r) o[nt][r] *= alq[r];

#pragma unroll
            for (int nt = 0; nt < 8; ++nt) {
                int d = nt * 16 + l15;
                bf16x8 vf = *(const bf16x8*)(Vb + d * 64 + ((quad ^ (d & 3)) * 16));
                o[nt] = __builtin_amdgcn_mfma_f32_16x16x32_bf16(pf, vf, o[nt], 0, 0, 0);
            }
        }
        __syncthreads();
    }

    float linv[4];
#pragma unroll
    for (int r = 0; r < 4; ++r) linv[r] = 1.f / __shfl(lstat, quad * 4 + r);
#pragma unroll
    for (int nt = 0; nt < 8; ++nt)
#pragma unroll
        for (int r = 0; r < 4; ++r) {
            int row = i0q + quad * 4 + r;
            int col = h * HD + nt * 16 + l15;
            ao[(size_t)row * H_DIM + col] = f2bf(o[nt][r] * linv[r]);
        }
}

// ---------------- top-2 routing ----------------
__global__ __launch_bounds__(256) void topk_k(const float* __restrict__ elog,
                                              float* __restrict__ w_out,
                                              float* __restrict__ id_out,
                                              int* __restrict__ ids_int) {
    int row = blockIdx.x * 256 + threadIdx.x;
    if (row >= N_TOK) return;
    const float4* e4 = (const float4*)(elog + (size_t)row * NE);
    float4 a = e4[0], b = e4[1];
    float e[8] = {a.x, a.y, a.z, a.w, b.x, b.y, b.z, b.w};
    int id0 = 0;
    float b0 = e[0];
#pragma unroll
    for (int t = 1; t < 8; ++t)
        if (e[t] > b0) { b0 = e[t]; id0 = t; }
    int id1 = -1;
    float b1 = -INFINITY;
#pragma unroll
    for (int t = 0; t < 8; ++t)
        if (t != id0 && e[t] > b1) { b1 = e[t]; id1 = t; }
    float s = b0 + b1;
    w_out[row * 2 + 0] = b0 / s;
    w_out[row * 2 + 1] = b1 / s;
    id_out[row * 2 + 0] = (float)id0;
    id_out[row * 2 + 1] = (float)id1;
    ids_int[row * 2 + 0] = id0;
    ids_int[row * 2 + 1] = id1;
}

// ---------------- stable argsort of 4096 expert ids (counting rank) ----------------
__global__ __launch_bounds__(256) void sort_k(const int* __restrict__ ids,
                                              float* __restrict__ reorder_out,
                                              int* __restrict__ perm) {
    __shared__ int sh[N_TOK * TOPK];
    int tid = threadIdx.x;
    for (int r = tid; r < N_TOK * TOPK; r += 256) sh[r] = ids[r];
    __syncthreads();
    int i = blockIdx.x * 256 + tid;
    int e = sh[i];
    int rank = 0;
    for (int j = 0; j < N_TOK * TOPK; ++j) {
        int ej = sh[j];
        rank += (ej < e) ? 1 : ((ej == e && j < i) ? 1 : 0);
    }
    reorder_out[rank] = (float)i;
    perm[rank] = i;
}

// ---------------- permuted row gather ----------------
__global__ __launch_bounds__(256) void gather_k(const float* __restrict__ src,
                                                const int* __restrict__ perm,
                                                float* __restrict__ dst) {
    int r = blockIdx.x;
    int srow = perm[r] >> 1;  // // TOPK
    const float4* s4 = (const float4*)(src + (size_t)srow * H_DIM);
    float4* d4 = (float4*)(dst + (size_t)r * H_DIM);
    int tid = threadIdx.x;
#pragma unroll
    for (int k = 0; k < 4; ++k) d4[tid + k * 256] = s4[tid + k * 256];
}

extern "C" void kernel_launch(void* const* d_in, const int* in_sizes, int n_in,
                              void* d_out, int out_size, void* d_ws, size_t ws_size,
                              hipStream_t stream) {
    const int*   positions = (const int*)d_in[0];
    const float* hidden    = (const float*)d_in[1];
    const float* w_qkv     = (const float*)d_in[2];
    const float* w_o       = (const float*)d_in[3];
    // d_in[4] = w_gate: dead code in reference
    const float* rms_pre   = (const float*)d_in[5];
    const float* rms_post  = (const float*)d_in[6];
    const float* elog      = (const float*)d_in[7];
    float* out = (float*)d_out;

    char* ws = (char*)d_ws;
    unsigned short* wqkvT = (unsigned short*)(ws);                 // [0, 50.3M) until qkv-gemm
    unsigned short* woT   = (unsigned short*)(ws);                 // [0, 33.5M) conv2..o-gemm
    float*          post  = (float*)(ws + 33554432ULL);            // [33.5M, 67.1M) rms2..gather
    unsigned short* xn    = (unsigned short*)(ws + 50331648ULL);   // [50.3M, 67.1M) rms1..qkv-gemm
    unsigned short* aout  = (unsigned short*)(ws + 50331648ULL);   // [50.3M, 67.1M) attn..o-gemm
    unsigned short* qkvb  = (unsigned short*)(ws + 67108864ULL);   // [67.1M, 92.3M) bf16 qkv
    float*          sbuf  = (float*)(ws + 67108864ULL);            // [67.1M, 100.7M) o-gemm..rms2
    unsigned short* Qc    = (unsigned short*)(ws + 117440512ULL);  // 16 MB
    unsigned short* Kc    = (unsigned short*)(ws + 134217728ULL);  // 4 MB
    unsigned short* Vt    = (unsigned short*)(ws + 138412032ULL);  // 4 MB
    int* ids_int  = (int*)(ws + 142606336ULL);
    int* perm_int = (int*)(ws + 142622720ULL);

    // 1. w_qkv -> bf16 transposed [6144][4096]
    convT_k<<<dim3(QKV_D / 64, H_DIM / 64), 256, 0, stream>>>(w_qkv, wqkvT, H_DIM, QKV_D);
    // 2. pre-attention RMSNorm -> bf16
    rmsnorm_k<<<N_TOK, 256, 0, stream>>>(hidden, rms_pre, nullptr, xn);
    // 3. QKV projection: 2-barrier 256^2 MFMA GEMM -> bf16 qkv
    gemm8_k<<<dim3(N_TOK / 256, QKV_D / 256), 512, 0, stream>>>(
        (const __hip_bfloat16*)xn, (const __hip_bfloat16*)wqkvT, qkvb, QKV_D);
    // 4. w_o -> bf16 transposed [4096][4096]  (reuses wqkvT region)
    convT_k<<<dim3(H_DIM / 64, H_DIM / 64), 256, 0, stream>>>(w_o, woT, H_DIM, H_DIM);
    // 5. RoPE + pack Qc/Kc bf16
    prep_k<<<N_TOK, 256, 0, stream>>>(qkvb, positions, Qc, Kc);
    // 6. V transpose -> Vt bf16
    vt_k<<<dim3(N_TOK / 64, NKV), 256, 0, stream>>>(qkvb, Vt);
    // 7. causal GQA flash attention (bf16 MFMA) -> bf16 attn_out
    attn_k<<<dim3(N_TOK / 64, 16), 512, 0, stream>>>(
        (const __hip_bfloat16*)Qc, (const __hip_bfloat16*)Kc, (const __hip_bfloat16*)Vt, aout);
    // 8. output projection + residual (2-phase bf16 MFMA) -> fp32 s
    gemm_k<<<dim3(N_TOK / 128, H_DIM / 128), 256, 0, stream>>>(
        (const __hip_bfloat16*)aout, (const __hip_bfloat16*)woT, sbuf, nullptr, hidden, H_DIM);
    // 9. post-attention RMSNorm -> fp32
    rmsnorm_k<<<N_TOK, 256, 0, stream>>>(sbuf, rms_post, post, nullptr);
    // 10. top-2 experts
    topk_k<<<N_TOK / 256, 256, 0, stream>>>(elog, out + OUT_W, out + OUT_IDS, ids_int);
    // 11. stable argsort of expert ids
    sort_k<<<(N_TOK * TOPK) / 256, 256, 0, stream>>>(ids_int, out + OUT_REO, perm_int);
    // 12. permuted gather
    gather_k<<<N_TOK * TOPK, 256, 0, stream>>>(post, perm_int, out + OUT_PERM);
}

// Round 7
// 668.637 us; speedup vs baseline: 1.2105x; 1.0686x over previous
//
#include <hip/hip_runtime.h>
#include <hip/hip_bf16.h>
#include <math.h>

// Problem constants
#define N_TOK 2048
#define H_DIM 4096
#define NH 32
#define NKV 8
#define HD 128
#define QKV_D 6144   // (NH + 2*NKV) * HD
#define NE 8
#define TOPK 2

// d_out layout (floats): permuted_output | topk_weights | topk_ids | reorder_ids
#define OUT_PERM 0
#define OUT_W    16777216   // 4096*4096
#define OUT_IDS  16781312
#define OUT_REO  16785408

typedef __bf16 bf16x8 __attribute__((ext_vector_type(8)));
typedef float f32x4 __attribute__((ext_vector_type(4)));

typedef __attribute__((address_space(3))) void lds_void;
typedef __attribute__((address_space(1))) const void gbl_void;

__device__ __forceinline__ void gld16(const void* g, void* l) {
    // async global->LDS, 16B per lane; LDS dest = wave-uniform base + lane*16
    __builtin_amdgcn_global_load_lds((gbl_void*)g, (lds_void*)l, 16, 0, 0);
}

__device__ __forceinline__ unsigned short f2bf(float f) {
    union { float f; unsigned u; } v; v.f = f;
    unsigned r = v.u + 0x7fff + ((v.u >> 16) & 1);
    return (unsigned short)(r >> 16);
}
__device__ __forceinline__ unsigned pack2bf(float a, float b) {
    return (unsigned)f2bf(a) | ((unsigned)f2bf(b) << 16);
}
__device__ __forceinline__ float bf2f(unsigned short u) {
    union { unsigned u; float f; } v; v.u = ((unsigned)u) << 16;
    return v.f;
}

// ---------------- RMSNorm (fp32 in; fp32 or bf16 out) ----------------
__global__ __launch_bounds__(256) void rmsnorm_k(const float* __restrict__ x,
                                                 const float* __restrict__ w,
                                                 float* __restrict__ yf,
                                                 unsigned short* __restrict__ yb) {
    int row = blockIdx.x;
    int tid = threadIdx.x;
    const float4* x4 = (const float4*)(x + (size_t)row * H_DIM);
    const float4* w4 = (const float4*)w;
    float4 v[4];
    float ss = 0.f;
#pragma unroll
    for (int k = 0; k < 4; ++k) {
        v[k] = x4[tid + k * 256];
        ss += v[k].x * v[k].x + v[k].y * v[k].y + v[k].z * v[k].z + v[k].w * v[k].w;
    }
#pragma unroll
    for (int off = 32; off; off >>= 1) ss += __shfl_xor(ss, off);
    __shared__ float sacc[4];
    if ((tid & 63) == 0) sacc[tid >> 6] = ss;
    __syncthreads();
    float tot = sacc[0] + sacc[1] + sacc[2] + sacc[3];
    float sc = rsqrtf(tot * (1.0f / H_DIM) + 1e-6f);
#pragma unroll
    for (int k = 0; k < 4; ++k) {
        float4 ww = w4[tid + k * 256];
        float4 o;
        o.x = v[k].x * sc * ww.x;
        o.y = v[k].y * sc * ww.y;
        o.z = v[k].z * sc * ww.z;
        o.w = v[k].w * sc * ww.w;
        if (yf) {
            *(float4*)(yf + (size_t)row * H_DIM + (tid + k * 256) * 4) = o;
        } else {
            uint2 p;
            p.x = pack2bf(o.x, o.y);
            p.y = pack2bf(o.z, o.w);
            *(uint2*)(yb + (size_t)row * H_DIM + (tid + k * 256) * 4) = p;
        }
    }
}

// ---------------- transpose + fp32->bf16 weight conversion ----------------
// src[R][C] fp32 -> dst[C][R] bf16 (64x64 tiles)
__global__ __launch_bounds__(256) void convT_k(const float* __restrict__ src,
                                               unsigned short* __restrict__ dst,
                                               int R, int C) {
    __shared__ float t[64][68];
    int r0 = blockIdx.y * 64, c0 = blockIdx.x * 64;
    int tid = threadIdx.x;
    int lr = tid >> 4, lc = tid & 15;
#pragma unroll
    for (int it = 0; it < 4; ++it) {
        int r = lr + it * 16;
        float4 v = *(const float4*)(src + (size_t)(r0 + r) * C + c0 + lc * 4);
        *(float4*)&t[r][lc * 4] = v;
    }
    __syncthreads();
#pragma unroll
    for (int it = 0; it < 4; ++it) {
        int cc = lr + it * 16;
        uint2 o;
        o.x = pack2bf(t[lc * 4 + 0][cc], t[lc * 4 + 1][cc]);
        o.y = pack2bf(t[lc * 4 + 2][cc], t[lc * 4 + 3][cc]);
        *(uint2*)(dst + (size_t)(c0 + cc) * R + r0 + lc * 4) = o;
    }
}

// ---------------- full-fill 256xBN bf16 MFMA GEMM (2-barrier schedule) ----------------
// BM=256, BN in {192,128} chosen so grid == 256 blocks (1/CU, full chip fill).
// BK=64, 8 waves (2M x 4N), per-wave 128 x BN/4 output. LDS: A 64KB + B 2*BN*128B.
// Schedule per K-tile (carried from verified R6 kernel):
//   region1: ds_read A0-3 + all B; stage A(j+1); setprio+MFMA     | mid barrier
//   region2: ds_read A4-7; stage B(j+2); setprio+MFMA; vmcnt(NT)  | end barrier
// vmcnt ledger (NT = BN/64 = B loads per thread per tile; A = 4 loads):
//   end-of-tile vmcnt(NT) leaves exactly B(j+2) in flight -> A(j+1), B(j+1)
//   proven resident for tile j+1. Tails drain with vmcnt(0).
// Mid barrier: all waves' B-reads of tile j done (sched_barrier-pinned) ->
//   safe to overwrite Bs[d] with B(j+2). End barrier: As[d^1] readers done.
// XOR swizzle on pre-swizzled GLOBAL source unit, mirrored on ds_read (rule #21).
template<int BN, bool BF16OUT>
__global__ __launch_bounds__(512) void gemm256_k(const __hip_bfloat16* __restrict__ A,
                                                 const __hip_bfloat16* __restrict__ Bt,
                                                 float* __restrict__ C,
                                                 unsigned short* __restrict__ Cb,
                                                 const float* __restrict__ residual,
                                                 int Ncols) {
    constexpr int NT = BN / 64;    // per-wave n-tiles AND B-stage loads/thread
    __shared__ __align__(16) __hip_bfloat16 As[2][256 * 64];  // 64 KB
    __shared__ __align__(16) __hip_bfloat16 Bs[2][BN * 64];   // 48/32 KB
    const int K = H_DIM;
    int tid = threadIdx.x, w = tid >> 6, lane = tid & 63;
    int quad = lane >> 4, l15 = lane & 15;
    int wr = w >> 2, wc = w & 3;       // wave grid 2M x 4N

    // XCD-aware bijective block swizzle (nwg == 256, %8 == 0)
    int gx = gridDim.x;
    int nwg = gx * gridDim.y;
    int v = blockIdx.y * gx + blockIdx.x;
    int lin = (v & 7) * (nwg >> 3) + (v >> 3);
    int m0 = (lin % gx) * 256, n0 = (lin / gx) * BN;

    const char* Abase = (const char*)A + (size_t)m0 * (K * 2);
    const char* Bbase = (const char*)Bt + (size_t)n0 * (K * 2);
    int srow = w * 8 + (lane >> 3);    // 0..63 stage row group

    // stage 64*L rows x 128 B; linear LDS dest, source unit pre-swizzled
    auto stageA = [&](char* lbase, size_t kbyte) {
#pragma unroll
        for (int l = 0; l < 4; ++l) {
            int r = l * 64 + srow;                  // 0..255
            int gu = (lane & 7) ^ (r & 7);
            gld16(Abase + (size_t)r * (K * 2) + kbyte + gu * 16,
                  lbase + (size_t)(l * 64 + w * 8) * 128);
        }
    };
    auto stageB = [&](char* lbase, size_t kbyte) {
#pragma unroll
        for (int l = 0; l < NT; ++l) {
            int r = l * 64 + srow;                  // 0..BN-1
            int gu = (lane & 7) ^ (r & 7);
            gld16(Bbase + (size_t)r * (K * 2) + kbyte + gu * 16,
                  lbase + (size_t)(l * 64 + w * 8) * 128);
        }
    };

    f32x4 acc[8][NT];
#pragma unroll
    for (int i = 0; i < 8; ++i)
#pragma unroll
        for (int j = 0; j < NT; ++j) acc[i][j] = (f32x4){0.f, 0.f, 0.f, 0.f};

    const int ntiles = K / 64;   // 64

    // prologue: A(0), B(0), B(1); wait all but B(1) (NT loads stay in flight)
    stageA((char*)&As[0][0], 0);
    stageB((char*)&Bs[0][0], 0);
    stageB((char*)&Bs[1][0], 128);
    if constexpr (NT == 3) asm volatile("s_waitcnt vmcnt(3)" ::: "memory");
    else                   asm volatile("s_waitcnt vmcnt(2)" ::: "memory");
    __builtin_amdgcn_sched_barrier(0);
    __builtin_amdgcn_s_barrier();
    __builtin_amdgcn_sched_barrier(0);

    for (int j = 0; j < ntiles; ++j) {
        int d = j & 1;
        const char* sA = (const char*)&As[d][0];
        const char* sB = (const char*)&Bs[d][0];
        size_t kb1 = (size_t)(j + 1) * 128, kb2 = (size_t)(j + 2) * 128;
        bf16x8 aR[4][2], bR[NT][2];

        // ========== region 1: A[mt0-3] + all B reads; stage A(j+1); MFMA ==========
#pragma unroll
        for (int mt = 0; mt < 4; ++mt)
#pragma unroll
            for (int kk = 0; kk < 2; ++kk) {
                int m = wr * 128 + mt * 16 + l15;
                aR[mt][kk] = *(const bf16x8*)(sA + m * 128 + (((kk * 4 + quad) ^ (m & 7)) * 16));
            }
#pragma unroll
        for (int nt = 0; nt < NT; ++nt)
#pragma unroll
            for (int kk = 0; kk < 2; ++kk) {
                int n = wc * (NT * 16) + nt * 16 + l15;
                bR[nt][kk] = *(const bf16x8*)(sB + n * 128 + (((kk * 4 + quad) ^ (n & 7)) * 16));
            }
        if (j + 1 < ntiles) stageA((char*)&As[d ^ 1][0], kb1);
        __builtin_amdgcn_s_setprio(1);
#pragma unroll
        for (int mt = 0; mt < 4; ++mt)
#pragma unroll
            for (int nt = 0; nt < NT; ++nt)
#pragma unroll
                for (int kk = 0; kk < 2; ++kk)
                    acc[mt][nt] = __builtin_amdgcn_mfma_f32_16x16x32_bf16(aR[mt][kk], bR[nt][kk], acc[mt][nt], 0, 0, 0);
        __builtin_amdgcn_s_setprio(0);
        __builtin_amdgcn_sched_barrier(0);
        __builtin_amdgcn_s_barrier();      // mid: all waves' B-reads of tile j done
        __builtin_amdgcn_sched_barrier(0);

        // ========== region 2: A[mt4-7] reads; stage B(j+2); MFMA; counted vmcnt ==========
#pragma unroll
        for (int mt = 0; mt < 4; ++mt)
#pragma unroll
            for (int kk = 0; kk < 2; ++kk) {
                int m = wr * 128 + (mt + 4) * 16 + l15;
                aR[mt][kk] = *(const bf16x8*)(sA + m * 128 + (((kk * 4 + quad) ^ (m & 7)) * 16));
            }
        if (j + 2 < ntiles) stageB((char*)&Bs[d][0], kb2);
        __builtin_amdgcn_s_setprio(1);
#pragma unroll
        for (int mt = 0; mt < 4; ++mt)
#pragma unroll
            for (int nt = 0; nt < NT; ++nt)
#pragma unroll
                for (int kk = 0; kk < 2; ++kk)
                    acc[mt + 4][nt] = __builtin_amdgcn_mfma_f32_16x16x32_bf16(aR[mt][kk], bR[nt][kk], acc[mt + 4][nt], 0, 0, 0);
        __builtin_amdgcn_s_setprio(0);
        if (j + 2 < ntiles) {
            if constexpr (NT == 3) asm volatile("s_waitcnt vmcnt(3)" ::: "memory");
            else                   asm volatile("s_waitcnt vmcnt(2)" ::: "memory");
        } else {
            asm volatile("s_waitcnt vmcnt(0)" ::: "memory");   // tail: drain
        }
        __builtin_amdgcn_sched_barrier(0);
        __builtin_amdgcn_s_barrier();      // end: tile j+1 resident; A-readers done
        __builtin_amdgcn_sched_barrier(0);
    }

    // epilogue: C/D layout col=lane&15, row=quad*4+reg
#pragma unroll
    for (int mt = 0; mt < 8; ++mt)
#pragma unroll
        for (int nt = 0; nt < NT; ++nt)
#pragma unroll
            for (int r = 0; r < 4; ++r) {
                int row = m0 + wr * 128 + mt * 16 + quad * 4 + r;
                int col = n0 + wc * (NT * 16) + nt * 16 + l15;
                size_t off = (size_t)row * Ncols + col;
                if constexpr (BF16OUT) {
                    Cb[off] = f2bf(acc[mt][nt][r]);
                } else {
                    float vv = acc[mt][nt][r];
                    if (residual) vv += residual[off];
                    C[off] = vv;
                }
            }
}

// ---------------- prep: RoPE + pack Qc (scaled bf16) and Kc (bf16, per-head rows) ----
__global__ __launch_bounds__(256) void prep_k(const unsigned short* __restrict__ qkvb,
                                              const int* __restrict__ pos,
                                              unsigned short* __restrict__ Qc,
                                              unsigned short* __restrict__ Kc) {
    int row = blockIdx.x, tid = threadIdx.x;
    float fpos = (float)pos[row];
    const float scale = 0.08838834764831845f;  // 1/sqrt(128)
    const float lg = 0.20762050593045f;        // log2(10000)/64
#pragma unroll
    for (int it = 0; it < 8; ++it) {
        int pi = tid + it * 256;        // 0..2047 : q pairs
        int head = pi >> 6, t = pi & 63;
        float inv = exp2f(-(float)t * lg);
        float ang = fpos * inv;
        float s = __sinf(ang), c = __cosf(ang);
        const unsigned short* bp = qkvb + (size_t)row * QKV_D + head * HD + t;
        float x1 = bf2f(bp[0]), x2 = bf2f(bp[64]);
        unsigned short* qb = Qc + (size_t)row * H_DIM + head * HD + t;
        qb[0]  = f2bf((x1 * c - x2 * s) * scale);
        qb[64] = f2bf((x2 * c + x1 * s) * scale);
    }
#pragma unroll
    for (int it = 0; it < 2; ++it) {
        int pi = tid + it * 256;        // 0..511 : k pairs
        int kvh = pi >> 6, t = pi & 63;
        float inv = exp2f(-(float)t * lg);
        float ang = fpos * inv;
        float s = __sinf(ang), c = __cosf(ang);
        const unsigned short* bp = qkvb + (size_t)row * QKV_D + H_DIM + kvh * HD + t;
        float x1 = bf2f(bp[0]), x2 = bf2f(bp[64]);
        unsigned short* kb = Kc + ((size_t)kvh * N_TOK + row) * HD + t;
        kb[0]  = f2bf(x1 * c - x2 * s);
        kb[64] = f2bf(x2 * c + x1 * s);
    }
}

// ---------------- V transpose: bf16 qkv V section -> Vt[kvh][d][key] ----------------
__global__ __launch_bounds__(256) void vt_k(const unsigned short* __restrict__ qkvb,
                                            unsigned short* __restrict__ Vt) {
    __shared__ unsigned short ts[64][136];
    int j0 = blockIdx.x * 64, kvh = blockIdx.y, tid = threadIdx.x;
#pragma unroll
    for (int it = 0; it < 4; ++it) {
        int idx = tid + it * 256;   // 16B slots of 64x128 ushort tile
        int r = idx >> 4, c8 = idx & 15;
        *(uint4*)&ts[r][c8 * 8] =
            *(const uint4*)(qkvb + (size_t)(j0 + r) * QKV_D + (NH + NKV) * HD + kvh * HD + c8 * 8);
    }
    __syncthreads();
    int d = tid >> 1, half = tid & 1;
    unsigned short* dst = Vt + ((size_t)kvh * HD + d) * N_TOK + j0 + half * 32;
#pragma unroll
    for (int g = 0; g < 4; ++g) {
        int kb = half * 32 + g * 8;
        uint4 o;
        o.x = (unsigned)ts[kb + 0][d] | ((unsigned)ts[kb + 1][d] << 16);
        o.y = (unsigned)ts[kb + 2][d] | ((unsigned)ts[kb + 3][d] << 16);
        o.z = (unsigned)ts[kb + 4][d] | ((unsigned)ts[kb + 5][d] << 16);
        o.w = (unsigned)ts[kb + 6][d] | ((unsigned)ts[kb + 7][d] << 16);
        *(uint4*)(dst + g * 8) = o;
    }
}

// ---------------- bf16 MFMA flash attention ----------------
// block = 512 threads / 8 waves: 64 q-rows x 2 heads (same kv-head group).
__global__ __launch_bounds__(512) void attn_k(const __hip_bfloat16* __restrict__ Qc,
                                              const __hip_bfloat16* __restrict__ Kc,
                                              const __hip_bfloat16* __restrict__ Vt,
                                              unsigned short* __restrict__ ao) {
    __shared__ __align__(16) __hip_bfloat16 Ks[2][32 * 128];   // [key][d], swizzled 16B units, 8KB/buf
    __shared__ __align__(16) __hip_bfloat16 Vs[2][128 * 32];   // [d][key], swizzled 16B units, 8KB/buf
    __shared__ __align__(16) unsigned short Pw[8][16 * 40];    // per-wave P, row stride 80B

    int tid = threadIdx.x, w = tid >> 6, lane = tid & 63;
    int quad = lane >> 4, l15 = lane & 15;
    int pr = blockIdx.y;                 // 0..15: (kvh, head-pair)
    int kvh = pr >> 1;
    int h = kvh * 4 + (pr & 1) * 2 + (w & 1);
    int qt = gridDim.x - 1 - blockIdx.x; // heavy tiles first
    int i0 = qt * 64;
    int i0q = i0 + (w >> 1) * 16;
    int q = i0q + l15;

    bf16x8 qf[4];
    const __hip_bfloat16* qrow = Qc + (size_t)q * H_DIM + h * HD;
#pragma unroll
    for (int kf = 0; kf < 4; ++kf)
        qf[kf] = *(const bf16x8*)(qrow + kf * 32 + quad * 8);

    const char* KcH = (const char*)(Kc + (size_t)kvh * N_TOK * HD);
    const char* VtH = (const char*)(Vt + (size_t)kvh * HD * N_TOK);

    int kKey = w * 4 + (lane >> 4);
    int kPart = (lane & 15) ^ (kKey & 15);
    int vD = w * 16 + (lane >> 2);
    int vP = (lane & 3) ^ (vD & 3);
    char* Kl[2] = { (char*)&Ks[0][0] + w * 1024, (char*)&Ks[1][0] + w * 1024 };
    char* Vl[2] = { (char*)&Vs[0][0] + w * 1024, (char*)&Vs[1][0] + w * 1024 };

    float mstat = -INFINITY, lstat = 0.f;
    f32x4 o[8];
#pragma unroll
    for (int nt = 0; nt < 8; ++nt) o[nt] = (f32x4){0.f, 0.f, 0.f, 0.f};

    int nsteps = (i0 + 64) >> 5;

    gld16(KcH + (size_t)kKey * 256 + kPart * 16, Kl[0]);
    gld16(VtH + (size_t)vD * (N_TOK * 2) + vP * 16, Vl[0]);
    __syncthreads();

    for (int t = 0; t < nsteps; ++t) {
        int j0 = t << 5;
        int cur = t & 1;
        if (t + 1 < nsteps) {
            int jn = j0 + 32;
            gld16(KcH + (size_t)(jn + kKey) * 256 + kPart * 16, Kl[cur ^ 1]);
            gld16(VtH + (size_t)vD * (N_TOK * 2) + (size_t)jn * 2 + vP * 16, Vl[cur ^ 1]);
        }
        if (j0 <= i0q + 15) {
            const char* Kb = (const char*)&Ks[cur][0];
            const char* Vb = (const char*)&Vs[cur][0];

            f32x4 s[2];
            s[0] = (f32x4){0.f, 0.f, 0.f, 0.f};
            s[1] = (f32x4){0.f, 0.f, 0.f, 0.f};
#pragma unroll
            for (int mt = 0; mt < 2; ++mt) {
                int key = mt * 16 + l15;
#pragma unroll
                for (int kf = 0; kf < 4; ++kf) {
                    bf16x8 kfr = *(const bf16x8*)(Kb + key * 256 + (((kf * 4 + quad) ^ (key & 15)) * 16));
                    s[mt] = __builtin_amdgcn_mfma_f32_16x16x32_bf16(kfr, qf[kf], s[mt], 0, 0, 0);
                }
            }
            if (j0 + 31 > i0q) {
#pragma unroll
                for (int mt = 0; mt < 2; ++mt) {
                    int keyb = j0 + mt * 16 + quad * 4;
#pragma unroll
                    for (int r = 0; r < 4; ++r)
                        if (keyb + r > q) s[mt][r] = -INFINITY;
                }
            }
            float mx = fmaxf(fmaxf(fmaxf(s[0][0], s[0][1]), fmaxf(s[0][2], s[0][3])),
                             fmaxf(fmaxf(s[1][0], s[1][1]), fmaxf(s[1][2], s[1][3])));
            mx = fmaxf(mx, __shfl_xor(mx, 16));
            mx = fmaxf(mx, __shfl_xor(mx, 32));
            float newm = fmaxf(mstat, mx);
            float alpha = __expf(mstat - newm);
            float p[8];
#pragma unroll
            for (int mt = 0; mt < 2; ++mt)
#pragma unroll
                for (int r = 0; r < 4; ++r) p[mt * 4 + r] = __expf(s[mt][r] - newm);
            float ps = p[0] + p[1] + p[2] + p[3] + p[4] + p[5] + p[6] + p[7];
            ps += __shfl_xor(ps, 16);
            ps += __shfl_xor(ps, 32);
            lstat = lstat * alpha + ps;
            mstat = newm;

            unsigned* pwb = (unsigned*)(&Pw[w][0]);
            int eo = l15 * 20 + quad * 2;
            pwb[eo]     = pack2bf(p[0], p[1]);
            pwb[eo + 1] = pack2bf(p[2], p[3]);
            pwb[eo + 8] = pack2bf(p[4], p[5]);
            pwb[eo + 9] = pack2bf(p[6], p[7]);
            bf16x8 pf = *(const bf16x8*)(&Pw[w][l15 * 40 + quad * 8]);

            float alq[4];
#pragma unroll
            for (int r = 0; r < 4; ++r) alq[r] = __shfl(alpha, quad * 4 + r);
#pragma unroll
            for (int nt = 0; nt < 8; ++nt)
#pragma unroll
                for (int r = 0; r < 4; ++r) o[nt][r] *= alq[r];

#pragma unroll
            for (int nt = 0; nt < 8; ++nt) {
                int d = nt * 16 + l15;
                bf16x8 vf = *(const bf16x8*)(Vb + d * 64 + ((quad ^ (d & 3)) * 16));
                o[nt] = __builtin_amdgcn_mfma_f32_16x16x32_bf16(pf, vf, o[nt], 0, 0, 0);
            }
        }
        __syncthreads();
    }

    float linv[4];
#pragma unroll
    for (int r = 0; r < 4; ++r) linv[r] = 1.f / __shfl(lstat, quad * 4 + r);
#pragma unroll
    for (int nt = 0; nt < 8; ++nt)
#pragma unroll
        for (int r = 0; r < 4; ++r) {
            int row = i0q + quad * 4 + r;
            int col = h * HD + nt * 16 + l15;
            ao[(size_t)row * H_DIM + col] = f2bf(o[nt][r] * linv[r]);
        }
}

// ---------------- top-2 routing ----------------
__global__ __launch_bounds__(256) void topk_k(const float* __restrict__ elog,
                                              float* __restrict__ w_out,
                                              float* __restrict__ id_out,
                                              int* __restrict__ ids_int) {
    int row = blockIdx.x * 256 + threadIdx.x;
    if (row >= N_TOK) return;
    const float4* e4 = (const float4*)(elog + (size_t)row * NE);
    float4 a = e4[0], b = e4[1];
    float e[8] = {a.x, a.y, a.z, a.w, b.x, b.y, b.z, b.w};
    int id0 = 0;
    float b0 = e[0];
#pragma unroll
    for (int t = 1; t < 8; ++t)
        if (e[t] > b0) { b0 = e[t]; id0 = t; }
    int id1 = -1;
    float b1 = -INFINITY;
#pragma unroll
    for (int t = 0; t < 8; ++t)
        if (t != id0 && e[t] > b1) { b1 = e[t]; id1 = t; }
    float s = b0 + b1;
    w_out[row * 2 + 0] = b0 / s;
    w_out[row * 2 + 1] = b1 / s;
    id_out[row * 2 + 0] = (float)id0;
    id_out[row * 2 + 1] = (float)id1;
    ids_int[row * 2 + 0] = id0;
    ids_int[row * 2 + 1] = id1;
}

// ---------------- stable argsort of 4096 expert ids (counting rank) ----------------
__global__ __launch_bounds__(256) void sort_k(const int* __restrict__ ids,
                                              float* __restrict__ reorder_out,
                                              int* __restrict__ perm) {
    __shared__ int sh[N_TOK * TOPK];
    int tid = threadIdx.x;
    for (int r = tid; r < N_TOK * TOPK; r += 256) sh[r] = ids[r];
    __syncthreads();
    int i = blockIdx.x * 256 + tid;
    int e = sh[i];
    int rank = 0;
    for (int j = 0; j < N_TOK * TOPK; ++j) {
        int ej = sh[j];
        rank += (ej < e) ? 1 : ((ej == e && j < i) ? 1 : 0);
    }
    reorder_out[rank] = (float)i;
    perm[rank] = i;
}

// ---------------- permuted row gather ----------------
__global__ __launch_bounds__(256) void gather_k(const float* __restrict__ src,
                                                const int* __restrict__ perm,
                                                float* __restrict__ dst) {
    int r = blockIdx.x;
    int srow = perm[r] >> 1;  // // TOPK
    const float4* s4 = (const float4*)(src + (size_t)srow * H_DIM);
    float4* d4 = (float4*)(dst + (size_t)r * H_DIM);
    int tid = threadIdx.x;
#pragma unroll
    for (int k = 0; k < 4; ++k) d4[tid + k * 256] = s4[tid + k * 256];
}

extern "C" void kernel_launch(void* const* d_in, const int* in_sizes, int n_in,
                              void* d_out, int out_size, void* d_ws, size_t ws_size,
                              hipStream_t stream) {
    const int*   positions = (const int*)d_in[0];
    const float* hidden    = (const float*)d_in[1];
    const float* w_qkv     = (const float*)d_in[2];
    const float* w_o       = (const float*)d_in[3];
    // d_in[4] = w_gate: dead code in reference
    const float* rms_pre   = (const float*)d_in[5];
    const float* rms_post  = (const float*)d_in[6];
    const float* elog      = (const float*)d_in[7];
    float* out = (float*)d_out;

    char* ws = (char*)d_ws;
    unsigned short* wqkvT = (unsigned short*)(ws);                 // [0, 50.3M) until qkv-gemm
    unsigned short* woT   = (unsigned short*)(ws);                 // [0, 33.5M) conv2..o-gemm
    float*          post  = (float*)(ws + 33554432ULL);            // [33.5M, 67.1M) rms2..gather
    unsigned short* xn    = (unsigned short*)(ws + 50331648ULL);   // [50.3M, 67.1M) rms1..qkv-gemm
    unsigned short* aout  = (unsigned short*)(ws + 50331648ULL);   // [50.3M, 67.1M) attn..o-gemm
    unsigned short* qkvb  = (unsigned short*)(ws + 67108864ULL);   // [67.1M, 92.3M) bf16 qkv
    float*          sbuf  = (float*)(ws + 67108864ULL);            // [67.1M, 100.7M) o-gemm..rms2
    unsigned short* Qc    = (unsigned short*)(ws + 117440512ULL);  // 16 MB
    unsigned short* Kc    = (unsigned short*)(ws + 134217728ULL);  // 4 MB
    unsigned short* Vt    = (unsigned short*)(ws + 138412032ULL);  // 4 MB
    int* ids_int  = (int*)(ws + 142606336ULL);
    int* perm_int = (int*)(ws + 142622720ULL);

    // 1. w_qkv -> bf16 transposed [6144][4096]
    convT_k<<<dim3(QKV_D / 64, H_DIM / 64), 256, 0, stream>>>(w_qkv, wqkvT, H_DIM, QKV_D);
    // 2. pre-attention RMSNorm -> bf16
    rmsnorm_k<<<N_TOK, 256, 0, stream>>>(hidden, rms_pre, nullptr, xn);
    // 3. QKV projection: 256x192 full-fill GEMM (8x32 = 256 blocks) -> bf16 qkv
    gemm256_k<192, true><<<dim3(N_TOK / 256, QKV_D / 192), 512, 0, stream>>>(
        (const __hip_bfloat16*)xn, (const __hip_bfloat16*)wqkvT, nullptr, qkvb, nullptr, QKV_D);
    // 4. w_o -> bf16 transposed [4096][4096]  (reuses wqkvT region)
    convT_k<<<dim3(H_DIM / 64, H_DIM / 64), 256, 0, stream>>>(w_o, woT, H_DIM, H_DIM);
    // 5. RoPE + pack Qc/Kc bf16
    prep_k<<<N_TOK, 256, 0, stream>>>(qkvb, positions, Qc, Kc);
    // 6. V transpose -> Vt bf16
    vt_k<<<dim3(N_TOK / 64, NKV), 256, 0, stream>>>(qkvb, Vt);
    // 7. causal GQA flash attention (bf16 MFMA) -> bf16 attn_out
    attn_k<<<dim3(N_TOK / 64, 16), 512, 0, stream>>>(
        (const __hip_bfloat16*)Qc, (const __hip_bfloat16*)Kc, (const __hip_bfloat16*)Vt, aout);
    // 8. output projection + residual: 256x128 full-fill GEMM (8x32 = 256 blocks) -> fp32 s
    gemm256_k<128, false><<<dim3(N_TOK / 256, H_DIM / 128), 512, 0, stream>>>(
        (const __hip_bfloat16*)aout, (const __hip_bfloat16*)woT, sbuf, nullptr, hidden, H_DIM);
    // 9. post-attention RMSNorm -> fp32
    rmsnorm_k<<<N_TOK, 256, 0, stream>>>(sbuf, rms_post, post, nullptr);
    // 10. top-2 experts
    topk_k<<<N_TOK / 256, 256, 0, stream>>>(elog, out + OUT_W, out + OUT_IDS, ids_int);
    // 11. stable argsort of expert ids
    sort_k<<<(N_TOK * TOPK) / 256, 256, 0, stream>>>(ids_int, out + OUT_REO, perm_int);
    // 12. permuted gather
    gather_k<<<N_TOK * TOPK, 256, 0, stream>>>(post, perm_int, out + OUT_PERM);
}

// Round 8
// 658.682 us; speedup vs baseline: 1.2288x; 1.0151x over previous
//
#include <hip/hip_runtime.h>
#include <hip/hip_bf16.h>
#include <math.h>

// Problem constants
#define N_TOK 2048
#define H_DIM 4096
#define NH 32
#define NKV 8
#define HD 128
#define QKV_D 6144   // (NH + 2*NKV) * HD
#define NE 8
#define TOPK 2

// d_out layout (floats): permuted_output | topk_weights | topk_ids | reorder_ids
#define OUT_PERM 0
#define OUT_W    16777216   // 4096*4096
#define OUT_IDS  16781312
#define OUT_REO  16785408

typedef __bf16 bf16x8 __attribute__((ext_vector_type(8)));
typedef float f32x4 __attribute__((ext_vector_type(4)));

typedef __attribute__((address_space(3))) void lds_void;
typedef __attribute__((address_space(1))) const void gbl_void;

__device__ __forceinline__ void gld16(const void* g, void* l) {
    // async global->LDS, 16B per lane; LDS dest = wave-uniform base + lane*16
    __builtin_amdgcn_global_load_lds((gbl_void*)g, (lds_void*)l, 16, 0, 0);
}

__device__ __forceinline__ unsigned short f2bf(float f) {
    union { float f; unsigned u; } v; v.f = f;
    unsigned r = v.u + 0x7fff + ((v.u >> 16) & 1);
    return (unsigned short)(r >> 16);
}
__device__ __forceinline__ unsigned pack2bf(float a, float b) {
    return (unsigned)f2bf(a) | ((unsigned)f2bf(b) << 16);
}
__device__ __forceinline__ float bf2f(unsigned short u) {
    union { unsigned u; float f; } v; v.u = ((unsigned)u) << 16;
    return v.f;
}

// ---------------- RMSNorm (fp32 in; fp32 or bf16 out) ----------------
__global__ __launch_bounds__(256) void rmsnorm_k(const float* __restrict__ x,
                                                 const float* __restrict__ w,
                                                 float* __restrict__ yf,
                                                 unsigned short* __restrict__ yb) {
    int row = blockIdx.x;
    int tid = threadIdx.x;
    const float4* x4 = (const float4*)(x + (size_t)row * H_DIM);
    const float4* w4 = (const float4*)w;
    float4 v[4];
    float ss = 0.f;
#pragma unroll
    for (int k = 0; k < 4; ++k) {
        v[k] = x4[tid + k * 256];
        ss += v[k].x * v[k].x + v[k].y * v[k].y + v[k].z * v[k].z + v[k].w * v[k].w;
    }
#pragma unroll
    for (int off = 32; off; off >>= 1) ss += __shfl_xor(ss, off);
    __shared__ float sacc[4];
    if ((tid & 63) == 0) sacc[tid >> 6] = ss;
    __syncthreads();
    float tot = sacc[0] + sacc[1] + sacc[2] + sacc[3];
    float sc = rsqrtf(tot * (1.0f / H_DIM) + 1e-6f);
#pragma unroll
    for (int k = 0; k < 4; ++k) {
        float4 ww = w4[tid + k * 256];
        float4 o;
        o.x = v[k].x * sc * ww.x;
        o.y = v[k].y * sc * ww.y;
        o.z = v[k].z * sc * ww.z;
        o.w = v[k].w * sc * ww.w;
        if (yf) {
            *(float4*)(yf + (size_t)row * H_DIM + (tid + k * 256) * 4) = o;
        } else {
            uint2 p;
            p.x = pack2bf(o.x, o.y);
            p.y = pack2bf(o.z, o.w);
            *(uint2*)(yb + (size_t)row * H_DIM + (tid + k * 256) * 4) = p;
        }
    }
}

// ---------------- transpose + fp32->bf16 weight conversion ----------------
// src[R][C] fp32 -> dst[C][R] bf16 (64x64 tiles)
__global__ __launch_bounds__(256) void convT_k(const float* __restrict__ src,
                                               unsigned short* __restrict__ dst,
                                               int R, int C) {
    __shared__ float t[64][68];
    int r0 = blockIdx.y * 64, c0 = blockIdx.x * 64;
    int tid = threadIdx.x;
    int lr = tid >> 4, lc = tid & 15;
#pragma unroll
    for (int it = 0; it < 4; ++it) {
        int r = lr + it * 16;
        float4 v = *(const float4*)(src + (size_t)(r0 + r) * C + c0 + lc * 4);
        *(float4*)&t[r][lc * 4] = v;
    }
    __syncthreads();
#pragma unroll
    for (int it = 0; it < 4; ++it) {
        int cc = lr + it * 16;
        uint2 o;
        o.x = pack2bf(t[lc * 4 + 0][cc], t[lc * 4 + 1][cc]);
        o.y = pack2bf(t[lc * 4 + 2][cc], t[lc * 4 + 3][cc]);
        *(uint2*)(dst + (size_t)(c0 + cc) * R + r0 + lc * 4) = o;
    }
}

// ---------------- full-fill 256xBN bf16 MFMA GEMM (2-barrier schedule) ----------------
// BM=256, BN in {192,128} chosen so grid == 256 blocks (1/CU, full chip fill).
// BK=64, 8 waves (2M x 4N), per-wave 128 x BN/4 output. LDS: A 64KB + B 2*BN*128B.
// Schedule per K-tile:
//   region1: ds_read A0-3 + all B; stage A(j+1); setprio+MFMA     | mid barrier
//   region2: ds_read A4-7; stage B(j+2); setprio+MFMA; vmcnt(NT)  | end barrier
// vmcnt ledger (NT = BN/64): end-of-tile vmcnt(NT) leaves exactly B(j+2) in
// flight -> A(j+1), B(j+1) proven resident. Tails drain with vmcnt(0).
// XOR swizzle on pre-swizzled GLOBAL source unit, mirrored on ds_read (rule #21).
template<int BN, bool BF16OUT>
__global__ __launch_bounds__(512) void gemm256_k(const __hip_bfloat16* __restrict__ A,
                                                 const __hip_bfloat16* __restrict__ Bt,
                                                 float* __restrict__ C,
                                                 unsigned short* __restrict__ Cb,
                                                 const float* __restrict__ residual,
                                                 int Ncols) {
    constexpr int NT = BN / 64;    // per-wave n-tiles AND B-stage loads/thread
    __shared__ __align__(16) __hip_bfloat16 As[2][256 * 64];  // 64 KB
    __shared__ __align__(16) __hip_bfloat16 Bs[2][BN * 64];   // 48/32 KB
    const int K = H_DIM;
    int tid = threadIdx.x, w = tid >> 6, lane = tid & 63;
    int quad = lane >> 4, l15 = lane & 15;
    int wr = w >> 2, wc = w & 3;       // wave grid 2M x 4N

    // XCD-aware bijective block swizzle (nwg == 256, %8 == 0)
    int gx = gridDim.x;
    int nwg = gx * gridDim.y;
    int v = blockIdx.y * gx + blockIdx.x;
    int lin = (v & 7) * (nwg >> 3) + (v >> 3);
    int m0 = (lin % gx) * 256, n0 = (lin / gx) * BN;

    const char* Abase = (const char*)A + (size_t)m0 * (K * 2);
    const char* Bbase = (const char*)Bt + (size_t)n0 * (K * 2);
    int srow = w * 8 + (lane >> 3);    // 0..63 stage row group

    auto stageA = [&](char* lbase, size_t kbyte) {
#pragma unroll
        for (int l = 0; l < 4; ++l) {
            int r = l * 64 + srow;                  // 0..255
            int gu = (lane & 7) ^ (r & 7);
            gld16(Abase + (size_t)r * (K * 2) + kbyte + gu * 16,
                  lbase + (size_t)(l * 64 + w * 8) * 128);
        }
    };
    auto stageB = [&](char* lbase, size_t kbyte) {
#pragma unroll
        for (int l = 0; l < NT; ++l) {
            int r = l * 64 + srow;                  // 0..BN-1
            int gu = (lane & 7) ^ (r & 7);
            gld16(Bbase + (size_t)r * (K * 2) + kbyte + gu * 16,
                  lbase + (size_t)(l * 64 + w * 8) * 128);
        }
    };

    f32x4 acc[8][NT];
#pragma unroll
    for (int i = 0; i < 8; ++i)
#pragma unroll
        for (int j = 0; j < NT; ++j) acc[i][j] = (f32x4){0.f, 0.f, 0.f, 0.f};

    const int ntiles = K / 64;   // 64

    // prologue: A(0), B(0), B(1); wait all but B(1) (NT loads stay in flight)
    stageA((char*)&As[0][0], 0);
    stageB((char*)&Bs[0][0], 0);
    stageB((char*)&Bs[1][0], 128);
    if constexpr (NT == 3) asm volatile("s_waitcnt vmcnt(3)" ::: "memory");
    else                   asm volatile("s_waitcnt vmcnt(2)" ::: "memory");
    __builtin_amdgcn_sched_barrier(0);
    __builtin_amdgcn_s_barrier();
    __builtin_amdgcn_sched_barrier(0);

    for (int j = 0; j < ntiles; ++j) {
        int d = j & 1;
        const char* sA = (const char*)&As[d][0];
        const char* sB = (const char*)&Bs[d][0];
        size_t kb1 = (size_t)(j + 1) * 128, kb2 = (size_t)(j + 2) * 128;
        bf16x8 aR[4][2], bR[NT][2];

        // ========== region 1: A[mt0-3] + all B reads; stage A(j+1); MFMA ==========
#pragma unroll
        for (int mt = 0; mt < 4; ++mt)
#pragma unroll
            for (int kk = 0; kk < 2; ++kk) {
                int m = wr * 128 + mt * 16 + l15;
                aR[mt][kk] = *(const bf16x8*)(sA + m * 128 + (((kk * 4 + quad) ^ (m & 7)) * 16));
            }
#pragma unroll
        for (int nt = 0; nt < NT; ++nt)
#pragma unroll
            for (int kk = 0; kk < 2; ++kk) {
                int n = wc * (NT * 16) + nt * 16 + l15;
                bR[nt][kk] = *(const bf16x8*)(sB + n * 128 + (((kk * 4 + quad) ^ (n & 7)) * 16));
            }
        if (j + 1 < ntiles) stageA((char*)&As[d ^ 1][0], kb1);
        __builtin_amdgcn_s_setprio(1);
#pragma unroll
        for (int mt = 0; mt < 4; ++mt)
#pragma unroll
            for (int nt = 0; nt < NT; ++nt)
#pragma unroll
                for (int kk = 0; kk < 2; ++kk)
                    acc[mt][nt] = __builtin_amdgcn_mfma_f32_16x16x32_bf16(aR[mt][kk], bR[nt][kk], acc[mt][nt], 0, 0, 0);
        __builtin_amdgcn_s_setprio(0);
        __builtin_amdgcn_sched_barrier(0);
        __builtin_amdgcn_s_barrier();      // mid: all waves' B-reads of tile j done
        __builtin_amdgcn_sched_barrier(0);

        // ========== region 2: A[mt4-7] reads; stage B(j+2); MFMA; counted vmcnt ==========
#pragma unroll
        for (int mt = 0; mt < 4; ++mt)
#pragma unroll
            for (int kk = 0; kk < 2; ++kk) {
                int m = wr * 128 + (mt + 4) * 16 + l15;
                aR[mt][kk] = *(const bf16x8*)(sA + m * 128 + (((kk * 4 + quad) ^ (m & 7)) * 16));
            }
        if (j + 2 < ntiles) stageB((char*)&Bs[d][0], kb2);
        __builtin_amdgcn_s_setprio(1);
#pragma unroll
        for (int mt = 0; mt < 4; ++mt)
#pragma unroll
            for (int nt = 0; nt < NT; ++nt)
#pragma unroll
                for (int kk = 0; kk < 2; ++kk)
                    acc[mt + 4][nt] = __builtin_amdgcn_mfma_f32_16x16x32_bf16(aR[mt][kk], bR[nt][kk], acc[mt + 4][nt], 0, 0, 0);
        __builtin_amdgcn_s_setprio(0);
        if (j + 2 < ntiles) {
            if constexpr (NT == 3) asm volatile("s_waitcnt vmcnt(3)" ::: "memory");
            else                   asm volatile("s_waitcnt vmcnt(2)" ::: "memory");
        } else {
            asm volatile("s_waitcnt vmcnt(0)" ::: "memory");   // tail: drain
        }
        __builtin_amdgcn_sched_barrier(0);
        __builtin_amdgcn_s_barrier();      // end: tile j+1 resident; A-readers done
        __builtin_amdgcn_sched_barrier(0);
    }

    // epilogue: C/D layout col=lane&15, row=quad*4+reg
#pragma unroll
    for (int mt = 0; mt < 8; ++mt)
#pragma unroll
        for (int nt = 0; nt < NT; ++nt)
#pragma unroll
            for (int r = 0; r < 4; ++r) {
                int row = m0 + wr * 128 + mt * 16 + quad * 4 + r;
                int col = n0 + wc * (NT * 16) + nt * 16 + l15;
                size_t off = (size_t)row * Ncols + col;
                if constexpr (BF16OUT) {
                    Cb[off] = f2bf(acc[mt][nt][r]);
                } else {
                    float vv = acc[mt][nt][r];
                    if (residual) vv += residual[off];
                    C[off] = vv;
                }
            }
}

// ---------------- prep: RoPE + pack Qc (scaled bf16) and Kc (bf16, per-head rows) ----
__global__ __launch_bounds__(256) void prep_k(const unsigned short* __restrict__ qkvb,
                                              const int* __restrict__ pos,
                                              unsigned short* __restrict__ Qc,
                                              unsigned short* __restrict__ Kc) {
    int row = blockIdx.x, tid = threadIdx.x;
    float fpos = (float)pos[row];
    const float scale = 0.08838834764831845f;  // 1/sqrt(128)
    const float lg = 0.20762050593045f;        // log2(10000)/64
#pragma unroll
    for (int it = 0; it < 8; ++it) {
        int pi = tid + it * 256;        // 0..2047 : q pairs
        int head = pi >> 6, t = pi & 63;
        float inv = exp2f(-(float)t * lg);
        float ang = fpos * inv;
        float s = __sinf(ang), c = __cosf(ang);
        const unsigned short* bp = qkvb + (size_t)row * QKV_D + head * HD + t;
        float x1 = bf2f(bp[0]), x2 = bf2f(bp[64]);
        unsigned short* qb = Qc + (size_t)row * H_DIM + head * HD + t;
        qb[0]  = f2bf((x1 * c - x2 * s) * scale);
        qb[64] = f2bf((x2 * c + x1 * s) * scale);
    }
#pragma unroll
    for (int it = 0; it < 2; ++it) {
        int pi = tid + it * 256;        // 0..511 : k pairs
        int kvh = pi >> 6, t = pi & 63;
        float inv = exp2f(-(float)t * lg);
        float ang = fpos * inv;
        float s = __sinf(ang), c = __cosf(ang);
        const unsigned short* bp = qkvb + (size_t)row * QKV_D + H_DIM + kvh * HD + t;
        float x1 = bf2f(bp[0]), x2 = bf2f(bp[64]);
        unsigned short* kb = Kc + ((size_t)kvh * N_TOK + row) * HD + t;
        kb[0]  = f2bf(x1 * c - x2 * s);
        kb[64] = f2bf(x2 * c + x1 * s);
    }
}

// ---------------- V transpose: bf16 qkv V section -> Vt[kvh][d][key] ----------------
__global__ __launch_bounds__(256) void vt_k(const unsigned short* __restrict__ qkvb,
                                            unsigned short* __restrict__ Vt) {
    __shared__ unsigned short ts[64][136];
    int j0 = blockIdx.x * 64, kvh = blockIdx.y, tid = threadIdx.x;
#pragma unroll
    for (int it = 0; it < 4; ++it) {
        int idx = tid + it * 256;   // 16B slots of 64x128 ushort tile
        int r = idx >> 4, c8 = idx & 15;
        *(uint4*)&ts[r][c8 * 8] =
            *(const uint4*)(qkvb + (size_t)(j0 + r) * QKV_D + (NH + NKV) * HD + kvh * HD + c8 * 8);
    }
    __syncthreads();
    int d = tid >> 1, half = tid & 1;
    unsigned short* dst = Vt + ((size_t)kvh * HD + d) * N_TOK + j0 + half * 32;
#pragma unroll
    for (int g = 0; g < 4; ++g) {
        int kb = half * 32 + g * 8;
        uint4 o;
        o.x = (unsigned)ts[kb + 0][d] | ((unsigned)ts[kb + 1][d] << 16);
        o.y = (unsigned)ts[kb + 2][d] | ((unsigned)ts[kb + 3][d] << 16);
        o.z = (unsigned)ts[kb + 4][d] | ((unsigned)ts[kb + 5][d] << 16);
        o.w = (unsigned)ts[kb + 6][d] | ((unsigned)ts[kb + 7][d] << 16);
        *(uint4*)(dst + g * 8) = o;
    }
}

// ---------------- bf16 MFMA flash attention ----------------
// block = 512 threads / 8 waves: 64 q-rows x 2 heads (same kv-head group).
// T4: counted vmcnt(2) + raw s_barrier (loads stay in flight across barrier).
// T13: defer-max — skip o-rescale when __all(mx <= mstat + 8); P bounded by e^8.
__global__ __launch_bounds__(512) void attn_k(const __hip_bfloat16* __restrict__ Qc,
                                              const __hip_bfloat16* __restrict__ Kc,
                                              const __hip_bfloat16* __restrict__ Vt,
                                              unsigned short* __restrict__ ao) {
    __shared__ __align__(16) __hip_bfloat16 Ks[2][32 * 128];   // [key][d], swizzled 16B units, 8KB/buf
    __shared__ __align__(16) __hip_bfloat16 Vs[2][128 * 32];   // [d][key], swizzled 16B units, 8KB/buf
    __shared__ __align__(16) unsigned short Pw[8][16 * 40];    // per-wave P, row stride 80B

    int tid = threadIdx.x, w = tid >> 6, lane = tid & 63;
    int quad = lane >> 4, l15 = lane & 15;
    int pr = blockIdx.y;                 // 0..15: (kvh, head-pair)
    int kvh = pr >> 1;
    int h = kvh * 4 + (pr & 1) * 2 + (w & 1);
    int qt = gridDim.x - 1 - blockIdx.x; // heavy tiles first
    int i0 = qt * 64;
    int i0q = i0 + (w >> 1) * 16;
    int q = i0q + l15;

    bf16x8 qf[4];
    const __hip_bfloat16* qrow = Qc + (size_t)q * H_DIM + h * HD;
#pragma unroll
    for (int kf = 0; kf < 4; ++kf)
        qf[kf] = *(const bf16x8*)(qrow + kf * 32 + quad * 8);

    const char* KcH = (const char*)(Kc + (size_t)kvh * N_TOK * HD);
    const char* VtH = (const char*)(Vt + (size_t)kvh * HD * N_TOK);

    int kKey = w * 4 + (lane >> 4);
    int kPart = (lane & 15) ^ (kKey & 15);
    int vD = w * 16 + (lane >> 2);
    int vP = (lane & 3) ^ (vD & 3);
    char* Kl[2] = { (char*)&Ks[0][0] + w * 1024, (char*)&Ks[1][0] + w * 1024 };
    char* Vl[2] = { (char*)&Vs[0][0] + w * 1024, (char*)&Vs[1][0] + w * 1024 };

    float mstat = -INFINITY, lstat = 0.f;
    f32x4 o[8];
#pragma unroll
    for (int nt = 0; nt < 8; ++nt) o[nt] = (f32x4){0.f, 0.f, 0.f, 0.f};

    int nsteps = (i0 + 64) >> 5;

    // prologue: stage step 0 into buf 0 (2 loads in flight; waited in iter 0)
    gld16(KcH + (size_t)kKey * 256 + kPart * 16, Kl[0]);
    gld16(VtH + (size_t)vD * (N_TOK * 2) + vP * 16, Vl[0]);

    for (int t = 0; t < nsteps; ++t) {
        int j0 = t << 5;
        int cur = t & 1;
        if (t + 1 < nsteps) {   // issue next tile's loads; keep them in flight
            int jn = j0 + 32;
            gld16(KcH + (size_t)(jn + kKey) * 256 + kPart * 16, Kl[cur ^ 1]);
            gld16(VtH + (size_t)vD * (N_TOK * 2) + (size_t)jn * 2 + vP * 16, Vl[cur ^ 1]);
            // wait only step t's 2 loads (leave the 2 new ones outstanding)
            asm volatile("s_waitcnt vmcnt(2)" ::: "memory");
        } else {
            asm volatile("s_waitcnt vmcnt(0)" ::: "memory");
        }
        __builtin_amdgcn_sched_barrier(0);
        __builtin_amdgcn_s_barrier();      // step-t K/V resident for all waves
        __builtin_amdgcn_sched_barrier(0);

        if (j0 <= i0q + 15) {
            const char* Kb = (const char*)&Ks[cur][0];
            const char* Vb = (const char*)&Vs[cur][0];

            // S^T = K (32keys x 128d) * Q^T : D row=key(quad*4+reg), col=q(lane&15)
            f32x4 s[2];
            s[0] = (f32x4){0.f, 0.f, 0.f, 0.f};
            s[1] = (f32x4){0.f, 0.f, 0.f, 0.f};
#pragma unroll
            for (int mt = 0; mt < 2; ++mt) {
                int key = mt * 16 + l15;
#pragma unroll
                for (int kf = 0; kf < 4; ++kf) {
                    bf16x8 kfr = *(const bf16x8*)(Kb + key * 256 + (((kf * 4 + quad) ^ (key & 15)) * 16));
                    s[mt] = __builtin_amdgcn_mfma_f32_16x16x32_bf16(kfr, qf[kf], s[mt], 0, 0, 0);
                }
            }
            if (j0 + 31 > i0q) {
#pragma unroll
                for (int mt = 0; mt < 2; ++mt) {
                    int keyb = j0 + mt * 16 + quad * 4;
#pragma unroll
                    for (int r = 0; r < 4; ++r)
                        if (keyb + r > q) s[mt][r] = -INFINITY;
                }
            }
            float mx = fmaxf(fmaxf(fmaxf(s[0][0], s[0][1]), fmaxf(s[0][2], s[0][3])),
                             fmaxf(fmaxf(s[1][0], s[1][1]), fmaxf(s[1][2], s[1][3])));
            mx = fmaxf(mx, __shfl_xor(mx, 16));
            mx = fmaxf(mx, __shfl_xor(mx, 32));

            // T13 defer-max: if max didn't grow past mstat+8, keep old max —
            // skips alpha broadcast + o-rescale. P bounded by e^8 (safe in bf16).
            bool skip = __all(mx <= mstat + 8.0f);
            float newm = skip ? mstat : fmaxf(mstat, mx);
            float p[8];
#pragma unroll
            for (int mt = 0; mt < 2; ++mt)
#pragma unroll
                for (int r = 0; r < 4; ++r) p[mt * 4 + r] = __expf(s[mt][r] - newm);
            float ps = p[0] + p[1] + p[2] + p[3] + p[4] + p[5] + p[6] + p[7];
            ps += __shfl_xor(ps, 16);
            ps += __shfl_xor(ps, 32);
            if (skip) {
                lstat += ps;
            } else {
                float alpha = __expf(mstat - newm);
                lstat = lstat * alpha + ps;
                mstat = newm;
                float alq[4];
#pragma unroll
                for (int r = 0; r < 4; ++r) alq[r] = __shfl(alpha, quad * 4 + r);
#pragma unroll
                for (int nt = 0; nt < 8; ++nt)
#pragma unroll
                    for (int r = 0; r < 4; ++r) o[nt][r] *= alq[r];
            }

            unsigned* pwb = (unsigned*)(&Pw[w][0]);
            int eo = l15 * 20 + quad * 2;
            pwb[eo]     = pack2bf(p[0], p[1]);
            pwb[eo + 1] = pack2bf(p[2], p[3]);
            pwb[eo + 8] = pack2bf(p[4], p[5]);
            pwb[eo + 9] = pack2bf(p[6], p[7]);
            bf16x8 pf = *(const bf16x8*)(&Pw[w][l15 * 40 + quad * 8]);

#pragma unroll
            for (int nt = 0; nt < 8; ++nt) {
                int d = nt * 16 + l15;
                bf16x8 vf = *(const bf16x8*)(Vb + d * 64 + ((quad ^ (d & 3)) * 16));
                o[nt] = __builtin_amdgcn_mfma_f32_16x16x32_bf16(pf, vf, o[nt], 0, 0, 0);
            }
        }
        __builtin_amdgcn_sched_barrier(0);
        __builtin_amdgcn_s_barrier();      // all reads of buf[cur] done before t+1 overwrites
        __builtin_amdgcn_sched_barrier(0);
    }

    float linv[4];
#pragma unroll
    for (int r = 0; r < 4; ++r) linv[r] = 1.f / __shfl(lstat, quad * 4 + r);
#pragma unroll
    for (int nt = 0; nt < 8; ++nt)
#pragma unroll
        for (int r = 0; r < 4; ++r) {
            int row = i0q + quad * 4 + r;
            int col = h * HD + nt * 16 + l15;
            ao[(size_t)row * H_DIM + col] = f2bf(o[nt][r] * linv[r]);
        }
}

// ---------------- top-2 routing ----------------
__global__ __launch_bounds__(256) void topk_k(const float* __restrict__ elog,
                                              float* __restrict__ w_out,
                                              float* __restrict__ id_out,
                                              int* __restrict__ ids_int) {
    int row = blockIdx.x * 256 + threadIdx.x;
    if (row >= N_TOK) return;
    const float4* e4 = (const float4*)(elog + (size_t)row * NE);
    float4 a = e4[0], b = e4[1];
    float e[8] = {a.x, a.y, a.z, a.w, b.x, b.y, b.z, b.w};
    int id0 = 0;
    float b0 = e[0];
#pragma unroll
    for (int t = 1; t < 8; ++t)
        if (e[t] > b0) { b0 = e[t]; id0 = t; }
    int id1 = -1;
    float b1 = -INFINITY;
#pragma unroll
    for (int t = 0; t < 8; ++t)
        if (t != id0 && e[t] > b1) { b1 = e[t]; id1 = t; }
    float s = b0 + b1;
    w_out[row * 2 + 0] = b0 / s;
    w_out[row * 2 + 1] = b1 / s;
    id_out[row * 2 + 0] = (float)id0;
    id_out[row * 2 + 1] = (float)id1;
    ids_int[row * 2 + 0] = id0;
    ids_int[row * 2 + 1] = id1;
}

// ---------------- stable argsort of 4096 expert ids (counting rank) ----------------
__global__ __launch_bounds__(256) void sort_k(const int* __restrict__ ids,
                                              float* __restrict__ reorder_out,
                                              int* __restrict__ perm) {
    __shared__ int sh[N_TOK * TOPK];
    int tid = threadIdx.x;
    for (int r = tid; r < N_TOK * TOPK; r += 256) sh[r] = ids[r];
    __syncthreads();
    int i = blockIdx.x * 256 + tid;
    int e = sh[i];
    int rank = 0;
    for (int j = 0; j < N_TOK * TOPK; ++j) {
        int ej = sh[j];
        rank += (ej < e) ? 1 : ((ej == e && j < i) ? 1 : 0);
    }
    reorder_out[rank] = (float)i;
    perm[rank] = i;
}

// ---------------- permuted row gather ----------------
__global__ __launch_bounds__(256) void gather_k(const float* __restrict__ src,
                                                const int* __restrict__ perm,
                                                float* __restrict__ dst) {
    int r = blockIdx.x;
    int srow = perm[r] >> 1;  // // TOPK
    const float4* s4 = (const float4*)(src + (size_t)srow * H_DIM);
    float4* d4 = (float4*)(dst + (size_t)r * H_DIM);
    int tid = threadIdx.x;
#pragma unroll
    for (int k = 0; k < 4; ++k) d4[tid + k * 256] = s4[tid + k * 256];
}

extern "C" void kernel_launch(void* const* d_in, const int* in_sizes, int n_in,
                              void* d_out, int out_size, void* d_ws, size_t ws_size,
                              hipStream_t stream) {
    const int*   positions = (const int*)d_in[0];
    const float* hidden    = (const float*)d_in[1];
    const float* w_qkv     = (const float*)d_in[2];
    const float* w_o       = (const float*)d_in[3];
    // d_in[4] = w_gate: dead code in reference
    const float* rms_pre   = (const float*)d_in[5];
    const float* rms_post  = (const float*)d_in[6];
    const float* elog      = (const float*)d_in[7];
    float* out = (float*)d_out;

    char* ws = (char*)d_ws;
    unsigned short* wqkvT = (unsigned short*)(ws);                 // [0, 50.3M) until qkv-gemm
    unsigned short* woT   = (unsigned short*)(ws);                 // [0, 33.5M) conv2..o-gemm
    float*          post  = (float*)(ws + 33554432ULL);            // [33.5M, 67.1M) rms2..gather
    unsigned short* xn    = (unsigned short*)(ws + 50331648ULL);   // [50.3M, 67.1M) rms1..qkv-gemm
    unsigned short* aout  = (unsigned short*)(ws + 50331648ULL);   // [50.3M, 67.1M) attn..o-gemm
    unsigned short* qkvb  = (unsigned short*)(ws + 67108864ULL);   // [67.1M, 92.3M) bf16 qkv
    float*          sbuf  = (float*)(ws + 67108864ULL);            // [67.1M, 100.7M) o-gemm..rms2
    unsigned short* Qc    = (unsigned short*)(ws + 117440512ULL);  // 16 MB
    unsigned short* Kc    = (unsigned short*)(ws + 134217728ULL);  // 4 MB
    unsigned short* Vt    = (unsigned short*)(ws + 138412032ULL);  // 4 MB
    int* ids_int  = (int*)(ws + 142606336ULL);
    int* perm_int = (int*)(ws + 142622720ULL);

    // 1. w_qkv -> bf16 transposed [6144][4096]
    convT_k<<<dim3(QKV_D / 64, H_DIM / 64), 256, 0, stream>>>(w_qkv, wqkvT, H_DIM, QKV_D);
    // 2. pre-attention RMSNorm -> bf16
    rmsnorm_k<<<N_TOK, 256, 0, stream>>>(hidden, rms_pre, nullptr, xn);
    // 3. QKV projection: 256x192 full-fill GEMM (8x32 = 256 blocks) -> bf16 qkv
    gemm256_k<192, true><<<dim3(N_TOK / 256, QKV_D / 192), 512, 0, stream>>>(
        (const __hip_bfloat16*)xn, (const __hip_bfloat16*)wqkvT, nullptr, qkvb, nullptr, QKV_D);
    // 4. w_o -> bf16 transposed [4096][4096]  (reuses wqkvT region)
    convT_k<<<dim3(H_DIM / 64, H_DIM / 64), 256, 0, stream>>>(w_o, woT, H_DIM, H_DIM);
    // 5. RoPE + pack Qc/Kc bf16
    prep_k<<<N_TOK, 256, 0, stream>>>(qkvb, positions, Qc, Kc);
    // 6. V transpose -> Vt bf16
    vt_k<<<dim3(N_TOK / 64, NKV), 256, 0, stream>>>(qkvb, Vt);
    // 7. causal GQA flash attention (bf16 MFMA) -> bf16 attn_out
    attn_k<<<dim3(N_TOK / 64, 16), 512, 0, stream>>>(
        (const __hip_bfloat16*)Qc, (const __hip_bfloat16*)Kc, (const __hip_bfloat16*)Vt, aout);
    // 8. output projection + residual: 256x128 full-fill GEMM (8x32 = 256 blocks) -> fp32 s
    gemm256_k<128, false><<<dim3(N_TOK / 256, H_DIM / 128), 512, 0, stream>>>(
        (const __hip_bfloat16*)aout, (const __hip_bfloat16*)woT, sbuf, nullptr, hidden, H_DIM);
    // 9. post-attention RMSNorm -> fp32
    rmsnorm_k<<<N_TOK, 256, 0, stream>>>(sbuf, rms_post, post, nullptr);
    // 10. top-2 experts
    topk_k<<<N_TOK / 256, 256, 0, stream>>>(elog, out + OUT_W, out + OUT_IDS, ids_int);
    // 11. stable argsort of expert ids
    sort_k<<<(N_TOK * TOPK) / 256, 256, 0, stream>>>(ids_int, out + OUT_REO, perm_int);
    // 12. permuted gather
    gather_k<<<N_TOK * TOPK, 256, 0, stream>>>(post, perm_int, out + OUT_PERM);
}

// Round 10
// 640.375 us; speedup vs baseline: 1.2639x; 1.0286x over previous
//
#include <hip/hip_runtime.h>
#include <hip/hip_bf16.h>
#include <math.h>

// Problem constants
#define N_TOK 2048
#define H_DIM 4096
#define NH 32
#define NKV 8
#define HD 128
#define QKV_D 6144   // (NH + 2*NKV) * HD
#define NE 8
#define TOPK 2

// d_out layout (floats): permuted_output | topk_weights | topk_ids | reorder_ids
#define OUT_PERM 0
#define OUT_W    16777216   // 4096*4096
#define OUT_IDS  16781312
#define OUT_REO  16785408

typedef __bf16 bf16x8 __attribute__((ext_vector_type(8)));
typedef float f32x4 __attribute__((ext_vector_type(4)));

typedef __attribute__((address_space(3))) void lds_void;
typedef __attribute__((address_space(1))) const void gbl_void;

__device__ __forceinline__ void gld16(const void* g, void* l) {
    // async global->LDS, 16B per lane; LDS dest = wave-uniform base + lane*16
    __builtin_amdgcn_global_load_lds((gbl_void*)g, (lds_void*)l, 16, 0, 0);
}

__device__ __forceinline__ unsigned short f2bf(float f) {
    union { float f; unsigned u; } v; v.f = f;
    unsigned r = v.u + 0x7fff + ((v.u >> 16) & 1);
    return (unsigned short)(r >> 16);
}
__device__ __forceinline__ unsigned pack2bf(float a, float b) {
    return (unsigned)f2bf(a) | ((unsigned)f2bf(b) << 16);
}
__device__ __forceinline__ float bf2f(unsigned short u) {
    union { unsigned u; float f; } v; v.u = ((unsigned)u) << 16;
    return v.f;
}

// ---------------- RMSNorm (fp32 in; fp32 or bf16 out) ----------------
__global__ __launch_bounds__(256) void rmsnorm_k(const float* __restrict__ x,
                                                 const float* __restrict__ w,
                                                 float* __restrict__ yf,
                                                 unsigned short* __restrict__ yb) {
    int row = blockIdx.x;
    int tid = threadIdx.x;
    const float4* x4 = (const float4*)(x + (size_t)row * H_DIM);
    const float4* w4 = (const float4*)w;
    float4 v[4];
    float ss = 0.f;
#pragma unroll
    for (int k = 0; k < 4; ++k) {
        v[k] = x4[tid + k * 256];
        ss += v[k].x * v[k].x + v[k].y * v[k].y + v[k].z * v[k].z + v[k].w * v[k].w;
    }
#pragma unroll
    for (int off = 32; off; off >>= 1) ss += __shfl_xor(ss, off);
    __shared__ float sacc[4];
    if ((tid & 63) == 0) sacc[tid >> 6] = ss;
    __syncthreads();
    float tot = sacc[0] + sacc[1] + sacc[2] + sacc[3];
    float sc = rsqrtf(tot * (1.0f / H_DIM) + 1e-6f);
#pragma unroll
    for (int k = 0; k < 4; ++k) {
        float4 ww = w4[tid + k * 256];
        float4 o;
        o.x = v[k].x * sc * ww.x;
        o.y = v[k].y * sc * ww.y;
        o.z = v[k].z * sc * ww.z;
        o.w = v[k].w * sc * ww.w;
        if (yf) {
            *(float4*)(yf + (size_t)row * H_DIM + (tid + k * 256) * 4) = o;
        } else {
            uint2 p;
            p.x = pack2bf(o.x, o.y);
            p.y = pack2bf(o.z, o.w);
            *(uint2*)(yb + (size_t)row * H_DIM + (tid + k * 256) * 4) = p;
        }
    }
}

// ---------------- transpose + fp32->bf16 weight conversion ----------------
// src[R][C] fp32 -> dst[C][R] bf16 (64x64 tiles)
__global__ __launch_bounds__(256) void convT_k(const float* __restrict__ src,
                                               unsigned short* __restrict__ dst,
                                               int R, int C) {
    __shared__ float t[64][68];
    int r0 = blockIdx.y * 64, c0 = blockIdx.x * 64;
    int tid = threadIdx.x;
    int lr = tid >> 4, lc = tid & 15;
#pragma unroll
    for (int it = 0; it < 4; ++it) {
        int r = lr + it * 16;
        float4 v = *(const float4*)(src + (size_t)(r0 + r) * C + c0 + lc * 4);
        *(float4*)&t[r][lc * 4] = v;
    }
    __syncthreads();
#pragma unroll
    for (int it = 0; it < 4; ++it) {
        int cc = lr + it * 16;
        uint2 o;
        o.x = pack2bf(t[lc * 4 + 0][cc], t[lc * 4 + 1][cc]);
        o.y = pack2bf(t[lc * 4 + 2][cc], t[lc * 4 + 3][cc]);
        *(uint2*)(dst + (size_t)(c0 + cc) * R + r0 + lc * 4) = o;
    }
}

// ---------------- full-fill 256xBN bf16 MFMA GEMM (2-barrier schedule) ----------------
// BM=256, BN in {192,128} chosen so grid == 256 blocks (1/CU, full chip fill).
// BK=64, 8 waves (2M x 4N), per-wave 128 x BN/4 output. LDS: A 64KB + B 2*BN*128B.
// Schedule per K-tile:
//   region1: ds_read A0-3 + all B; stage A(j+1); setprio+MFMA     | mid barrier
//   region2: ds_read A4-7; stage B(j+2); setprio+MFMA; vmcnt(NT)  | end barrier
// vmcnt ledger (NT = BN/64): end-of-tile vmcnt(NT) leaves exactly B(j+2) in
// flight -> A(j+1), B(j+1) proven resident. Tails drain with vmcnt(0).
// XOR swizzle on pre-swizzled GLOBAL source unit, mirrored on ds_read (rule #21).
template<int BN, bool BF16OUT>
__global__ __launch_bounds__(512) void gemm256_k(const __hip_bfloat16* __restrict__ A,
                                                 const __hip_bfloat16* __restrict__ Bt,
                                                 float* __restrict__ C,
                                                 unsigned short* __restrict__ Cb,
                                                 const float* __restrict__ residual,
                                                 int Ncols) {
    constexpr int NT = BN / 64;    // per-wave n-tiles AND B-stage loads/thread
    __shared__ __align__(16) __hip_bfloat16 As[2][256 * 64];  // 64 KB
    __shared__ __align__(16) __hip_bfloat16 Bs[2][BN * 64];   // 48/32 KB
    const int K = H_DIM;
    int tid = threadIdx.x, w = tid >> 6, lane = tid & 63;
    int quad = lane >> 4, l15 = lane & 15;
    int wr = w >> 2, wc = w & 3;       // wave grid 2M x 4N

    // XCD-aware bijective block swizzle (nwg == 256, %8 == 0)
    int gx = gridDim.x;
    int nwg = gx * gridDim.y;
    int v = blockIdx.y * gx + blockIdx.x;
    int lin = (v & 7) * (nwg >> 3) + (v >> 3);
    int m0 = (lin % gx) * 256, n0 = (lin / gx) * BN;

    const char* Abase = (const char*)A + (size_t)m0 * (K * 2);
    const char* Bbase = (const char*)Bt + (size_t)n0 * (K * 2);
    int srow = w * 8 + (lane >> 3);    // 0..63 stage row group

    auto stageA = [&](char* lbase, size_t kbyte) {
#pragma unroll
        for (int l = 0; l < 4; ++l) {
            int r = l * 64 + srow;                  // 0..255
            int gu = (lane & 7) ^ (r & 7);
            gld16(Abase + (size_t)r * (K * 2) + kbyte + gu * 16,
                  lbase + (size_t)(l * 64 + w * 8) * 128);
        }
    };
    auto stageB = [&](char* lbase, size_t kbyte) {
#pragma unroll
        for (int l = 0; l < NT; ++l) {
            int r = l * 64 + srow;                  // 0..BN-1
            int gu = (lane & 7) ^ (r & 7);
            gld16(Bbase + (size_t)r * (K * 2) + kbyte + gu * 16,
                  lbase + (size_t)(l * 64 + w * 8) * 128);
        }
    };

    f32x4 acc[8][NT];
#pragma unroll
    for (int i = 0; i < 8; ++i)
#pragma unroll
        for (int j = 0; j < NT; ++j) acc[i][j] = (f32x4){0.f, 0.f, 0.f, 0.f};

    const int ntiles = K / 64;   // 64

    // prologue: A(0), B(0), B(1); wait all but B(1) (NT loads stay in flight)
    stageA((char*)&As[0][0], 0);
    stageB((char*)&Bs[0][0], 0);
    stageB((char*)&Bs[1][0], 128);
    if constexpr (NT == 3) asm volatile("s_waitcnt vmcnt(3)" ::: "memory");
    else                   asm volatile("s_waitcnt vmcnt(2)" ::: "memory");
    __builtin_amdgcn_sched_barrier(0);
    __builtin_amdgcn_s_barrier();
    __builtin_amdgcn_sched_barrier(0);

    for (int j = 0; j < ntiles; ++j) {
        int d = j & 1;
        const char* sA = (const char*)&As[d][0];
        const char* sB = (const char*)&Bs[d][0];
        size_t kb1 = (size_t)(j + 1) * 128, kb2 = (size_t)(j + 2) * 128;
        bf16x8 aR[4][2], bR[NT][2];

        // ========== region 1: A[mt0-3] + all B reads; stage A(j+1); MFMA ==========
#pragma unroll
        for (int mt = 0; mt < 4; ++mt)
#pragma unroll
            for (int kk = 0; kk < 2; ++kk) {
                int m = wr * 128 + mt * 16 + l15;
                aR[mt][kk] = *(const bf16x8*)(sA + m * 128 + (((kk * 4 + quad) ^ (m & 7)) * 16));
            }
#pragma unroll
        for (int nt = 0; nt < NT; ++nt)
#pragma unroll
            for (int kk = 0; kk < 2; ++kk) {
                int n = wc * (NT * 16) + nt * 16 + l15;
                bR[nt][kk] = *(const bf16x8*)(sB + n * 128 + (((kk * 4 + quad) ^ (n & 7)) * 16));
            }
        if (j + 1 < ntiles) stageA((char*)&As[d ^ 1][0], kb1);
        __builtin_amdgcn_s_setprio(1);
#pragma unroll
        for (int mt = 0; mt < 4; ++mt)
#pragma unroll
            for (int nt = 0; nt < NT; ++nt)
#pragma unroll
                for (int kk = 0; kk < 2; ++kk)
                    acc[mt][nt] = __builtin_amdgcn_mfma_f32_16x16x32_bf16(aR[mt][kk], bR[nt][kk], acc[mt][nt], 0, 0, 0);
        __builtin_amdgcn_s_setprio(0);
        __builtin_amdgcn_sched_barrier(0);
        __builtin_amdgcn_s_barrier();      // mid: all waves' B-reads of tile j done
        __builtin_amdgcn_sched_barrier(0);

        // ========== region 2: A[mt4-7] reads; stage B(j+2); MFMA; counted vmcnt ==========
#pragma unroll
        for (int mt = 0; mt < 4; ++mt)
#pragma unroll
            for (int kk = 0; kk < 2; ++kk) {
                int m = wr * 128 + (mt + 4) * 16 + l15;
                aR[mt][kk] = *(const bf16x8*)(sA + m * 128 + (((kk * 4 + quad) ^ (m & 7)) * 16));
            }
        if (j + 2 < ntiles) stageB((char*)&Bs[d][0], kb2);
        __builtin_amdgcn_s_setprio(1);
#pragma unroll
        for (int mt = 0; mt < 4; ++mt)
#pragma unroll
            for (int nt = 0; nt < NT; ++nt)
#pragma unroll
                for (int kk = 0; kk < 2; ++kk)
                    acc[mt + 4][nt] = __builtin_amdgcn_mfma_f32_16x16x32_bf16(aR[mt][kk], bR[nt][kk], acc[mt + 4][nt], 0, 0, 0);
        __builtin_amdgcn_s_setprio(0);
        if (j + 2 < ntiles) {
            if constexpr (NT == 3) asm volatile("s_waitcnt vmcnt(3)" ::: "memory");
            else                   asm volatile("s_waitcnt vmcnt(2)" ::: "memory");
        } else {
            asm volatile("s_waitcnt vmcnt(0)" ::: "memory");   // tail: drain
        }
        __builtin_amdgcn_sched_barrier(0);
        __builtin_amdgcn_s_barrier();      // end: tile j+1 resident; A-readers done
        __builtin_amdgcn_sched_barrier(0);
    }

    // epilogue: C/D layout col=lane&15, row=quad*4+reg
#pragma unroll
    for (int mt = 0; mt < 8; ++mt)
#pragma unroll
        for (int nt = 0; nt < NT; ++nt)
#pragma unroll
            for (int r = 0; r < 4; ++r) {
                int row = m0 + wr * 128 + mt * 16 + quad * 4 + r;
                int col = n0 + wc * (NT * 16) + nt * 16 + l15;
                size_t off = (size_t)row * Ncols + col;
                if constexpr (BF16OUT) {
                    Cb[off] = f2bf(acc[mt][nt][r]);
                } else {
                    float vv = acc[mt][nt][r];
                    if (residual) vv += residual[off];
                    C[off] = vv;
                }
            }
}

// ---------------- prep: RoPE + pack Qc (scaled bf16) and Kc (bf16, per-head rows) ----
__global__ __launch_bounds__(256) void prep_k(const unsigned short* __restrict__ qkvb,
                                              const int* __restrict__ pos,
                                              unsigned short* __restrict__ Qc,
                                              unsigned short* __restrict__ Kc) {
    int row = blockIdx.x, tid = threadIdx.x;
    float fpos = (float)pos[row];
    const float scale = 0.08838834764831845f;  // 1/sqrt(128)
    const float lg = 0.20762050593045f;        // log2(10000)/64
#pragma unroll
    for (int it = 0; it < 8; ++it) {
        int pi = tid + it * 256;        // 0..2047 : q pairs
        int head = pi >> 6, t = pi & 63;
        float inv = exp2f(-(float)t * lg);
        float ang = fpos * inv;
        float s = __sinf(ang), c = __cosf(ang);
        const unsigned short* bp = qkvb + (size_t)row * QKV_D + head * HD + t;
        float x1 = bf2f(bp[0]), x2 = bf2f(bp[64]);
        unsigned short* qb = Qc + (size_t)row * H_DIM + head * HD + t;
        qb[0]  = f2bf((x1 * c - x2 * s) * scale);
        qb[64] = f2bf((x2 * c + x1 * s) * scale);
    }
#pragma unroll
    for (int it = 0; it < 2; ++it) {
        int pi = tid + it * 256;        // 0..511 : k pairs
        int kvh = pi >> 6, t = pi & 63;
        float inv = exp2f(-(float)t * lg);
        float ang = fpos * inv;
        float s = __sinf(ang), c = __cosf(ang);
        const unsigned short* bp = qkvb + (size_t)row * QKV_D + H_DIM + kvh * HD + t;
        float x1 = bf2f(bp[0]), x2 = bf2f(bp[64]);
        unsigned short* kb = Kc + ((size_t)kvh * N_TOK + row) * HD + t;
        kb[0]  = f2bf(x1 * c - x2 * s);
        kb[64] = f2bf(x2 * c + x1 * s);
    }
}

// ---------------- V transpose: bf16 qkv V section -> Vt[kvh][d][key] ----------------
__global__ __launch_bounds__(256) void vt_k(const unsigned short* __restrict__ qkvb,
                                            unsigned short* __restrict__ Vt) {
    __shared__ unsigned short ts[64][136];
    int j0 = blockIdx.x * 64, kvh = blockIdx.y, tid = threadIdx.x;
#pragma unroll
    for (int it = 0; it < 4; ++it) {
        int idx = tid + it * 256;   // 16B slots of 64x128 ushort tile
        int r = idx >> 4, c8 = idx & 15;
        *(uint4*)&ts[r][c8 * 8] =
            *(const uint4*)(qkvb + (size_t)(j0 + r) * QKV_D + (NH + NKV) * HD + kvh * HD + c8 * 8);
    }
    __syncthreads();
    int d = tid >> 1, half = tid & 1;
    unsigned short* dst = Vt + ((size_t)kvh * HD + d) * N_TOK + j0 + half * 32;
#pragma unroll
    for (int g = 0; g < 4; ++g) {
        int kb = half * 32 + g * 8;
        uint4 o;
        o.x = (unsigned)ts[kb + 0][d] | ((unsigned)ts[kb + 1][d] << 16);
        o.y = (unsigned)ts[kb + 2][d] | ((unsigned)ts[kb + 3][d] << 16);
        o.z = (unsigned)ts[kb + 4][d] | ((unsigned)ts[kb + 5][d] << 16);
        o.w = (unsigned)ts[kb + 6][d] | ((unsigned)ts[kb + 7][d] << 16);
        *(uint4*)(dst + g * 8) = o;
    }
}

// ---------------- bf16 MFMA flash attention ----------------
// block = 512 threads / 8 waves: 64 q-rows x 2 heads (same kv-head group).
// KVBLK=64: 32 MFMA per softmax round (halves softmax/barrier cost per key).
// T4: counted vmcnt(4) + raw s_barrier. T13: defer-max (skip o-rescale).
// LDS 80KB exactly (2 blocks/CU): K 2x16KB (256B rows, ^(row&15) unit swizzle),
// V 2x16KB (128B rows, ^(d&7) swizzle), P 16KB (128B rows, ^(q&7) swizzle).
__global__ __launch_bounds__(512) void attn_k(const __hip_bfloat16* __restrict__ Qc,
                                              const __hip_bfloat16* __restrict__ Kc,
                                              const __hip_bfloat16* __restrict__ Vt,
                                              unsigned short* __restrict__ ao) {
    __shared__ __align__(16) __hip_bfloat16 Ks[2][64 * 128];   // [key][d] 16KB/buf
    __shared__ __align__(16) __hip_bfloat16 Vs[2][128 * 64];   // [d][key] 16KB/buf
    __shared__ __align__(16) unsigned short Pw[8][16 * 64];    // per-wave P, 128B rows

    int tid = threadIdx.x, w = tid >> 6, lane = tid & 63;
    int quad = lane >> 4, l15 = lane & 15;
    int pr = blockIdx.y;                 // 0..15: (kvh, head-pair)
    int kvh = pr >> 1;
    int h = kvh * 4 + (pr & 1) * 2 + (w & 1);
    int qt = gridDim.x - 1 - blockIdx.x; // heavy tiles first
    int i0 = qt * 64;
    int i0q = i0 + (w >> 1) * 16;
    int q = i0q + l15;

    bf16x8 qf[4];
    const __hip_bfloat16* qrow = Qc + (size_t)q * H_DIM + h * HD;
#pragma unroll
    for (int kf = 0; kf < 4; ++kf)
        qf[kf] = *(const bf16x8*)(qrow + kf * 32 + quad * 8);

    const char* KcH = (const char*)(Kc + (size_t)kvh * N_TOK * HD);
    const char* VtH = (const char*)(Vt + (size_t)kvh * HD * N_TOK);

    // staging: wave w stages K rows 8w..8w+7 (2 passes x 4 rows x 256B) and
    // V d-rows 16w..16w+15 (2 passes x 8 rows x 128B)
    int rK0 = w * 8 + (lane >> 4), rK1 = rK0 + 4;
    int guK0 = (lane & 15) ^ (rK0 & 15), guK1 = (lane & 15) ^ (rK1 & 15);
    int dV0 = w * 16 + (lane >> 3), dV1 = dV0 + 8;
    int guV0 = (lane & 7) ^ (dV0 & 7), guV1 = (lane & 7) ^ (dV1 & 7);

    float mstat = -INFINITY, lstat = 0.f;
    f32x4 o[8];
#pragma unroll
    for (int nt = 0; nt < 8; ++nt) o[nt] = (f32x4){0.f, 0.f, 0.f, 0.f};

    int nsteps = qt + 1;

    auto stage = [&](int buf, int j0s) {
        char* Kb = (char*)&Ks[buf][0];
        char* Vb = (char*)&Vs[buf][0];
        gld16(KcH + (size_t)(j0s + rK0) * 256 + guK0 * 16, Kb + (w * 8) * 256);
        gld16(KcH + (size_t)(j0s + rK1) * 256 + guK1 * 16, Kb + (w * 8 + 4) * 256);
        gld16(VtH + (size_t)dV0 * (N_TOK * 2) + (size_t)j0s * 2 + guV0 * 16, Vb + (w * 16) * 128);
        gld16(VtH + (size_t)dV1 * (N_TOK * 2) + (size_t)j0s * 2 + guV1 * 16, Vb + (w * 16 + 8) * 128);
    };

    // prologue: stage step 0 into buf 0 (4 loads in flight; waited in iter 0)
    stage(0, 0);

    for (int t = 0; t < nsteps; ++t) {
        int j0 = t << 6;
        int cur = t & 1;
        if (t + 1 < nsteps) {   // issue next tile's 4 loads; keep them in flight
            stage(cur ^ 1, j0 + 64);
            asm volatile("s_waitcnt vmcnt(4)" ::: "memory");
        } else {
            asm volatile("s_waitcnt vmcnt(0)" ::: "memory");
        }
        __builtin_amdgcn_sched_barrier(0);
        __builtin_amdgcn_s_barrier();      // step-t K/V resident for all waves
        __builtin_amdgcn_sched_barrier(0);

        if (j0 <= i0q + 15) {
            const char* Kb = (const char*)&Ks[cur][0];
            const char* Vb = (const char*)&Vs[cur][0];

            // S^T = K (64keys x 128d) * Q^T : D row=key(quad*4+reg), col=q(lane&15)
            f32x4 s[4];
#pragma unroll
            for (int mt = 0; mt < 4; ++mt) s[mt] = (f32x4){0.f, 0.f, 0.f, 0.f};
#pragma unroll
            for (int mt = 0; mt < 4; ++mt) {
                int key = mt * 16 + l15;
#pragma unroll
                for (int kf = 0; kf < 4; ++kf) {
                    bf16x8 kfr = *(const bf16x8*)(Kb + key * 256 + (((kf * 4 + quad) ^ (key & 15)) * 16));
                    s[mt] = __builtin_amdgcn_mfma_f32_16x16x32_bf16(kfr, qf[kf], s[mt], 0, 0, 0);
                }
            }
            if (j0 + 63 > i0q) {
#pragma unroll
                for (int mt = 0; mt < 4; ++mt) {
                    int keyb = j0 + mt * 16 + quad * 4;
#pragma unroll
                    for (int r = 0; r < 4; ++r)
                        if (keyb + r > q) s[mt][r] = -INFINITY;
                }
            }
            float mx = -INFINITY;
#pragma unroll
            for (int mt = 0; mt < 4; ++mt)
                mx = fmaxf(mx, fmaxf(fmaxf(s[mt][0], s[mt][1]), fmaxf(s[mt][2], s[mt][3])));
            mx = fmaxf(mx, __shfl_xor(mx, 16));
            mx = fmaxf(mx, __shfl_xor(mx, 32));

            // T13 defer-max
            bool skip = __all(mx <= mstat + 8.0f);
            float newm = skip ? mstat : fmaxf(mstat, mx);
            float p[16];
#pragma unroll
            for (int mt = 0; mt < 4; ++mt)
#pragma unroll
                for (int r = 0; r < 4; ++r) p[mt * 4 + r] = __expf(s[mt][r] - newm);
            float ps = 0.f;
#pragma unroll
            for (int i = 0; i < 16; ++i) ps += p[i];
            ps += __shfl_xor(ps, 16);
            ps += __shfl_xor(ps, 32);
            if (skip) {
                lstat += ps;
            } else {
                float alpha = __expf(mstat - newm);
                lstat = lstat * alpha + ps;
                mstat = newm;
                float alq[4];
#pragma unroll
                for (int r = 0; r < 4; ++r) alq[r] = __shfl(alpha, quad * 4 + r);
#pragma unroll
                for (int nt = 0; nt < 8; ++nt)
#pragma unroll
                    for (int r = 0; r < 4; ++r) o[nt][r] *= alq[r];
            }

            // P -> LDS, ^(q&7) unit swizzle on 128B rows (conflict-free)
            char* pwb = (char*)&Pw[w][0] + l15 * 128;
#pragma unroll
            for (int mt = 0; mt < 4; ++mt) {
                uint2 pk;
                pk.x = pack2bf(p[mt * 4 + 0], p[mt * 4 + 1]);
                pk.y = pack2bf(p[mt * 4 + 2], p[mt * 4 + 3]);
                *(uint2*)(pwb + (((2 * mt + (quad >> 1)) ^ (l15 & 7)) * 16) + (quad & 1) * 8) = pk;
            }
            bf16x8 pf[2];
#pragma unroll
            for (int ks = 0; ks < 2; ++ks)
                pf[ks] = *(const bf16x8*)(pwb + (((ks * 4 + quad) ^ (l15 & 7)) * 16));

#pragma unroll
            for (int ks = 0; ks < 2; ++ks)
#pragma unroll
                for (int nt = 0; nt < 8; ++nt) {
                    int d = nt * 16 + l15;
                    bf16x8 vf = *(const bf16x8*)(Vb + d * 128 + (((ks * 4 + quad) ^ (d & 7)) * 16));
                    o[nt] = __builtin_amdgcn_mfma_f32_16x16x32_bf16(pf[ks], vf, o[nt], 0, 0, 0);
                }
        }
        __builtin_amdgcn_sched_barrier(0);
        __builtin_amdgcn_s_barrier();      // all reads of buf[cur] done before t+1 overwrites
        __builtin_amdgcn_sched_barrier(0);
    }

    float linv[4];
#pragma unroll
    for (int r = 0; r < 4; ++r) linv[r] = 1.f / __shfl(lstat, quad * 4 + r);
#pragma unroll
    for (int nt = 0; nt < 8; ++nt)
#pragma unroll
        for (int r = 0; r < 4; ++r) {
            int row = i0q + quad * 4 + r;
            int col = h * HD + nt * 16 + l15;
            ao[(size_t)row * H_DIM + col] = f2bf(o[nt][r] * linv[r]);
        }
}

// ---------------- top-2 routing ----------------
__global__ __launch_bounds__(256) void topk_k(const float* __restrict__ elog,
                                              float* __restrict__ w_out,
                                              float* __restrict__ id_out,
                                              int* __restrict__ ids_int) {
    int row = blockIdx.x * 256 + threadIdx.x;
    if (row >= N_TOK) return;
    const float4* e4 = (const float4*)(elog + (size_t)row * NE);
    float4 a = e4[0], b = e4[1];
    float e[8] = {a.x, a.y, a.z, a.w, b.x, b.y, b.z, b.w};
    int id0 = 0;
    float b0 = e[0];
#pragma unroll
    for (int t = 1; t < 8; ++t)
        if (e[t] > b0) { b0 = e[t]; id0 = t; }
    int id1 = -1;
    float b1 = -INFINITY;
#pragma unroll
    for (int t = 0; t < 8; ++t)
        if (t != id0 && e[t] > b1) { b1 = e[t]; id1 = t; }
    float s = b0 + b1;
    w_out[row * 2 + 0] = b0 / s;
    w_out[row * 2 + 1] = b1 / s;
    id_out[row * 2 + 0] = (float)id0;
    id_out[row * 2 + 1] = (float)id1;
    ids_int[row * 2 + 0] = id0;
    ids_int[row * 2 + 1] = id1;
}

// ---------------- stable argsort of 4096 expert ids (counting rank) ----------------
__global__ __launch_bounds__(256) void sort_k(const int* __restrict__ ids,
                                              float* __restrict__ reorder_out,
                                              int* __restrict__ perm) {
    __shared__ int sh[N_TOK * TOPK];
    int tid = threadIdx.x;
    for (int r = tid; r < N_TOK * TOPK; r += 256) sh[r] = ids[r];
    __syncthreads();
    int i = blockIdx.x * 256 + tid;
    int e = sh[i];
    int rank = 0;
    for (int j = 0; j < N_TOK * TOPK; ++j) {
        int ej = sh[j];
        rank += (ej < e) ? 1 : ((ej == e && j < i) ? 1 : 0);
    }
    reorder_out[rank] = (float)i;
    perm[rank] = i;
}

// ---------------- permuted row gather ----------------
__global__ __launch_bounds__(256) void gather_k(const float* __restrict__ src,
                                                const int* __restrict__ perm,
                                                float* __restrict__ dst) {
    int r = blockIdx.x;
    int srow = perm[r] >> 1;  // // TOPK
    const float4* s4 = (const float4*)(src + (size_t)srow * H_DIM);
    float4* d4 = (float4*)(dst + (size_t)r * H_DIM);
    int tid = threadIdx.x;
#pragma unroll
    for (int k = 0; k < 4; ++k) d4[tid + k * 256] = s4[tid + k * 256];
}

extern "C" void kernel_launch(void* const* d_in, const int* in_sizes, int n_in,
                              void* d_out, int out_size, void* d_ws, size_t ws_size,
                              hipStream_t stream) {
    const int*   positions = (const int*)d_in[0];
    const float* hidden    = (const float*)d_in[1];
    const float* w_qkv     = (const float*)d_in[2];
    const float* w_o       = (const float*)d_in[3];
    // d_in[4] = w_gate: dead code in reference
    const float* rms_pre   = (const float*)d_in[5];
    const float* rms_post  = (const float*)d_in[6];
    const float* elog      = (const float*)d_in[7];
    float* out = (float*)d_out;

    char* ws = (char*)d_ws;
    unsigned short* wqkvT = (unsigned short*)(ws);                 // [0, 50.3M) until qkv-gemm
    unsigned short* woT   = (unsigned short*)(ws);                 // [0, 33.5M) conv2..o-gemm
    float*          post  = (float*)(ws + 33554432ULL);            // [33.5M, 67.1M) rms2..gather
    unsigned short* xn    = (unsigned short*)(ws + 50331648ULL);   // [50.3M, 67.1M) rms1..qkv-gemm
    unsigned short* aout  = (unsigned short*)(ws + 50331648ULL);   // [50.3M, 67.1M) attn..o-gemm
    unsigned short* qkvb  = (unsigned short*)(ws + 67108864ULL);   // [67.1M, 92.3M) bf16 qkv
    float*          sbuf  = (float*)(ws + 67108864ULL);            // [67.1M, 100.7M) o-gemm..rms2
    unsigned short* Qc    = (unsigned short*)(ws + 117440512ULL);  // 16 MB
    unsigned short* Kc    = (unsigned short*)(ws + 134217728ULL);  // 4 MB
    unsigned short* Vt    = (unsigned short*)(ws + 138412032ULL);  // 4 MB
    int* ids_int  = (int*)(ws + 142606336ULL);
    int* perm_int = (int*)(ws + 142622720ULL);

    // 1. w_qkv -> bf16 transposed [6144][4096]
    convT_k<<<dim3(QKV_D / 64, H_DIM / 64), 256, 0, stream>>>(w_qkv, wqkvT, H_DIM, QKV_D);
    // 2. pre-attention RMSNorm -> bf16
    rmsnorm_k<<<N_TOK, 256, 0, stream>>>(hidden, rms_pre, nullptr, xn);
    // 3. QKV projection: 256x192 full-fill GEMM (8x32 = 256 blocks) -> bf16 qkv
    gemm256_k<192, true><<<dim3(N_TOK / 256, QKV_D / 192), 512, 0, stream>>>(
        (const __hip_bfloat16*)xn, (const __hip_bfloat16*)wqkvT, nullptr, qkvb, nullptr, QKV_D);
    // 4. w_o -> bf16 transposed [4096][4096]  (reuses wqkvT region)
    convT_k<<<dim3(H_DIM / 64, H_DIM / 64), 256, 0, stream>>>(w_o, woT, H_DIM, H_DIM);
    // 5. RoPE + pack Qc/Kc bf16
    prep_k<<<N_TOK, 256, 0, stream>>>(qkvb, positions, Qc, Kc);
    // 6. V transpose -> Vt bf16
    vt_k<<<dim3(N_TOK / 64, NKV), 256, 0, stream>>>(qkvb, Vt);
    // 7. causal GQA flash attention (bf16 MFMA, KVBLK=64) -> bf16 attn_out
    attn_k<<<dim3(N_TOK / 64, 16), 512, 0, stream>>>(
        (const __hip_bfloat16*)Qc, (const __hip_bfloat16*)Kc, (const __hip_bfloat16*)Vt, aout);
    // 8. output projection + residual: 256x128 full-fill GEMM (8x32 = 256 blocks) -> fp32 s
    gemm256_k<128, false><<<dim3(N_TOK / 256, H_DIM / 128), 512, 0, stream>>>(
        (const __hip_bfloat16*)aout, (const __hip_bfloat16*)woT, sbuf, nullptr, hidden, H_DIM);
    // 9. post-attention RMSNorm -> fp32
    rmsnorm_k<<<N_TOK, 256, 0, stream>>>(sbuf, rms_post, post, nullptr);
    // 10. top-2 experts
    topk_k<<<N_TOK / 256, 256, 0, stream>>>(elog, out + OUT_W, out + OUT_IDS, ids_int);
    // 11. stable argsort of expert ids
    sort_k<<<(N_TOK * TOPK) / 256, 256, 0, stream>>>(ids_int, out + OUT_REO, perm_int);
    // 12. permuted gather
    gather_k<<<N_TOK * TOPK, 256, 0, stream>>>(post, perm_int, out + OUT_PERM);
}